// Round 1
// baseline (1905.296 us; speedup 1.0000x reference)
//
#include <hip/hip_runtime.h>
#include <hip/hip_bf16.h>

typedef __attribute__((ext_vector_type(4))) float f32x4;
typedef __attribute__((ext_vector_type(8))) unsigned short u16x8;
typedef __attribute__((ext_vector_type(4))) unsigned short u16x4;
typedef __bf16 bf16x8 __attribute__((ext_vector_type(8)));

#define DEVFN static __device__ __forceinline__

constexpr int CB = 8, CT = 1024, CDM = 1024, CH = 16, CDH = 64, CDFF = 4096, CV = 2000, CM = 256;
constexpr int CNT = CB * CT; // 8192 tokens
constexpr float CDN = 0.35355339059327373f;   // 64^-0.25
constexpr float CRATIO = 0.0625f;             // 256^-0.5
constexpr float CKEPS = 1e-4f;

DEVFN unsigned short f2bu(float x) {
  __hip_bfloat16 h = __float2bfloat16(x);
  return __builtin_bit_cast(unsigned short, h);
}
DEVFN float b2f(unsigned short u) {
  __hip_bfloat16 h = __builtin_bit_cast(__hip_bfloat16, u);
  return __bfloat162float(h);
}
DEVFN float wredsum(float s) {
#pragma unroll
  for (int ofs = 32; ofs; ofs >>= 1) s += __shfl_xor(s, ofs, 64);
  return s;
}
DEVFN float wredmax(float s) {
#pragma unroll
  for (int ofs = 32; ofs; ofs >>= 1) s = fmaxf(s, __shfl_xor(s, ofs, 64));
  return s;
}
DEVFN void gl_lds16(const void* g, void* l) {
  __builtin_amdgcn_global_load_lds(
      (const __attribute__((address_space(1))) unsigned int*)g,
      (__attribute__((address_space(3))) unsigned int*)l, 16, 0, 0);
}
DEVFN f32x4 mfma16(u16x8 a, u16x8 b, f32x4 c) {
  return __builtin_amdgcn_mfma_f32_16x16x32_bf16(
      __builtin_bit_cast(bf16x8, a), __builtin_bit_cast(bf16x8, b), c, 0, 0, 0);
}

// ---------------- generic batched bf16 GEMM: C = A(M,K) * Bt(N,K)^T ----------------
#define EPI_BIAS 1
#define EPI_ACCUM 2
#define EPI_GELU 4
#define EPI_OUTBF 8
#define EPI_RSCALE 16

template <int EPI>
__global__ __launch_bounds__(256) void gemm_k(
    const unsigned short* __restrict__ Aall, const unsigned short* __restrict__ Btall,
    const float* __restrict__ bias, void* __restrict__ Call, const float* __restrict__ rsall,
    int Mr, int Nr, int Kr, int lda, int ldb, int ldc, int bdiv,
    long As1, long As2, long Bs1, long Bs2, long Cs1, long Cs2, long Rs1, long Rs2) {
  __shared__ unsigned short smA[128 * 32];
  __shared__ unsigned short smB[128 * 32];
  int bz = blockIdx.z;
  const unsigned short* A = Aall + (long)(bz / bdiv) * As1 + (long)(bz % bdiv) * As2;
  const unsigned short* Bt = Btall + (long)(bz / bdiv) * Bs1 + (long)(bz % bdiv) * Bs2;
  long coff = (long)(bz / bdiv) * Cs1 + (long)(bz % bdiv) * Cs2;
  const float* rs = nullptr;
  if (EPI & EPI_RSCALE) rs = rsall + (long)(bz / bdiv) * Rs1 + (long)(bz % bdiv) * Rs2;

  int tid = threadIdx.x, wv = tid >> 6, ll = tid & 63;
  int m0 = blockIdx.x * 128, n0 = blockIdx.y * 128;
  int sr = tid >> 2, sc = (tid & 3) * 8;
  long ar0 = min(m0 + sr, Mr - 1), ar1 = min(m0 + sr + 64, Mr - 1);
  long br0 = min(n0 + sr, Nr - 1), br1 = min(n0 + sr + 64, Nr - 1);
  unsigned short* lA0 = &smA[(wv * 16) * 32];       // wave-uniform LDS bases
  unsigned short* lA1 = &smA[(64 + wv * 16) * 32];
  unsigned short* lB0 = &smB[(wv * 16) * 32];
  unsigned short* lB1 = &smB[(64 + wv * 16) * 32];

  f32x4 acc[4][4] = {};
  int wr = (wv >> 1) * 64, wc = (wv & 1) * 64;
  int fr = ll & 15, fk = (ll >> 4) * 8;

  for (int k0 = 0; k0 < Kr; k0 += 32) {
    __syncthreads();
    gl_lds16(A + ar0 * lda + k0 + sc, lA0);
    gl_lds16(A + ar1 * lda + k0 + sc, lA1);
    gl_lds16(Bt + br0 * ldb + k0 + sc, lB0);
    gl_lds16(Bt + br1 * ldb + k0 + sc, lB1);
    __syncthreads();
    u16x8 af[4], bfr[4];
#pragma unroll
    for (int i = 0; i < 4; i++) {
      af[i] = *(const u16x8*)&smA[(wr + i * 16 + fr) * 32 + fk];
      bfr[i] = *(const u16x8*)&smB[(wc + i * 16 + fr) * 32 + fk];
    }
#pragma unroll
    for (int i = 0; i < 4; i++)
#pragma unroll
      for (int j = 0; j < 4; j++) acc[i][j] = mfma16(af[i], bfr[j], acc[i][j]);
  }

#pragma unroll
  for (int i = 0; i < 4; i++) {
#pragma unroll
    for (int j = 0; j < 4; j++) {
#pragma unroll
      for (int e = 0; e < 4; e++) {
        int gr = m0 + wr + i * 16 + (ll >> 4) * 4 + e;
        int gc = n0 + wc + j * 16 + (ll & 15);
        if (gr < Mr && gc < Nr) {
          float v = acc[i][j][e];
          if (EPI & EPI_BIAS) v += bias[gc];
          if (EPI & EPI_GELU) v = 0.5f * v * (1.0f + erff(v * 0.70710678118f));
          if (EPI & EPI_RSCALE) v *= rs[gr];
          long idx = coff + (long)gr * ldc + gc;
          if (EPI & EPI_ACCUM) v += ((float*)Call)[idx];
          if (EPI & EPI_OUTBF) ((unsigned short*)Call)[idx] = f2bu(v);
          else ((float*)Call)[idx] = v;
        }
      }
    }
  }
}

// ---------------- LayerNorm: fp32 in -> bf16 out ----------------
__global__ __launch_bounds__(256) void ln_k(const float* __restrict__ h,
                                            const float* __restrict__ g,
                                            const float* __restrict__ b,
                                            unsigned short* __restrict__ y) {
  int wv = threadIdx.x >> 6, ll = threadIdx.x & 63;
  long row = (long)blockIdx.x * 4 + wv;
  const float* hr = h + row * CDM;
  f32x4 x[4];
#pragma unroll
  for (int i = 0; i < 4; i++) x[i] = *(const f32x4*)&hr[ll * 16 + i * 4];
  float s = 0;
#pragma unroll
  for (int i = 0; i < 4; i++)
#pragma unroll
    for (int e = 0; e < 4; e++) s += x[i][e];
  float mu = wredsum(s) * (1.f / CDM);
  float v = 0;
#pragma unroll
  for (int i = 0; i < 4; i++)
#pragma unroll
    for (int e = 0; e < 4; e++) {
      float d = x[i][e] - mu;
      v += d * d;
    }
  float inv = rsqrtf(wredsum(v) * (1.f / CDM) + 1e-5f);
  unsigned short o[16];
#pragma unroll
  for (int i = 0; i < 4; i++)
#pragma unroll
    for (int e = 0; e < 4; e++) {
      int c = ll * 16 + i * 4 + e;
      o[i * 4 + e] = f2bu((x[i][e] - mu) * inv * g[c] + b[c]);
    }
  *(u16x8*)&y[row * CDM + ll * 16] = *(u16x8*)&o[0];
  *(u16x8*)&y[row * CDM + ll * 16 + 8] = *(u16x8*)&o[8];
}

// ---------------- FAVOR+ query features ----------------
__global__ __launch_bounds__(256) void featq_k(const float* __restrict__ dd,
                                               const unsigned short* __restrict__ qb,
                                               unsigned short* __restrict__ qp) {
  int wv = threadIdx.x >> 6, ll = threadIdx.x & 63;
  long gid = (long)blockIdx.x * 4 + wv;  // (b*H+h)*T + t
  long bh = gid >> 10;
  int t = gid & 1023;
  int b = bh >> 4, hh = bh & 15;
  const float* dr = dd + gid * CM;
  f32x4 d4 = *(const f32x4*)&dr[ll * 4];
  float qv = b2f(qb[((long)b * CT + t) * CDM + hh * CDH + ll]);
  float diag = wredsum(qv * qv) * (0.5f * CDN * CDN);
  float mx = fmaxf(fmaxf(d4[0], d4[1]), fmaxf(d4[2], d4[3]));
  mx = wredmax(mx);
  unsigned short o[4];
#pragma unroll
  for (int e = 0; e < 4; e++) o[e] = f2bu(CRATIO * (expf(d4[e] - diag - mx) + CKEPS));
  *(u16x4*)&qp[gid * CM + ll * 4] = *(u16x4*)&o[0];
}

// ---------------- key stabilizer partial max (per bh, 16 chunks) ----------------
__global__ __launch_bounds__(256) void stabp_k(const float* __restrict__ dd,
                                               float* __restrict__ part) {
  int bh = blockIdx.x >> 4, c = blockIdx.x & 15;
  const float* base = dd + ((long)bh * CT * CM) + (long)c * 16384;
  float mx = -3.4e38f;
#pragma unroll 4
  for (int it = 0; it < 16; it++) {
    f32x4 v = *(const f32x4*)&base[(it * 256 + threadIdx.x) * 4];
    mx = fmaxf(mx, fmaxf(fmaxf(v[0], v[1]), fmaxf(v[2], v[3])));
  }
  mx = wredmax(mx);
  __shared__ float sm[4];
  if ((threadIdx.x & 63) == 0) sm[threadIdx.x >> 6] = mx;
  __syncthreads();
  if (threadIdx.x == 0) part[blockIdx.x] = fmaxf(fmaxf(sm[0], sm[1]), fmaxf(sm[2], sm[3]));
}

// ---------------- key features, written transposed (B,H,M,T) ----------------
__global__ __launch_bounds__(256) void featk_k(const float* __restrict__ dd,
                                               const unsigned short* __restrict__ kb,
                                               const float* __restrict__ part,
                                               unsigned short* __restrict__ kpt) {
  int bh = blockIdx.x >> 5;
  int t0 = (blockIdx.x & 31) * 32;
  int b = bh >> 4, hh = bh & 15;
  float st = -3.4e38f;
#pragma unroll
  for (int i = 0; i < 16; i++) st = fmaxf(st, part[bh * 16 + i]);
  __shared__ unsigned short tile[32][256];
  int wv = threadIdx.x >> 6, ll = threadIdx.x & 63;
  for (int rr = 0; rr < 8; rr++) {
    int tr = wv * 8 + rr;
    int t = t0 + tr;
    const float* drr = dd + ((long)bh * CT + t) * CM;
    f32x4 d4 = *(const f32x4*)&drr[ll * 4];
    float kv = b2f(kb[((long)b * CT + t) * CDM + hh * CDH + ll]);
    float diag = wredsum(kv * kv) * (0.5f * CDN * CDN);
#pragma unroll
    for (int e = 0; e < 4; e++)
      tile[tr][ll * 4 + e] = f2bu(CRATIO * (expf(d4[e] - diag - st) + CKEPS));
  }
  __syncthreads();
#pragma unroll
  for (int p = 0; p < 4; p++) {
    int m = p * 64 + (threadIdx.x >> 2);
    int tz = (threadIdx.x & 3) * 8;
    unsigned short o[8];
#pragma unroll
    for (int e = 0; e < 8; e++) o[e] = tile[tz + e][m];
    *(u16x8*)&kpt[((long)bh * CM + m) * CT + t0 + tz] = *(u16x8*)&o[0];
  }
}

// ---------------- v (B,T,H,DH) -> v_t (B,H,DH,T) ----------------
__global__ __launch_bounds__(256) void trv_k(const unsigned short* __restrict__ vb,
                                             unsigned short* __restrict__ vt) {
  int bh = blockIdx.x >> 5;
  int t0 = (blockIdx.x & 31) * 32;
  int b = bh >> 4, hh = bh & 15;
  __shared__ unsigned short tile[32][64];
  int tr = threadIdx.x >> 3, dblk = (threadIdx.x & 7) * 8;
  *(u16x8*)&tile[tr][dblk] = *(const u16x8*)&vb[((long)b * CT + t0 + tr) * CDM + hh * CDH + dblk];
  __syncthreads();
  int d = threadIdx.x >> 2, tz = (threadIdx.x & 3) * 8;
  unsigned short o[8];
#pragma unroll
  for (int e = 0; e < 8; e++) o[e] = tile[tz + e][d];
  *(u16x8*)&vt[((long)bh * CDH + d) * CT + t0 + tz] = *(u16x8*)&o[0];
}

// ---------------- ksum[bh,m] = sum_t kp_t[bh,m,t] ----------------
__global__ __launch_bounds__(256) void ksum_k(const unsigned short* __restrict__ kpt,
                                              float* __restrict__ ksum) {
  int wv = threadIdx.x >> 6, ll = threadIdx.x & 63;
  long gid = (long)blockIdx.x * 4 + wv;  // bh*256+m
  const unsigned short* r = kpt + gid * CT;
  u16x8 a = *(const u16x8*)&r[ll * 16];
  u16x8 b = *(const u16x8*)&r[ll * 16 + 8];
  float s = 0;
#pragma unroll
  for (int e = 0; e < 8; e++) s += b2f(a[e]) + b2f(b[e]);
  s = wredsum(s);
  if (ll == 0) ksum[gid] = s;
}

// ---------------- dinv[bh,t] = 1 / (qp[bh,t,:] . ksum[bh,:]) ----------------
__global__ __launch_bounds__(256) void dinv_k(const unsigned short* __restrict__ qp,
                                              const float* __restrict__ ksum,
                                              float* __restrict__ dinv) {
  int wv = threadIdx.x >> 6, ll = threadIdx.x & 63;
  long gid = (long)blockIdx.x * 4 + wv;  // bh*T + t
  long bh = gid >> 10;
  const unsigned short* r = qp + gid * CM;
  const float* ks = ksum + bh * CM;
  u16x4 a = *(const u16x4*)&r[ll * 4];
  float s = 0;
#pragma unroll
  for (int e = 0; e < 4; e++) s += b2f(a[e]) * ks[ll * 4 + e];
  s = wredsum(s);
  if (ll == 0) dinv[gid] = 1.0f / s;
}

// ---------------- h += pe ----------------
__global__ __launch_bounds__(256) void addpe_k(float* __restrict__ h, const float* __restrict__ pe) {
  long i = ((long)blockIdx.x * 256 + threadIdx.x) * 4;
  int t = (int)((i >> 10) & 1023);
  int c = (int)(i & 1023);
  f32x4 v = *(f32x4*)&h[i];
  f32x4 p = *(const f32x4*)&pe[(long)t * 1024 + c];
  v += p;
  *(f32x4*)&h[i] = v;
}

// ---------------- fp32 -> bf16 flat ----------------
__global__ __launch_bounds__(256) void f2b_k(const float* __restrict__ in,
                                             unsigned short* __restrict__ out, long n) {
  long i = ((long)blockIdx.x * 256 + threadIdx.x) * 4;
  if (i >= n) return;
  f32x4 v = *(const f32x4*)&in[i];
  unsigned short o[4];
#pragma unroll
  for (int e = 0; e < 4; e++) o[e] = f2bu(v[e]);
  *(u16x4*)&out[i] = *(u16x4*)&o[0];
}

// ---------------- transpose-convert: in (R,C) fp32 -> out (C,R) bf16 ----------------
__global__ __launch_bounds__(256) void tconv_k(const float* __restrict__ in,
                                               unsigned short* __restrict__ out, int R, int C) {
  __shared__ float tile[32][33];
  int r0 = blockIdx.x * 32, c0 = blockIdx.y * 32;
  int tr = threadIdx.x >> 5, tc = threadIdx.x & 31;
#pragma unroll
  for (int p = 0; p < 4; p++) {
    int r = r0 + p * 8 + tr, c = c0 + tc;
    tile[p * 8 + tr][tc] = (r < R && c < C) ? in[(long)r * C + c] : 0.f;
  }
  __syncthreads();
#pragma unroll
  for (int p = 0; p < 4; p++) {
    int c = c0 + p * 8 + tr, r = r0 + tc;
    if (c < C && r < R) out[(long)c * R + r] = f2bu(tile[tc][p * 8 + tr]);
  }
}

// ---------------- Wconv (64,1024,3) -> per-tap (64,1024) bf16 ----------------
__global__ __launch_bounds__(256) void wconv_k(const float* __restrict__ W,
                                               unsigned short* __restrict__ out) {
  int idx = blockIdx.x * 256 + threadIdx.x;  // < 3*64*1024
  int r = idx >> 16, rem = idx & 65535, oc = rem >> 10, ic = rem & 1023;
  out[idx] = f2bu(W[oc * 3072 + ic * 3 + r]);
}

// ---------------- proj * dn -> bf16 ----------------
__global__ __launch_bounds__(256) void projc_k(const float* __restrict__ p,
                                               unsigned short* __restrict__ out) {
  int i = blockIdx.x * 256 + threadIdx.x;  // < 16384
  out[i] = f2bu(p[i] * CDN);
}

// ---------------- exact conv recompute at batch boundaries (t=0, t=T-1) ----------------
__global__ __launch_bounds__(256) void patch_k(const float* __restrict__ h,
                                               const float* __restrict__ W,
                                               const float* __restrict__ bc,
                                               float* __restrict__ xa) {
  int b = blockIdx.x >> 1;
  int t = (blockIdx.x & 1) ? (CT - 1) : 0;
  int oc = threadIdx.x & 63, ch = threadIdx.x >> 6;
  float s = 0;
  for (int r = 0; r < 3; r++) {
    int tt = t + r - 1;
    if (tt < 0 || tt >= CT) continue;
    const float* hr = h + ((long)b * CT + tt) * CDM;
    const float* wr = W + oc * 3072 + r;
    for (int ic = ch * 256; ic < ch * 256 + 256; ic++) s += hr[ic] * wr[ic * 3];
  }
  __shared__ float sm[256];
  sm[threadIdx.x] = s;
  __syncthreads();
  if (threadIdx.x < 64) {
    float tot = sm[oc] + sm[64 + oc] + sm[128 + oc] + sm[192 + oc] + bc[oc];
    xa[((long)b * CT + t) * 64 + oc] = tot;
  }
}

#define LAUNCH_GEMM(EPI, A, Bt, bias, C, rsp, Mr, Nr, Kr, lda, ldb, ldc, nb, bdiv, As1, As2, Bs1, Bs2, Cs1, Cs2, Rs1, Rs2) \
  gemm_k<EPI><<<dim3(((Mr) + 127) / 128, ((Nr) + 127) / 128, (nb)), 256, 0, stream>>>(           \
      (const unsigned short*)(A), (const unsigned short*)(Bt), (bias), (void*)(C), (rsp),        \
      (Mr), (Nr), (Kr), (lda), (ldb), (ldc), (bdiv), (long)(As1), (long)(As2), (long)(Bs1),      \
      (long)(Bs2), (long)(Cs1), (long)(Cs2), (long)(Rs1), (long)(Rs2))

extern "C" void kernel_launch(void* const* d_in, const int* in_sizes, int n_in,
                              void* d_out, int out_size, void* d_ws, size_t ws_size,
                              hipStream_t stream) {
  const float* x = (const float*)d_in[0];
  const float* Win = (const float*)d_in[1];
  const float* b_in = (const float*)d_in[2];
  const float* pe = (const float*)d_in[3];
  const float* ln1_g = (const float*)d_in[4];
  const float* ln1_b = (const float*)d_in[5];
  const float* Wq = (const float*)d_in[6];
  const float* bq = (const float*)d_in[7];
  const float* Wk = (const float*)d_in[8];
  const float* bk = (const float*)d_in[9];
  const float* Wv = (const float*)d_in[10];
  const float* bv = (const float*)d_in[11];
  const float* Wo = (const float*)d_in[12];
  const float* bo = (const float*)d_in[13];
  const float* ln2_g = (const float*)d_in[14];
  const float* ln2_b = (const float*)d_in[15];
  const float* W1 = (const float*)d_in[16];
  const float* b1 = (const float*)d_in[17];
  const float* W2 = (const float*)d_in[18];
  const float* b2 = (const float*)d_in[19];
  const float* Wc = (const float*)d_in[20];
  const float* bc = (const float*)d_in[21];
  const float* Wconv = (const float*)d_in[22];
  const float* bconv = (const float*)d_in[23];
  const float* Waux = (const float*)d_in[24];
  const float* baux = (const float*)d_in[25];
  const float* proj = (const float*)d_in[26];
  float* out = (float*)d_out;

  // ---- workspace carve-up (~437 MB) ----
  char* wsp = (char*)d_ws;
  size_t off = 0;
  auto take = [&](size_t bytes) {
    char* p = wsp + off;
    off = (off + bytes + 255) & ~(size_t)255;
    return p;
  };
  float* h_f = (float*)take(33554432);                      // (8192,1024) fp32 residual stream
  unsigned short* y_bf = (unsigned short*)take(16777216);   // LN out; also o_bf
  unsigned short* q_bf = (unsigned short*)take(16777216);   // also v_t after featq
  unsigned short* k_bf = (unsigned short*)take(16777216);
  unsigned short* v_bf = (unsigned short*)take(16777216);
  float* dd_f = (float*)take(134217728);                    // (B,H,T,M) fp32; also ff_bf
  unsigned short* qp_bf = (unsigned short*)take(67108864);  // (B,H,T,M)
  unsigned short* kpt_bf = (unsigned short*)take(67108864); // (B,H,M,T)
  unsigned short* ctx_bf = (unsigned short*)take(4194304);  // (B,H,DH,M)
  float* ksum_f = (float*)take(131072);
  float* dinv_f = (float*)take(524288);
  float* stab_f = (float*)take(8192);
  float* xa_f = (float*)take(2097152);
  unsigned short* xabf = (unsigned short*)take(1048576);
  take(65536);                                              // guard (conv r=0 reads before hbf)
  unsigned short* hbf = (unsigned short*)take(16777216);
  take(65536);                                              // guard (conv r=2 reads past hbf)
  unsigned short* xbf = (unsigned short*)take(4194304);
  unsigned short* win_t = (unsigned short*)take(524288);
  unsigned short* wqkvo_t = (unsigned short*)take(16777216);
  unsigned short* w1_t = (unsigned short*)take(16777216);
  unsigned short* w2_t = (unsigned short*)take(16777216);
  unsigned short* wc_t = (unsigned short*)take(4096000);
  unsigned short* projc = (unsigned short*)take(32768);
  unsigned short* wconv_t = (unsigned short*)take(393216);
  unsigned short* waux_t = (unsigned short*)take(256128);
  unsigned short* ff_bf = (unsigned short*)dd_f;  // alias: ff used after dd is dead
  unsigned short* vt_bf = q_bf;                   // alias: v_t written after q_bf dead
  unsigned short* o_bf = y_bf;                    // alias: o written after y_bf dead
  (void)in_sizes; (void)n_in; (void)out_size; (void)ws_size;

  // ---- weight conversion (per launch; deterministic) ----
  f2b_k<<<2048, 256, 0, stream>>>(x, xbf, (long)CNT * 256);
  tconv_k<<<dim3(8, 32), 256, 0, stream>>>(Win, win_t, 256, 1024);
  for (int l = 0; l < 2; l++) {
    tconv_k<<<dim3(32, 32), 256, 0, stream>>>(Wq + (long)l * 1048576, wqkvo_t + (long)(l * 4 + 0) * 1048576, 1024, 1024);
    tconv_k<<<dim3(32, 32), 256, 0, stream>>>(Wk + (long)l * 1048576, wqkvo_t + (long)(l * 4 + 1) * 1048576, 1024, 1024);
    tconv_k<<<dim3(32, 32), 256, 0, stream>>>(Wv + (long)l * 1048576, wqkvo_t + (long)(l * 4 + 2) * 1048576, 1024, 1024);
    tconv_k<<<dim3(32, 32), 256, 0, stream>>>(Wo + (long)l * 1048576, wqkvo_t + (long)(l * 4 + 3) * 1048576, 1024, 1024);
    tconv_k<<<dim3(32, 128), 256, 0, stream>>>(W1 + (long)l * 4194304, w1_t + (long)l * 4194304, 1024, 4096);
    tconv_k<<<dim3(128, 32), 256, 0, stream>>>(W2 + (long)l * 4194304, w2_t + (long)l * 4194304, 4096, 1024);
  }
  tconv_k<<<dim3(32, 63), 256, 0, stream>>>(Wc, wc_t, 1024, 2000);
  tconv_k<<<dim3(2, 63), 256, 0, stream>>>(Waux, waux_t, 64, 2001);
  wconv_k<<<768, 256, 0, stream>>>(Wconv, wconv_t);
  projc_k<<<64, 256, 0, stream>>>(proj, projc);

  // ---- embed ----
  LAUNCH_GEMM(EPI_BIAS, xbf, win_t, b_in, h_f, nullptr, CNT, CDM, 256, 256, 256, CDM, 1, 1, 0, 0, 0, 0, 0, 0, 0, 0);
  addpe_k<<<8192, 256, 0, stream>>>(h_f, pe);

  for (int l = 0; l < 2; l++) {
    const unsigned short* wq_t = wqkvo_t + (long)(l * 4 + 0) * 1048576;
    const unsigned short* wk_t = wqkvo_t + (long)(l * 4 + 1) * 1048576;
    const unsigned short* wv_t = wqkvo_t + (long)(l * 4 + 2) * 1048576;
    const unsigned short* wo_t = wqkvo_t + (long)(l * 4 + 3) * 1048576;

    ln_k<<<2048, 256, 0, stream>>>(h_f, ln1_g + l * CDM, ln1_b + l * CDM, y_bf);
    LAUNCH_GEMM(EPI_BIAS | EPI_OUTBF, y_bf, wq_t, bq + l * CDM, q_bf, nullptr, CNT, CDM, CDM, CDM, CDM, CDM, 1, 1, 0, 0, 0, 0, 0, 0, 0, 0);
    LAUNCH_GEMM(EPI_BIAS | EPI_OUTBF, y_bf, wk_t, bk + l * CDM, k_bf, nullptr, CNT, CDM, CDM, CDM, CDM, CDM, 1, 1, 0, 0, 0, 0, 0, 0, 0, 0);
    LAUNCH_GEMM(EPI_BIAS | EPI_OUTBF, y_bf, wv_t, bv + l * CDM, v_bf, nullptr, CNT, CDM, CDM, CDM, CDM, CDM, 1, 1, 0, 0, 0, 0, 0, 0, 0, 0);

    // dd = (q @ (proj*dn)^T), batched over (b,h)
    LAUNCH_GEMM(0, q_bf, projc, nullptr, dd_f, nullptr, CT, CM, CDH, CDM, CDH, CM, 128, CH,
                (long)CT * CDM, 64, 0, 0, (long)CH * CT * CM, (long)CT * CM, 0, 0);
    featq_k<<<32768, 256, 0, stream>>>(dd_f, q_bf, qp_bf);
    LAUNCH_GEMM(0, k_bf, projc, nullptr, dd_f, nullptr, CT, CM, CDH, CDM, CDH, CM, 128, CH,
                (long)CT * CDM, 64, 0, 0, (long)CH * CT * CM, (long)CT * CM, 0, 0);
    stabp_k<<<2048, 256, 0, stream>>>(dd_f, stab_f);
    featk_k<<<4096, 256, 0, stream>>>(dd_f, k_bf, stab_f, kpt_bf);
    trv_k<<<4096, 256, 0, stream>>>(v_bf, vt_bf);
    ksum_k<<<8192, 256, 0, stream>>>(kpt_bf, ksum_f);
    // ctx^T (DH,M) = v^T @ kp, batched
    LAUNCH_GEMM(EPI_OUTBF, vt_bf, kpt_bf, nullptr, ctx_bf, nullptr, CDH, CM, CT, CT, CT, CM, 128, CH,
                (long)CH * CDH * CT, (long)CDH * CT, (long)CH * CM * CT, (long)CM * CT,
                (long)CH * CDH * CM, (long)CDH * CM, 0, 0);
    dinv_k<<<32768, 256, 0, stream>>>(qp_bf, ksum_f, dinv_f);
    // o = (qp @ ctx) * dinv, written straight into (B,T,H*DH) bf16
    LAUNCH_GEMM(EPI_RSCALE | EPI_OUTBF, qp_bf, ctx_bf, nullptr, o_bf, dinv_f, CT, CDH, CM, CM, CM, CDM, 128, CH,
                (long)CH * CT * CM, (long)CT * CM, (long)CH * CDH * CM, (long)CDH * CM,
                (long)CT * CDM, 64, (long)CH * CT, (long)CT);
    LAUNCH_GEMM(EPI_BIAS | EPI_ACCUM, o_bf, wo_t, bo + l * CDM, h_f, nullptr, CNT, CDM, CDM, CDM, CDM, CDM, 1, 1, 0, 0, 0, 0, 0, 0, 0, 0);

    ln_k<<<2048, 256, 0, stream>>>(h_f, ln2_g + l * CDM, ln2_b + l * CDM, y_bf);
    LAUNCH_GEMM(EPI_BIAS | EPI_GELU | EPI_OUTBF, y_bf, w1_t + (long)l * 4194304, b1 + l * CDFF, ff_bf, nullptr,
                CNT, CDFF, CDM, CDM, CDM, CDFF, 1, 1, 0, 0, 0, 0, 0, 0, 0, 0);
    LAUNCH_GEMM(EPI_BIAS | EPI_ACCUM, ff_bf, w2_t + (long)l * 4194304, b2 + l * CDM, h_f, nullptr,
                CNT, CDM, CDFF, CDFF, CDFF, CDM, 1, 1, 0, 0, 0, 0, 0, 0, 0, 0);

    if (l == 0) {
      // conv1d over channels + aux head, from layer-0 output h
      f2b_k<<<8192, 256, 0, stream>>>(h_f, hbf, (long)CNT * CDM);
      LAUNCH_GEMM(0, hbf - CDM, wconv_t + 0 * 65536, nullptr, xa_f, nullptr, CNT, 64, CDM, CDM, CDM, 64, 1, 1, 0, 0, 0, 0, 0, 0, 0, 0);
      LAUNCH_GEMM(EPI_ACCUM, hbf, wconv_t + 1 * 65536, nullptr, xa_f, nullptr, CNT, 64, CDM, CDM, CDM, 64, 1, 1, 0, 0, 0, 0, 0, 0, 0, 0);
      LAUNCH_GEMM(EPI_BIAS | EPI_ACCUM, hbf + CDM, wconv_t + 2 * 65536, bconv, xa_f, nullptr, CNT, 64, CDM, CDM, CDM, 64, 1, 1, 0, 0, 0, 0, 0, 0, 0, 0);
      patch_k<<<16, 256, 0, stream>>>(h_f, Wconv, bconv, xa_f);
      f2b_k<<<512, 256, 0, stream>>>(xa_f, xabf, (long)CNT * 64);
      LAUNCH_GEMM(EPI_BIAS, xabf, waux_t, baux, out + 16384000, nullptr, CNT, CV + 1, 64, 64, 64, CV + 1, 1, 1, 0, 0, 0, 0, 0, 0, 0, 0);
    }
  }

  // ---- classifier ----
  f2b_k<<<8192, 256, 0, stream>>>(h_f, hbf, (long)CNT * CDM);
  LAUNCH_GEMM(EPI_BIAS, hbf, wc_t, bc, out, nullptr, CNT, CV, CDM, CDM, CDM, CV, 1, 1, 0, 0, 0, 0, 0, 0, 0, 0);
}

// Round 2
// 1884.200 us; speedup vs baseline: 1.0112x; 1.0112x over previous
//
#include <hip/hip_runtime.h>
#include <hip/hip_bf16.h>

typedef __attribute__((ext_vector_type(4))) float f32x4;
typedef __attribute__((ext_vector_type(8))) unsigned short u16x8;
typedef __attribute__((ext_vector_type(4))) unsigned short u16x4;
typedef __bf16 bf16x8 __attribute__((ext_vector_type(8)));

#define DEVFN static __device__ __forceinline__

constexpr int CB = 8, CT = 1024, CDM = 1024, CH = 16, CDH = 64, CDFF = 4096, CV = 2000, CM = 256;
constexpr int CNT = CB * CT; // 8192 tokens
constexpr int CQKV = 3072;   // fused qkv row stride
constexpr float CDN = 0.35355339059327373f;   // 64^-0.25
constexpr float CRATIO = 0.0625f;             // 256^-0.5
constexpr float CKEPS = 1e-4f;

DEVFN unsigned short f2bu(float x) {
  __hip_bfloat16 h = __float2bfloat16(x);
  return __builtin_bit_cast(unsigned short, h);
}
DEVFN float b2f(unsigned short u) {
  __hip_bfloat16 h = __builtin_bit_cast(__hip_bfloat16, u);
  return __bfloat162float(h);
}
DEVFN float wredsum(float s) {
#pragma unroll
  for (int ofs = 32; ofs; ofs >>= 1) s += __shfl_xor(s, ofs, 64);
  return s;
}
DEVFN float wredmax(float s) {
#pragma unroll
  for (int ofs = 32; ofs; ofs >>= 1) s = fmaxf(s, __shfl_xor(s, ofs, 64));
  return s;
}
DEVFN void gl_lds16(const void* g, void* l) {
  __builtin_amdgcn_global_load_lds(
      (const __attribute__((address_space(1))) unsigned int*)g,
      (__attribute__((address_space(3))) unsigned int*)l, 16, 0, 0);
}
DEVFN f32x4 mfma16(u16x8 a, u16x8 b, f32x4 c) {
  return __builtin_amdgcn_mfma_f32_16x16x32_bf16(
      __builtin_bit_cast(bf16x8, a), __builtin_bit_cast(bf16x8, b), c, 0, 0, 0);
}

#define EPI_BIAS 1
#define EPI_ACCUM 2
#define EPI_GELU 4
#define EPI_OUTBF 8
#define EPI_RSCALE 16

// ================= 8-phase-style big GEMM: C = A(M,K) * Bt(N,K)^T =================
// TMx x 256 tile, BK=64, 8 waves (2Mx4N), 2 LDS buffers, st_16x32 XOR swizzle,
// counted vmcnt(2) (never drained in loop), raw s_barrier, setprio around MFMA.
template <int TMx, int EPI>
__global__ __launch_bounds__(512, 2) void gemm8_k(
    const unsigned short* __restrict__ A, const unsigned short* __restrict__ Bt,
    const float* __restrict__ bias, void* __restrict__ C,
    int Mr, int Nr, int Kr, int lda, int ldb, int ldc) {
  constexpr int AR = TMx * 64 / 4096;  // A staging rounds (4 or 2)
  constexpr int BR = 4;                // B staging rounds
  constexpr int ST = AR + BR;
  constexpr int MREP = TMx / 32;       // per-wave m-fragments (8 or 4)
  __shared__ unsigned short smA[2][TMx * 64];
  __shared__ unsigned short smB[2][256 * 64];

  int tid = threadIdx.x, wv = tid >> 6, ll = tid & 63;
  int wm = wv >> 2, wn = wv & 3;  // 2 x 4 wave grid
  int m0 = blockIdx.x * TMx, n0 = blockIdx.y * 256;
  int fr = ll & 15, f16 = ll >> 4, fk = f16 * 8;

  const char* Ab = (const char*)A;
  const char* Bb = (const char*)Bt;

  // staging source byte offsets (inverse-swizzled so linear LDS dest + swizzled read match)
  unsigned int offA[AR], offB[BR];
#pragma unroll
  for (int ro = 0; ro < AR; ro++) {
    int L = (ro * 512 + tid) * 16;
    int P = L ^ (((L >> 9) & 1) << 5);
    int kh = P / (TMx * 64), rem = P % (TMx * 64);
    int r = rem >> 6, cb = rem & 63;
    long row = min(m0 + r, Mr - 1);
    offA[ro] = (unsigned int)((row * lda + kh * 32) * 2 + cb);
  }
#pragma unroll
  for (int ro = 0; ro < BR; ro++) {
    int L = (ro * 512 + tid) * 16;
    int P = L ^ (((L >> 9) & 1) << 5);
    int kh = P / 16384, rem = P & 16383;
    int r = rem >> 6, cb = rem & 63;
    long row = min(n0 + r, Nr - 1);
    offB[ro] = (unsigned int)((row * ldb + kh * 32) * 2 + cb);
  }
  // fragment LDS offsets (shorts), swizzled
  int loA[MREP][2], loB[4][2];
#pragma unroll
  for (int i = 0; i < MREP; i++)
#pragma unroll
    for (int ks = 0; ks < 2; ks++) {
      int r = wm * (TMx / 2) + i * 16 + fr;
      loA[i][ks] = ks * TMx * 32 + r * 32 + (fk ^ (((r >> 3) & 1) << 4));
    }
#pragma unroll
  for (int j = 0; j < 4; j++)
#pragma unroll
    for (int ks = 0; ks < 2; ks++) {
      int r = wn * 64 + j * 16 + fr;
      loB[j][ks] = ks * 8192 + r * 32 + (fk ^ (((r >> 3) & 1) << 4));
    }

#define STG(bp, ph, kb2)                                                        \
  {                                                                             \
    _Pragma("unroll") for (int ro = (ph); ro < ST; ro += 4) {                   \
      if (ro < AR)                                                              \
        gl_lds16(Ab + offA[ro] + (kb2), &smA[bp][(ro * 512 + wv * 64) * 8]);    \
      else                                                                      \
        gl_lds16(Bb + offB[ro - AR] + (kb2),                                    \
                 &smB[bp][((ro - AR) * 512 + wv * 64) * 8]);                    \
    }                                                                           \
  }
#define RDA(bp, ks)                                                             \
  { _Pragma("unroll") for (int i = 0; i < MREP; i++)                            \
      afr[i] = *(const u16x8*)&smA[bp][loA[i][ks]]; }
#define RDB2(bp, ks, jh)                                                        \
  {                                                                             \
    bq0 = *(const u16x8*)&smB[bp][loB[(jh) * 2][ks]];                           \
    bq1 = *(const u16x8*)&smB[bp][loB[(jh) * 2 + 1][ks]];                       \
  }
#define MFQ(jh)                                                                 \
  { _Pragma("unroll") for (int i = 0; i < MREP; i++) {                          \
      acc[i][(jh) * 2] = mfma16(afr[i], bq0, acc[i][(jh) * 2]);                 \
      acc[i][(jh) * 2 + 1] = mfma16(afr[i], bq1, acc[i][(jh) * 2 + 1]);         \
    } }
#define SBAR()                                                                  \
  {                                                                             \
    __builtin_amdgcn_s_barrier();                                               \
    __builtin_amdgcn_sched_barrier(0);                                          \
  }

  f32x4 acc[MREP][4] = {};
  int NT = Kr / 64;

  // prologue: stage tile 0 into buf 0
#pragma unroll
  for (int ro = 0; ro < ST; ro++) {
    if (ro < AR)
      gl_lds16(Ab + offA[ro], &smA[0][(ro * 512 + wv * 64) * 8]);
    else
      gl_lds16(Bb + offB[ro - AR], &smB[0][((ro - AR) * 512 + wv * 64) * 8]);
  }

  int p = 0;
  for (int t = 0; t < NT; t++) {
    long kbn = (long)((t + 1 < NT) ? t + 1 : t) * 128;  // next-tile K byte offset (clamped; dangling loads harmless)
    u16x8 afr[MREP], bq0, bq1;
    // ---- phase 0: stage, counted wait, tile-ready barrier, ks=0 / cols 0-31 ----
    STG(p ^ 1, 0, kbn);
    asm volatile("s_waitcnt vmcnt(2)" ::: "memory");
    SBAR();
    RDA(p, 0);
    RDB2(p, 0, 0);
    __builtin_amdgcn_s_setprio(1);
    MFQ(0);
    __builtin_amdgcn_s_setprio(0);
    SBAR();
    // ---- phase 1: ks=0 / cols 32-63 ----
    RDB2(p, 0, 1);
    STG(p ^ 1, 1, kbn);
    SBAR();
    __builtin_amdgcn_s_setprio(1);
    MFQ(1);
    __builtin_amdgcn_s_setprio(0);
    SBAR();
    // ---- phase 2: ks=1 / cols 0-31 ----
    RDA(p, 1);
    RDB2(p, 1, 0);
    STG(p ^ 1, 2, kbn);
    SBAR();
    __builtin_amdgcn_s_setprio(1);
    MFQ(0);
    __builtin_amdgcn_s_setprio(0);
    SBAR();
    // ---- phase 3: ks=1 / cols 32-63 ----
    RDB2(p, 1, 1);
    STG(p ^ 1, 3, kbn);
    SBAR();
    __builtin_amdgcn_s_setprio(1);
    MFQ(1);
    __builtin_amdgcn_s_setprio(0);
    SBAR();
    p ^= 1;
  }

  // ---- epilogue ----
#pragma unroll
  for (int i = 0; i < MREP; i++) {
#pragma unroll
    for (int j = 0; j < 4; j++) {
#pragma unroll
      for (int e = 0; e < 4; e++) {
        int gr = m0 + wm * (TMx / 2) + i * 16 + f16 * 4 + e;
        int gc = n0 + wn * 64 + j * 16 + fr;
        if (gr < Mr && gc < Nr) {
          float v = acc[i][j][e];
          if (EPI & EPI_BIAS) v += bias[gc];
          if (EPI & EPI_GELU) v = 0.5f * v * (1.0f + erff(v * 0.70710678118f));
          long idx = (long)gr * ldc + gc;
          if (EPI & EPI_ACCUM) v += ((float*)C)[idx];
          if (EPI & EPI_OUTBF) ((unsigned short*)C)[idx] = f2bu(v);
          else ((float*)C)[idx] = v;
        }
      }
    }
  }
#undef STG
#undef RDA
#undef RDB2
#undef MFQ
#undef SBAR
}

// ================= legacy 128x128 GEMM (small/batched shapes) =================
template <int EPI>
__global__ __launch_bounds__(256) void gemm_k(
    const unsigned short* __restrict__ Aall, const unsigned short* __restrict__ Btall,
    const float* __restrict__ bias, void* __restrict__ Call, const float* __restrict__ rsall,
    int Mr, int Nr, int Kr, int lda, int ldb, int ldc, int bdiv,
    long As1, long As2, long Bs1, long Bs2, long Cs1, long Cs2, long Rs1, long Rs2) {
  __shared__ unsigned short smA[128 * 32];
  __shared__ unsigned short smB[128 * 32];
  int bz = blockIdx.z;
  const unsigned short* A = Aall + (long)(bz / bdiv) * As1 + (long)(bz % bdiv) * As2;
  const unsigned short* Bt = Btall + (long)(bz / bdiv) * Bs1 + (long)(bz % bdiv) * Bs2;
  long coff = (long)(bz / bdiv) * Cs1 + (long)(bz % bdiv) * Cs2;
  const float* rs = nullptr;
  if (EPI & EPI_RSCALE) rs = rsall + (long)(bz / bdiv) * Rs1 + (long)(bz % bdiv) * Rs2;

  int tid = threadIdx.x, wv = tid >> 6, ll = tid & 63;
  int m0 = blockIdx.x * 128, n0 = blockIdx.y * 128;
  int sr = tid >> 2, sc = (tid & 3) * 8;
  long ar0 = min(m0 + sr, Mr - 1), ar1 = min(m0 + sr + 64, Mr - 1);
  long br0 = min(n0 + sr, Nr - 1), br1 = min(n0 + sr + 64, Nr - 1);
  unsigned short* lA0 = &smA[(wv * 16) * 32];
  unsigned short* lA1 = &smA[(64 + wv * 16) * 32];
  unsigned short* lB0 = &smB[(wv * 16) * 32];
  unsigned short* lB1 = &smB[(64 + wv * 16) * 32];

  f32x4 acc[4][4] = {};
  int wr = (wv >> 1) * 64, wc = (wv & 1) * 64;
  int fr = ll & 15, fk = (ll >> 4) * 8;

  for (int k0 = 0; k0 < Kr; k0 += 32) {
    __syncthreads();
    gl_lds16(A + ar0 * lda + k0 + sc, lA0);
    gl_lds16(A + ar1 * lda + k0 + sc, lA1);
    gl_lds16(Bt + br0 * ldb + k0 + sc, lB0);
    gl_lds16(Bt + br1 * ldb + k0 + sc, lB1);
    __syncthreads();
    u16x8 af[4], bfr[4];
#pragma unroll
    for (int i = 0; i < 4; i++) {
      af[i] = *(const u16x8*)&smA[(wr + i * 16 + fr) * 32 + fk];
      bfr[i] = *(const u16x8*)&smB[(wc + i * 16 + fr) * 32 + fk];
    }
#pragma unroll
    for (int i = 0; i < 4; i++)
#pragma unroll
      for (int j = 0; j < 4; j++) acc[i][j] = mfma16(af[i], bfr[j], acc[i][j]);
  }

#pragma unroll
  for (int i = 0; i < 4; i++) {
#pragma unroll
    for (int j = 0; j < 4; j++) {
#pragma unroll
      for (int e = 0; e < 4; e++) {
        int gr = m0 + wr + i * 16 + (ll >> 4) * 4 + e;
        int gc = n0 + wc + j * 16 + (ll & 15);
        if (gr < Mr && gc < Nr) {
          float v = acc[i][j][e];
          if (EPI & EPI_BIAS) v += bias[gc];
          if (EPI & EPI_GELU) v = 0.5f * v * (1.0f + erff(v * 0.70710678118f));
          if (EPI & EPI_RSCALE) v *= rs[gr];
          long idx = coff + (long)gr * ldc + gc;
          if (EPI & EPI_ACCUM) v += ((float*)Call)[idx];
          if (EPI & EPI_OUTBF) ((unsigned short*)Call)[idx] = f2bu(v);
          else ((float*)Call)[idx] = v;
        }
      }
    }
  }
}

// ---------------- LayerNorm: fp32 in -> bf16 out ----------------
__global__ __launch_bounds__(256) void ln_k(const float* __restrict__ h,
                                            const float* __restrict__ g,
                                            const float* __restrict__ b,
                                            unsigned short* __restrict__ y) {
  int wv = threadIdx.x >> 6, ll = threadIdx.x & 63;
  long row = (long)blockIdx.x * 4 + wv;
  const float* hr = h + row * CDM;
  f32x4 x[4];
#pragma unroll
  for (int i = 0; i < 4; i++) x[i] = *(const f32x4*)&hr[ll * 16 + i * 4];
  float s = 0;
#pragma unroll
  for (int i = 0; i < 4; i++)
#pragma unroll
    for (int e = 0; e < 4; e++) s += x[i][e];
  float mu = wredsum(s) * (1.f / CDM);
  float v = 0;
#pragma unroll
  for (int i = 0; i < 4; i++)
#pragma unroll
    for (int e = 0; e < 4; e++) {
      float d = x[i][e] - mu;
      v += d * d;
    }
  float inv = rsqrtf(wredsum(v) * (1.f / CDM) + 1e-5f);
  unsigned short o[16];
#pragma unroll
  for (int i = 0; i < 4; i++)
#pragma unroll
    for (int e = 0; e < 4; e++) {
      int c = ll * 16 + i * 4 + e;
      o[i * 4 + e] = f2bu((x[i][e] - mu) * inv * g[c] + b[c]);
    }
  *(u16x8*)&y[row * CDM + ll * 16] = *(u16x8*)&o[0];
  *(u16x8*)&y[row * CDM + ll * 16 + 8] = *(u16x8*)&o[8];
}

// ---------------- FAVOR+ query features (q from fused qkv, stride 3072) ----------------
__global__ __launch_bounds__(256) void featq_k(const float* __restrict__ dd,
                                               const unsigned short* __restrict__ qb,
                                               unsigned short* __restrict__ qp) {
  int wv = threadIdx.x >> 6, ll = threadIdx.x & 63;
  long gid = (long)blockIdx.x * 4 + wv;  // (b*H+h)*T + t
  long bh = gid >> 10;
  int t = gid & 1023;
  int b = bh >> 4, hh = bh & 15;
  const float* dr = dd + gid * CM;
  f32x4 d4 = *(const f32x4*)&dr[ll * 4];
  float qv = b2f(qb[((long)b * CT + t) * CQKV + hh * CDH + ll]);
  float diag = wredsum(qv * qv) * (0.5f * CDN * CDN);
  float mx = fmaxf(fmaxf(d4[0], d4[1]), fmaxf(d4[2], d4[3]));
  mx = wredmax(mx);
  unsigned short o[4];
#pragma unroll
  for (int e = 0; e < 4; e++) o[e] = f2bu(CRATIO * (expf(d4[e] - diag - mx) + CKEPS));
  *(u16x4*)&qp[gid * CM + ll * 4] = *(u16x4*)&o[0];
}

// ---------------- key stabilizer partial max ----------------
__global__ __launch_bounds__(256) void stabp_k(const float* __restrict__ dd,
                                               float* __restrict__ part) {
  int bh = blockIdx.x >> 4, c = blockIdx.x & 15;
  const float* base = dd + ((long)bh * CT * CM) + (long)c * 16384;
  float mx = -3.4e38f;
#pragma unroll 4
  for (int it = 0; it < 16; it++) {
    f32x4 v = *(const f32x4*)&base[(it * 256 + threadIdx.x) * 4];
    mx = fmaxf(mx, fmaxf(fmaxf(v[0], v[1]), fmaxf(v[2], v[3])));
  }
  mx = wredmax(mx);
  __shared__ float sm[4];
  if ((threadIdx.x & 63) == 0) sm[threadIdx.x >> 6] = mx;
  __syncthreads();
  if (threadIdx.x == 0) part[blockIdx.x] = fmaxf(fmaxf(sm[0], sm[1]), fmaxf(sm[2], sm[3]));
}

// ---------------- key features, transposed out (k from fused qkv) ----------------
__global__ __launch_bounds__(256) void featk_k(const float* __restrict__ dd,
                                               const unsigned short* __restrict__ kb,
                                               const float* __restrict__ part,
                                               unsigned short* __restrict__ kpt) {
  int bh = blockIdx.x >> 5;
  int t0 = (blockIdx.x & 31) * 32;
  int b = bh >> 4, hh = bh & 15;
  float st = -3.4e38f;
#pragma unroll
  for (int i = 0; i < 16; i++) st = fmaxf(st, part[bh * 16 + i]);
  __shared__ unsigned short tile[32][256];
  int wv = threadIdx.x >> 6, ll = threadIdx.x & 63;
  for (int rr = 0; rr < 8; rr++) {
    int tr = wv * 8 + rr;
    int t = t0 + tr;
    const float* drr = dd + ((long)bh * CT + t) * CM;
    f32x4 d4 = *(const f32x4*)&drr[ll * 4];
    float kv = b2f(kb[((long)b * CT + t) * CQKV + hh * CDH + ll]);
    float diag = wredsum(kv * kv) * (0.5f * CDN * CDN);
#pragma unroll
    for (int e = 0; e < 4; e++)
      tile[tr][ll * 4 + e] = f2bu(CRATIO * (expf(d4[e] - diag - st) + CKEPS));
  }
  __syncthreads();
#pragma unroll
  for (int p = 0; p < 4; p++) {
    int m = p * 64 + (threadIdx.x >> 2);
    int tz = (threadIdx.x & 3) * 8;
    unsigned short o[8];
#pragma unroll
    for (int e = 0; e < 8; e++) o[e] = tile[tz + e][m];
    *(u16x8*)&kpt[((long)bh * CM + m) * CT + t0 + tz] = *(u16x8*)&o[0];
  }
}

// ---------------- v (from fused qkv) -> v_t (B,H,DH,T) ----------------
__global__ __launch_bounds__(256) void trv_k(const unsigned short* __restrict__ vb,
                                             unsigned short* __restrict__ vt) {
  int bh = blockIdx.x >> 5;
  int t0 = (blockIdx.x & 31) * 32;
  int b = bh >> 4, hh = bh & 15;
  __shared__ unsigned short tile[32][64];
  int tr = threadIdx.x >> 3, dblk = (threadIdx.x & 7) * 8;
  *(u16x8*)&tile[tr][dblk] = *(const u16x8*)&vb[((long)b * CT + t0 + tr) * CQKV + hh * CDH + dblk];
  __syncthreads();
  int d = threadIdx.x >> 2, tz = (threadIdx.x & 3) * 8;
  unsigned short o[8];
#pragma unroll
  for (int e = 0; e < 8; e++) o[e] = tile[tz + e][d];
  *(u16x8*)&vt[((long)bh * CDH + d) * CT + t0 + tz] = *(u16x8*)&o[0];
}

// ---------------- ksum[bh,m] = sum_t kp_t[bh,m,t] ----------------
__global__ __launch_bounds__(256) void ksum_k(const unsigned short* __restrict__ kpt,
                                              float* __restrict__ ksum) {
  int wv = threadIdx.x >> 6, ll = threadIdx.x & 63;
  long gid = (long)blockIdx.x * 4 + wv;
  const unsigned short* r = kpt + gid * CT;
  u16x8 a = *(const u16x8*)&r[ll * 16];
  u16x8 b = *(const u16x8*)&r[ll * 16 + 8];
  float s = 0;
#pragma unroll
  for (int e = 0; e < 8; e++) s += b2f(a[e]) + b2f(b[e]);
  s = wredsum(s);
  if (ll == 0) ksum[gid] = s;
}

// ---------------- dinv[bh,t] = 1 / (qp . ksum) ----------------
__global__ __launch_bounds__(256) void dinv_k(const unsigned short* __restrict__ qp,
                                              const float* __restrict__ ksum,
                                              float* __restrict__ dinv) {
  int wv = threadIdx.x >> 6, ll = threadIdx.x & 63;
  long gid = (long)blockIdx.x * 4 + wv;
  long bh = gid >> 10;
  const unsigned short* r = qp + gid * CM;
  const float* ks = ksum + bh * CM;
  u16x4 a = *(const u16x4*)&r[ll * 4];
  float s = 0;
#pragma unroll
  for (int e = 0; e < 4; e++) s += b2f(a[e]) * ks[ll * 4 + e];
  s = wredsum(s);
  if (ll == 0) dinv[gid] = 1.0f / s;
}

// ---------------- h += pe ----------------
__global__ __launch_bounds__(256) void addpe_k(float* __restrict__ h, const float* __restrict__ pe) {
  long i = ((long)blockIdx.x * 256 + threadIdx.x) * 4;
  int t = (int)((i >> 10) & 1023);
  int c = (int)(i & 1023);
  f32x4 v = *(f32x4*)&h[i];
  f32x4 p = *(const f32x4*)&pe[(long)t * 1024 + c];
  v += p;
  *(f32x4*)&h[i] = v;
}

// ---------------- fp32 -> bf16 flat ----------------
__global__ __launch_bounds__(256) void f2b_k(const float* __restrict__ in,
                                             unsigned short* __restrict__ out, long n) {
  long i = ((long)blockIdx.x * 256 + threadIdx.x) * 4;
  if (i >= n) return;
  f32x4 v = *(const f32x4*)&in[i];
  unsigned short o[4];
#pragma unroll
  for (int e = 0; e < 4; e++) o[e] = f2bu(v[e]);
  *(u16x4*)&out[i] = *(u16x4*)&o[0];
}

// ---------------- transpose-convert: in (R,C) fp32 -> out (C,R) bf16 ----------------
__global__ __launch_bounds__(256) void tconv_k(const float* __restrict__ in,
                                               unsigned short* __restrict__ out, int R, int C) {
  __shared__ float tile[32][33];
  int r0 = blockIdx.x * 32, c0 = blockIdx.y * 32;
  int tr = threadIdx.x >> 5, tc = threadIdx.x & 31;
#pragma unroll
  for (int p = 0; p < 4; p++) {
    int r = r0 + p * 8 + tr, c = c0 + tc;
    tile[p * 8 + tr][tc] = (r < R && c < C) ? in[(long)r * C + c] : 0.f;
  }
  __syncthreads();
#pragma unroll
  for (int p = 0; p < 4; p++) {
    int c = c0 + p * 8 + tr, r = r0 + tc;
    if (c < C && r < R) out[(long)c * R + r] = f2bu(tile[tc][p * 8 + tr]);
  }
}

// ---------------- Wconv (64,1024,3) -> per-tap (64,1024) bf16 ----------------
__global__ __launch_bounds__(256) void wconv_k(const float* __restrict__ W,
                                               unsigned short* __restrict__ out) {
  int idx = blockIdx.x * 256 + threadIdx.x;
  int r = idx >> 16, rem = idx & 65535, oc = rem >> 10, ic = rem & 1023;
  out[idx] = f2bu(W[oc * 3072 + ic * 3 + r]);
}

// ---------------- proj * dn -> bf16 ----------------
__global__ __launch_bounds__(256) void projc_k(const float* __restrict__ p,
                                               unsigned short* __restrict__ out) {
  int i = blockIdx.x * 256 + threadIdx.x;
  out[i] = f2bu(p[i] * CDN);
}

// ---------------- concat q/k/v biases ----------------
__global__ __launch_bounds__(256) void catb_k(const float* __restrict__ q,
                                              const float* __restrict__ k,
                                              const float* __restrict__ v,
                                              float* __restrict__ o) {
  int i = blockIdx.x * 256 + threadIdx.x;  // < 3072
  o[i] = i < 1024 ? q[i] : (i < 2048 ? k[i - 1024] : v[i - 2048]);
}

// ---------------- exact conv recompute at batch boundaries ----------------
__global__ __launch_bounds__(256) void patch_k(const float* __restrict__ h,
                                               const float* __restrict__ W,
                                               const float* __restrict__ bc,
                                               float* __restrict__ xa) {
  int b = blockIdx.x >> 1;
  int t = (blockIdx.x & 1) ? (CT - 1) : 0;
  int oc = threadIdx.x & 63, ch = threadIdx.x >> 6;
  float s = 0;
  for (int r = 0; r < 3; r++) {
    int tt = t + r - 1;
    if (tt < 0 || tt >= CT) continue;
    const float* hr = h + ((long)b * CT + tt) * CDM;
    const float* wr = W + oc * 3072 + r;
    for (int ic = ch * 256; ic < ch * 256 + 256; ic++) s += hr[ic] * wr[ic * 3];
  }
  __shared__ float sm[256];
  sm[threadIdx.x] = s;
  __syncthreads();
  if (threadIdx.x < 64) {
    float tot = sm[oc] + sm[64 + oc] + sm[128 + oc] + sm[192 + oc] + bc[oc];
    xa[((long)b * CT + t) * 64 + oc] = tot;
  }
}

#define LAUNCH_GEMM(EPI, A, Bt, bias, C, rsp, Mr, Nr, Kr, lda, ldb, ldc, nb, bdiv, As1, As2, Bs1, Bs2, Cs1, Cs2, Rs1, Rs2) \
  gemm_k<EPI><<<dim3(((Mr) + 127) / 128, ((Nr) + 127) / 128, (nb)), 256, 0, stream>>>(           \
      (const unsigned short*)(A), (const unsigned short*)(Bt), (bias), (void*)(C), (rsp),        \
      (Mr), (Nr), (Kr), (lda), (ldb), (ldc), (bdiv), (long)(As1), (long)(As2), (long)(Bs1),      \
      (long)(Bs2), (long)(Cs1), (long)(Cs2), (long)(Rs1), (long)(Rs2))

#define LAUNCH_G8(TMX, EPI, A, Bt, bias, C, Mr, Nr, Kr, lda, ldb, ldc)                           \
  gemm8_k<TMX, EPI><<<dim3(((Mr) + (TMX)-1) / (TMX), ((Nr) + 255) / 256), 512, 0, stream>>>(     \
      (const unsigned short*)(A), (const unsigned short*)(Bt), (bias), (void*)(C),               \
      (Mr), (Nr), (Kr), (lda), (ldb), (ldc))

extern "C" void kernel_launch(void* const* d_in, const int* in_sizes, int n_in,
                              void* d_out, int out_size, void* d_ws, size_t ws_size,
                              hipStream_t stream) {
  const float* x = (const float*)d_in[0];
  const float* Win = (const float*)d_in[1];
  const float* b_in = (const float*)d_in[2];
  const float* pe = (const float*)d_in[3];
  const float* ln1_g = (const float*)d_in[4];
  const float* ln1_b = (const float*)d_in[5];
  const float* Wq = (const float*)d_in[6];
  const float* bq = (const float*)d_in[7];
  const float* Wk = (const float*)d_in[8];
  const float* bk = (const float*)d_in[9];
  const float* Wv = (const float*)d_in[10];
  const float* bv = (const float*)d_in[11];
  const float* Wo = (const float*)d_in[12];
  const float* bo = (const float*)d_in[13];
  const float* ln2_g = (const float*)d_in[14];
  const float* ln2_b = (const float*)d_in[15];
  const float* W1 = (const float*)d_in[16];
  const float* b1 = (const float*)d_in[17];
  const float* W2 = (const float*)d_in[18];
  const float* b2 = (const float*)d_in[19];
  const float* Wc = (const float*)d_in[20];
  const float* bc = (const float*)d_in[21];
  const float* Wconv = (const float*)d_in[22];
  const float* bconv = (const float*)d_in[23];
  const float* Waux = (const float*)d_in[24];
  const float* baux = (const float*)d_in[25];
  const float* proj = (const float*)d_in[26];
  float* out = (float*)d_out;

  char* wsp = (char*)d_ws;
  size_t off = 0;
  auto take = [&](size_t bytes) {
    char* p = wsp + off;
    off = (off + bytes + 255) & ~(size_t)255;
    return p;
  };
  float* h_f = (float*)take(33554432);                      // (8192,1024) fp32 residual
  unsigned short* y_bf = (unsigned short*)take(16777216);   // LN out; aliased: vt, o
  unsigned short* qkv_bf = (unsigned short*)take(50331648); // (8192,3072) fused q,k,v
  float* dd_f = (float*)take(134217728);                    // (B,H,T,M) fp32; aliased: ff_bf
  unsigned short* qp_bf = (unsigned short*)take(67108864);  // (B,H,T,M)
  unsigned short* kpt_bf = (unsigned short*)take(67108864); // (B,H,M,T)
  unsigned short* ctx_bf = (unsigned short*)take(4194304);  // (B,H,DH,M)
  float* ksum_f = (float*)take(131072);
  float* dinv_f = (float*)take(524288);
  float* stab_f = (float*)take(8192);
  float* xa_f = (float*)take(2097152);
  unsigned short* xabf = (unsigned short*)take(1048576);
  float* bqkv_f = (float*)take(24576);                      // 2 layers x 3072
  take(65536);                                              // guard (conv reads before hbf)
  unsigned short* hbf = (unsigned short*)take(16777216);
  take(65536);                                              // guard (conv reads past hbf)
  unsigned short* xbf = (unsigned short*)take(4194304);
  unsigned short* win_t = (unsigned short*)take(524288);
  unsigned short* wqkvo_t = (unsigned short*)take(16777216);
  unsigned short* w1_t = (unsigned short*)take(16777216);
  unsigned short* w2_t = (unsigned short*)take(16777216);
  unsigned short* wc_t = (unsigned short*)take(4096000);
  unsigned short* projc = (unsigned short*)take(32768);
  unsigned short* wconv_t = (unsigned short*)take(393216);
  unsigned short* waux_t = (unsigned short*)take(256128);
  unsigned short* ff_bf = (unsigned short*)dd_f;   // alias
  unsigned short* vt_bf = y_bf;                    // alias (y dead after QKV)
  unsigned short* o_bf = y_bf;                     // alias (vt dead after ctx)
  (void)in_sizes; (void)n_in; (void)out_size; (void)ws_size;

  // ---- weight conversion ----
  f2b_k<<<2048, 256, 0, stream>>>(x, xbf, (long)CNT * 256);
  tconv_k<<<dim3(8, 32), 256, 0, stream>>>(Win, win_t, 256, 1024);
  for (int l = 0; l < 2; l++) {
    tconv_k<<<dim3(32, 32), 256, 0, stream>>>(Wq + (long)l * 1048576, wqkvo_t + (long)(l * 4 + 0) * 1048576, 1024, 1024);
    tconv_k<<<dim3(32, 32), 256, 0, stream>>>(Wk + (long)l * 1048576, wqkvo_t + (long)(l * 4 + 1) * 1048576, 1024, 1024);
    tconv_k<<<dim3(32, 32), 256, 0, stream>>>(Wv + (long)l * 1048576, wqkvo_t + (long)(l * 4 + 2) * 1048576, 1024, 1024);
    tconv_k<<<dim3(32, 32), 256, 0, stream>>>(Wo + (long)l * 1048576, wqkvo_t + (long)(l * 4 + 3) * 1048576, 1024, 1024);
    tconv_k<<<dim3(32, 128), 256, 0, stream>>>(W1 + (long)l * 4194304, w1_t + (long)l * 4194304, 1024, 4096);
    tconv_k<<<dim3(128, 32), 256, 0, stream>>>(W2 + (long)l * 4194304, w2_t + (long)l * 4194304, 4096, 1024);
    catb_k<<<12, 256, 0, stream>>>(bq + l * CDM, bk + l * CDM, bv + l * CDM, bqkv_f + l * CQKV);
  }
  tconv_k<<<dim3(32, 63), 256, 0, stream>>>(Wc, wc_t, 1024, 2000);
  tconv_k<<<dim3(2, 63), 256, 0, stream>>>(Waux, waux_t, 64, 2001);
  wconv_k<<<768, 256, 0, stream>>>(Wconv, wconv_t);
  projc_k<<<64, 256, 0, stream>>>(proj, projc);

  // ---- embed ----
  LAUNCH_G8(128, EPI_BIAS, xbf, win_t, b_in, h_f, CNT, CDM, 256, 256, 256, CDM);
  addpe_k<<<8192, 256, 0, stream>>>(h_f, pe);

  for (int l = 0; l < 2; l++) {
    const unsigned short* wqkv_t = wqkvo_t + (long)(l * 4) * 1048576;  // q,k,v adjacent: 3072 x 1024
    const unsigned short* wo_t = wqkvo_t + (long)(l * 4 + 3) * 1048576;

    ln_k<<<2048, 256, 0, stream>>>(h_f, ln1_g + l * CDM, ln1_b + l * CDM, y_bf);
    // fused QKV: (8192,1024) x (3072,1024)^T -> (8192,3072) bf16
    LAUNCH_G8(256, EPI_BIAS | EPI_OUTBF, y_bf, wqkv_t, bqkv_f + l * CQKV, qkv_bf, CNT, CQKV, CDM, CDM, CDM, CQKV);

    // dd = q @ (proj*dn)^T, batched over (b,h)
    LAUNCH_GEMM(0, qkv_bf, projc, nullptr, dd_f, nullptr, CT, CM, CDH, CQKV, CDH, CM, 128, CH,
                (long)CT * CQKV, 64, 0, 0, (long)CH * CT * CM, (long)CT * CM, 0, 0);
    featq_k<<<32768, 256, 0, stream>>>(dd_f, qkv_bf, qp_bf);
    LAUNCH_GEMM(0, qkv_bf + 1024, projc, nullptr, dd_f, nullptr, CT, CM, CDH, CQKV, CDH, CM, 128, CH,
                (long)CT * CQKV, 64, 0, 0, (long)CH * CT * CM, (long)CT * CM, 0, 0);
    stabp_k<<<2048, 256, 0, stream>>>(dd_f, stab_f);
    featk_k<<<4096, 256, 0, stream>>>(dd_f, qkv_bf + 1024, stab_f, kpt_bf);
    trv_k<<<4096, 256, 0, stream>>>(qkv_bf + 2048, vt_bf);
    ksum_k<<<8192, 256, 0, stream>>>(kpt_bf, ksum_f);
    // ctx^T (DH,M) = v^T @ kp, batched
    LAUNCH_GEMM(EPI_OUTBF, vt_bf, kpt_bf, nullptr, ctx_bf, nullptr, CDH, CM, CT, CT, CT, CM, 128, CH,
                (long)CH * CDH * CT, (long)CDH * CT, (long)CH * CM * CT, (long)CM * CT,
                (long)CH * CDH * CM, (long)CDH * CM, 0, 0);
    dinv_k<<<32768, 256, 0, stream>>>(qp_bf, ksum_f, dinv_f);
    // o = (qp @ ctx) * dinv -> (B,T,H*DH) bf16 (overwrites vt alias after ctx done)
    LAUNCH_GEMM(EPI_RSCALE | EPI_OUTBF, qp_bf, ctx_bf, nullptr, o_bf, dinv_f, CT, CDH, CM, CM, CM, CDM, 128, CH,
                (long)CH * CT * CM, (long)CT * CM, (long)CH * CDH * CM, (long)CDH * CM,
                (long)CT * CDM, 64, (long)CH * CT, (long)CT);
    LAUNCH_G8(128, EPI_BIAS | EPI_ACCUM, o_bf, wo_t, bo + l * CDM, h_f, CNT, CDM, CDM, CDM, CDM, CDM);

    ln_k<<<2048, 256, 0, stream>>>(h_f, ln2_g + l * CDM, ln2_b + l * CDM, y_bf);
    LAUNCH_G8(256, EPI_BIAS | EPI_GELU | EPI_OUTBF, y_bf, w1_t + (long)l * 4194304, b1 + l * CDFF, ff_bf,
              CNT, CDFF, CDM, CDM, CDM, CDFF);
    LAUNCH_G8(128, EPI_BIAS | EPI_ACCUM, ff_bf, w2_t + (long)l * 4194304, b2 + l * CDM, h_f,
              CNT, CDM, CDFF, CDFF, CDFF, CDM);

    if (l == 0) {
      f2b_k<<<8192, 256, 0, stream>>>(h_f, hbf, (long)CNT * CDM);
      LAUNCH_GEMM(0, hbf - CDM, wconv_t + 0 * 65536, nullptr, xa_f, nullptr, CNT, 64, CDM, CDM, CDM, 64, 1, 1, 0, 0, 0, 0, 0, 0, 0, 0);
      LAUNCH_GEMM(EPI_ACCUM, hbf, wconv_t + 1 * 65536, nullptr, xa_f, nullptr, CNT, 64, CDM, CDM, CDM, 64, 1, 1, 0, 0, 0, 0, 0, 0, 0, 0);
      LAUNCH_GEMM(EPI_BIAS | EPI_ACCUM, hbf + CDM, wconv_t + 2 * 65536, bconv, xa_f, nullptr, CNT, 64, CDM, CDM, CDM, 64, 1, 1, 0, 0, 0, 0, 0, 0, 0, 0);
      patch_k<<<16, 256, 0, stream>>>(h_f, Wconv, bconv, xa_f);
      f2b_k<<<512, 256, 0, stream>>>(xa_f, xabf, (long)CNT * 64);
      LAUNCH_GEMM(EPI_BIAS, xabf, waux_t, baux, out + 16384000, nullptr, CNT, CV + 1, 64, 64, 64, CV + 1, 1, 1, 0, 0, 0, 0, 0, 0, 0, 0);
    }
  }

  // ---- classifier ----
  f2b_k<<<8192, 256, 0, stream>>>(h_f, hbf, (long)CNT * CDM);
  LAUNCH_G8(256, EPI_BIAS, hbf, wc_t, bc, out, CNT, CV, CDM, CDM, CDM, CV);
}

// Round 3
// 1823.639 us; speedup vs baseline: 1.0448x; 1.0332x over previous
//
#include <hip/hip_runtime.h>
#include <hip/hip_bf16.h>

typedef __attribute__((ext_vector_type(4))) float f32x4;
typedef __attribute__((ext_vector_type(8))) unsigned short u16x8;
typedef __attribute__((ext_vector_type(4))) unsigned short u16x4;
typedef __bf16 bf16x8 __attribute__((ext_vector_type(8)));

#define DEVFN static __device__ __forceinline__

constexpr int CB = 8, CT = 1024, CDM = 1024, CH = 16, CDH = 64, CDFF = 4096, CV = 2000, CM = 256;
constexpr int CNT = CB * CT; // 8192 tokens
constexpr int CQKV = 3072;   // fused qkv row stride
constexpr float CDN = 0.35355339059327373f;   // 64^-0.25
constexpr float CRATIO = 0.0625f;             // 256^-0.5
constexpr float CKEPS = 1e-4f;

DEVFN unsigned short f2bu(float x) {
  __hip_bfloat16 h = __float2bfloat16(x);
  return __builtin_bit_cast(unsigned short, h);
}
DEVFN float b2f(unsigned short u) {
  __hip_bfloat16 h = __builtin_bit_cast(__hip_bfloat16, u);
  return __bfloat162float(h);
}
DEVFN float wredsum(float s) {
#pragma unroll
  for (int ofs = 32; ofs; ofs >>= 1) s += __shfl_xor(s, ofs, 64);
  return s;
}
DEVFN float wredmax(float s) {
#pragma unroll
  for (int ofs = 32; ofs; ofs >>= 1) s = fmaxf(s, __shfl_xor(s, ofs, 64));
  return s;
}
DEVFN void gl_lds16(const void* g, void* l) {
  __builtin_amdgcn_global_load_lds(
      (const __attribute__((address_space(1))) unsigned int*)g,
      (__attribute__((address_space(3))) unsigned int*)l, 16, 0, 0);
}
DEVFN f32x4 mfma16(u16x8 a, u16x8 b, f32x4 c) {
  return __builtin_amdgcn_mfma_f32_16x16x32_bf16(
      __builtin_bit_cast(bf16x8, a), __builtin_bit_cast(bf16x8, b), c, 0, 0, 0);
}

#define EPI_BIAS 1
#define EPI_ACCUM 2
#define EPI_GELU 4
#define EPI_OUTBF 8
#define EPI_RSCALE 16

// ================= big GEMM: C = A(M,K) * Bt(N,K)^T =================
// TMx x 256 tile, BK=64, 8 waves (2Mx4N), 2 LDS buffers, st-swizzle,
// FULL-TILE prefetch: stage tile t+1 at top of tile t, counted vmcnt(ST),
// 2 barriers/tile, free-running MFMA+ds_read inside the tile, setprio.
template <int TMx, int EPI>
__global__ __launch_bounds__(512, 2) void gemm8_k(
    const unsigned short* __restrict__ A, const unsigned short* __restrict__ Bt,
    const float* __restrict__ bias, void* __restrict__ C,
    int Mr, int Nr, int Kr, int lda, int ldb, int ldc) {
  constexpr int AR = TMx * 64 / 4096;  // A staging rounds (4 or 2)
  constexpr int BR = 4;                // B staging rounds
  constexpr int ST = AR + BR;
  constexpr int MREP = TMx / 32;       // per-wave m-fragments (8 or 4)
  __shared__ unsigned short smA[2][TMx * 64];
  __shared__ unsigned short smB[2][256 * 64];

  int tid = threadIdx.x, wv = tid >> 6, ll = tid & 63;
  int wm = wv >> 2, wn = wv & 3;  // 2 x 4 wave grid
  int m0 = blockIdx.x * TMx, n0 = blockIdx.y * 256;
  int fr = ll & 15, f16 = ll >> 4, fk = f16 * 8;

  const char* Ab = (const char*)A;
  const char* Bb = (const char*)Bt;

  // staging source byte offsets (inverse-swizzled: linear LDS dest + swizzled read)
  unsigned int offA[AR], offB[BR];
#pragma unroll
  for (int ro = 0; ro < AR; ro++) {
    int L = (ro * 512 + tid) * 16;
    int P = L ^ (((L >> 9) & 1) << 5);
    int kh = P / (TMx * 64), rem = P % (TMx * 64);
    int r = rem >> 6, cb = rem & 63;
    long row = min(m0 + r, Mr - 1);
    offA[ro] = (unsigned int)((row * lda + kh * 32) * 2 + cb);
  }
#pragma unroll
  for (int ro = 0; ro < BR; ro++) {
    int L = (ro * 512 + tid) * 16;
    int P = L ^ (((L >> 9) & 1) << 5);
    int kh = P / 16384, rem = P & 16383;
    int r = rem >> 6, cb = rem & 63;
    long row = min(n0 + r, Nr - 1);
    offB[ro] = (unsigned int)((row * ldb + kh * 32) * 2 + cb);
  }
  // fragment LDS offsets (shorts), swizzled
  int loA[MREP][2], loB[4][2];
#pragma unroll
  for (int i = 0; i < MREP; i++)
#pragma unroll
    for (int ks = 0; ks < 2; ks++) {
      int r = wm * (TMx / 2) + i * 16 + fr;
      loA[i][ks] = ks * TMx * 32 + r * 32 + (fk ^ (((r >> 3) & 1) << 4));
    }
#pragma unroll
  for (int j = 0; j < 4; j++)
#pragma unroll
    for (int ks = 0; ks < 2; ks++) {
      int r = wn * 64 + j * 16 + fr;
      loB[j][ks] = ks * 8192 + r * 32 + (fk ^ (((r >> 3) & 1) << 4));
    }

  f32x4 acc[MREP][4] = {};
  int NT = Kr / 64;

  // prologue: stage tile 0 into buf 0
#pragma unroll
  for (int ro = 0; ro < ST; ro++) {
    if (ro < AR)
      gl_lds16(Ab + offA[ro], &smA[0][(ro * 512 + wv * 64) * 8]);
    else
      gl_lds16(Bb + offB[ro - AR], &smB[0][((ro - AR) * 512 + wv * 64) * 8]);
  }

  int p = 0;
  for (int t = 0; t < NT; t++) {
    long kbn = (long)((t + 1 < NT) ? t + 1 : t) * 128;  // next K-tile byte offset (clamped)
    __builtin_amdgcn_s_barrier();            // all waves done reading buf p^1
    __builtin_amdgcn_sched_barrier(0);
    // stage tile t+1 into buf p^1 (issue-early; one full tile to land)
#pragma unroll
    for (int ro = 0; ro < ST; ro++) {
      if (ro < AR)
        gl_lds16(Ab + offA[ro] + kbn, &smA[p ^ 1][(ro * 512 + wv * 64) * 8]);
      else
        gl_lds16(Bb + offB[ro - AR] + kbn, &smB[p ^ 1][((ro - AR) * 512 + wv * 64) * 8]);
    }
    // counted wait: retire tile t's ST loads (issued one tile ago); keep ST in flight
    if constexpr (ST == 8) {
      asm volatile("s_waitcnt vmcnt(8)" ::: "memory");
    } else {
      asm volatile("s_waitcnt vmcnt(6)" ::: "memory");
    }
    __builtin_amdgcn_s_barrier();            // buf p globally ready
    __builtin_amdgcn_sched_barrier(0);

    u16x8 afr[MREP], bq0, bq1;
#pragma unroll
    for (int ks = 0; ks < 2; ks++) {
#pragma unroll
      for (int i = 0; i < MREP; i++) afr[i] = *(const u16x8*)&smA[p][loA[i][ks]];
#pragma unroll
      for (int jh = 0; jh < 2; jh++) {
        bq0 = *(const u16x8*)&smB[p][loB[jh * 2][ks]];
        bq1 = *(const u16x8*)&smB[p][loB[jh * 2 + 1][ks]];
        __builtin_amdgcn_s_setprio(1);
#pragma unroll
        for (int i = 0; i < MREP; i++) {
          acc[i][jh * 2] = mfma16(afr[i], bq0, acc[i][jh * 2]);
          acc[i][jh * 2 + 1] = mfma16(afr[i], bq1, acc[i][jh * 2 + 1]);
        }
        __builtin_amdgcn_s_setprio(0);
      }
    }
    p ^= 1;
  }

  // ---- epilogue ----
#pragma unroll
  for (int i = 0; i < MREP; i++) {
#pragma unroll
    for (int j = 0; j < 4; j++) {
#pragma unroll
      for (int e = 0; e < 4; e++) {
        int gr = m0 + wm * (TMx / 2) + i * 16 + f16 * 4 + e;
        int gc = n0 + wn * 64 + j * 16 + fr;
        if (gr < Mr && gc < Nr) {
          float v = acc[i][j][e];
          if (EPI & EPI_BIAS) v += bias[gc];
          if (EPI & EPI_GELU) v = 0.5f * v * (1.0f + erff(v * 0.70710678118f));
          long idx = (long)gr * ldc + gc;
          if (EPI & EPI_ACCUM) v += ((float*)C)[idx];
          if (EPI & EPI_OUTBF) ((unsigned short*)C)[idx] = f2bu(v);
          else ((float*)C)[idx] = v;
        }
      }
    }
  }
}

// ================= legacy 128x128 GEMM (small/batched shapes) =================
template <int EPI>
__global__ __launch_bounds__(256) void gemm_k(
    const unsigned short* __restrict__ Aall, const unsigned short* __restrict__ Btall,
    const float* __restrict__ bias, void* __restrict__ Call, const float* __restrict__ rsall,
    int Mr, int Nr, int Kr, int lda, int ldb, int ldc, int bdiv,
    long As1, long As2, long Bs1, long Bs2, long Cs1, long Cs2, long Rs1, long Rs2) {
  __shared__ unsigned short smA[128 * 32];
  __shared__ unsigned short smB[128 * 32];
  int bz = blockIdx.z;
  const unsigned short* A = Aall + (long)(bz / bdiv) * As1 + (long)(bz % bdiv) * As2;
  const unsigned short* Bt = Btall + (long)(bz / bdiv) * Bs1 + (long)(bz % bdiv) * Bs2;
  long coff = (long)(bz / bdiv) * Cs1 + (long)(bz % bdiv) * Cs2;
  const float* rs = nullptr;
  if (EPI & EPI_RSCALE) rs = rsall + (long)(bz / bdiv) * Rs1 + (long)(bz % bdiv) * Rs2;

  int tid = threadIdx.x, wv = tid >> 6, ll = tid & 63;
  int m0 = blockIdx.x * 128, n0 = blockIdx.y * 128;
  int sr = tid >> 2, sc = (tid & 3) * 8;
  long ar0 = min(m0 + sr, Mr - 1), ar1 = min(m0 + sr + 64, Mr - 1);
  long br0 = min(n0 + sr, Nr - 1), br1 = min(n0 + sr + 64, Nr - 1);
  unsigned short* lA0 = &smA[(wv * 16) * 32];
  unsigned short* lA1 = &smA[(64 + wv * 16) * 32];
  unsigned short* lB0 = &smB[(wv * 16) * 32];
  unsigned short* lB1 = &smB[(64 + wv * 16) * 32];

  f32x4 acc[4][4] = {};
  int wr = (wv >> 1) * 64, wc = (wv & 1) * 64;
  int fr = ll & 15, fk = (ll >> 4) * 8;

  for (int k0 = 0; k0 < Kr; k0 += 32) {
    __syncthreads();
    gl_lds16(A + ar0 * lda + k0 + sc, lA0);
    gl_lds16(A + ar1 * lda + k0 + sc, lA1);
    gl_lds16(Bt + br0 * ldb + k0 + sc, lB0);
    gl_lds16(Bt + br1 * ldb + k0 + sc, lB1);
    __syncthreads();
    u16x8 af[4], bfr[4];
#pragma unroll
    for (int i = 0; i < 4; i++) {
      af[i] = *(const u16x8*)&smA[(wr + i * 16 + fr) * 32 + fk];
      bfr[i] = *(const u16x8*)&smB[(wc + i * 16 + fr) * 32 + fk];
    }
#pragma unroll
    for (int i = 0; i < 4; i++)
#pragma unroll
      for (int j = 0; j < 4; j++) acc[i][j] = mfma16(af[i], bfr[j], acc[i][j]);
  }

#pragma unroll
  for (int i = 0; i < 4; i++) {
#pragma unroll
    for (int j = 0; j < 4; j++) {
#pragma unroll
      for (int e = 0; e < 4; e++) {
        int gr = m0 + wr + i * 16 + (ll >> 4) * 4 + e;
        int gc = n0 + wc + j * 16 + (ll & 15);
        if (gr < Mr && gc < Nr) {
          float v = acc[i][j][e];
          if (EPI & EPI_BIAS) v += bias[gc];
          if (EPI & EPI_GELU) v = 0.5f * v * (1.0f + erff(v * 0.70710678118f));
          if (EPI & EPI_RSCALE) v *= rs[gr];
          long idx = coff + (long)gr * ldc + gc;
          if (EPI & EPI_ACCUM) v += ((float*)Call)[idx];
          if (EPI & EPI_OUTBF) ((unsigned short*)Call)[idx] = f2bu(v);
          else ((float*)Call)[idx] = v;
        }
      }
    }
  }
}

// ---------------- LayerNorm: fp32 in -> bf16 out ----------------
__global__ __launch_bounds__(256) void ln_k(const float* __restrict__ h,
                                            const float* __restrict__ g,
                                            const float* __restrict__ b,
                                            unsigned short* __restrict__ y) {
  int wv = threadIdx.x >> 6, ll = threadIdx.x & 63;
  long row = (long)blockIdx.x * 4 + wv;
  const float* hr = h + row * CDM;
  f32x4 x[4];
#pragma unroll
  for (int i = 0; i < 4; i++) x[i] = *(const f32x4*)&hr[ll * 16 + i * 4];
  float s = 0;
#pragma unroll
  for (int i = 0; i < 4; i++)
#pragma unroll
    for (int e = 0; e < 4; e++) s += x[i][e];
  float mu = wredsum(s) * (1.f / CDM);
  float v = 0;
#pragma unroll
  for (int i = 0; i < 4; i++)
#pragma unroll
    for (int e = 0; e < 4; e++) {
      float d = x[i][e] - mu;
      v += d * d;
    }
  float inv = rsqrtf(wredsum(v) * (1.f / CDM) + 1e-5f);
  unsigned short o[16];
#pragma unroll
  for (int i = 0; i < 4; i++)
#pragma unroll
    for (int e = 0; e < 4; e++) {
      int c = ll * 16 + i * 4 + e;
      o[i * 4 + e] = f2bu((x[i][e] - mu) * inv * g[c] + b[c]);
    }
  *(u16x8*)&y[row * CDM + ll * 16] = *(u16x8*)&o[0];
  *(u16x8*)&y[row * CDM + ll * 16 + 8] = *(u16x8*)&o[8];
}

// ---------------- FAVOR+ query features (q from fused qkv, stride 3072) ----------------
__global__ __launch_bounds__(256) void featq_k(const float* __restrict__ dd,
                                               const unsigned short* __restrict__ qb,
                                               unsigned short* __restrict__ qp) {
  int wv = threadIdx.x >> 6, ll = threadIdx.x & 63;
  long gid = (long)blockIdx.x * 4 + wv;  // (b*H+h)*T + t
  long bh = gid >> 10;
  int t = gid & 1023;
  int b = bh >> 4, hh = bh & 15;
  const float* dr = dd + gid * CM;
  f32x4 d4 = *(const f32x4*)&dr[ll * 4];
  float qv = b2f(qb[((long)b * CT + t) * CQKV + hh * CDH + ll]);
  float diag = wredsum(qv * qv) * (0.5f * CDN * CDN);
  float mx = fmaxf(fmaxf(d4[0], d4[1]), fmaxf(d4[2], d4[3]));
  mx = wredmax(mx);
  unsigned short o[4];
#pragma unroll
  for (int e = 0; e < 4; e++) o[e] = f2bu(CRATIO * (expf(d4[e] - diag - mx) + CKEPS));
  *(u16x4*)&qp[gid * CM + ll * 4] = *(u16x4*)&o[0];
}

// ---------------- key stabilizer partial max ----------------
__global__ __launch_bounds__(256) void stabp_k(const float* __restrict__ dd,
                                               float* __restrict__ part) {
  int bh = blockIdx.x >> 4, c = blockIdx.x & 15;
  const float* base = dd + ((long)bh * CT * CM) + (long)c * 16384;
  float mx = -3.4e38f;
#pragma unroll 4
  for (int it = 0; it < 16; it++) {
    f32x4 v = *(const f32x4*)&base[(it * 256 + threadIdx.x) * 4];
    mx = fmaxf(mx, fmaxf(fmaxf(v[0], v[1]), fmaxf(v[2], v[3])));
  }
  mx = wredmax(mx);
  __shared__ float sm[4];
  if ((threadIdx.x & 63) == 0) sm[threadIdx.x >> 6] = mx;
  __syncthreads();
  if (threadIdx.x == 0) part[blockIdx.x] = fmaxf(fmaxf(sm[0], sm[1]), fmaxf(sm[2], sm[3]));
}

// ---------------- key features, transposed out (k from fused qkv) ----------------
__global__ __launch_bounds__(256) void featk_k(const float* __restrict__ dd,
                                               const unsigned short* __restrict__ kb,
                                               const float* __restrict__ part,
                                               unsigned short* __restrict__ kpt) {
  int bh = blockIdx.x >> 5;
  int t0 = (blockIdx.x & 31) * 32;
  int b = bh >> 4, hh = bh & 15;
  float st = -3.4e38f;
#pragma unroll
  for (int i = 0; i < 16; i++) st = fmaxf(st, part[bh * 16 + i]);
  __shared__ unsigned short tile[32][256];
  int wv = threadIdx.x >> 6, ll = threadIdx.x & 63;
  for (int rr = 0; rr < 8; rr++) {
    int tr = wv * 8 + rr;
    int t = t0 + tr;
    const float* drr = dd + ((long)bh * CT + t) * CM;
    f32x4 d4 = *(const f32x4*)&drr[ll * 4];
    float kv = b2f(kb[((long)b * CT + t) * CQKV + hh * CDH + ll]);
    float diag = wredsum(kv * kv) * (0.5f * CDN * CDN);
#pragma unroll
    for (int e = 0; e < 4; e++)
      tile[tr][ll * 4 + e] = f2bu(CRATIO * (expf(d4[e] - diag - st) + CKEPS));
  }
  __syncthreads();
#pragma unroll
  for (int p = 0; p < 4; p++) {
    int m = p * 64 + (threadIdx.x >> 2);
    int tz = (threadIdx.x & 3) * 8;
    unsigned short o[8];
#pragma unroll
    for (int e = 0; e < 8; e++) o[e] = tile[tz + e][m];
    *(u16x8*)&kpt[((long)bh * CM + m) * CT + t0 + tz] = *(u16x8*)&o[0];
  }
}

// ---------------- v (from fused qkv) -> v_t (B,H,DH,T) ----------------
__global__ __launch_bounds__(256) void trv_k(const unsigned short* __restrict__ vb,
                                             unsigned short* __restrict__ vt) {
  int bh = blockIdx.x >> 5;
  int t0 = (blockIdx.x & 31) * 32;
  int b = bh >> 4, hh = bh & 15;
  __shared__ unsigned short tile[32][64];
  int tr = threadIdx.x >> 3, dblk = (threadIdx.x & 7) * 8;
  *(u16x8*)&tile[tr][dblk] = *(const u16x8*)&vb[((long)b * CT + t0 + tr) * CQKV + hh * CDH + dblk];
  __syncthreads();
  int d = threadIdx.x >> 2, tz = (threadIdx.x & 3) * 8;
  unsigned short o[8];
#pragma unroll
  for (int e = 0; e < 8; e++) o[e] = tile[tz + e][d];
  *(u16x8*)&vt[((long)bh * CDH + d) * CT + t0 + tz] = *(u16x8*)&o[0];
}

// ---------------- ksum[bh,m] = sum_t kp_t[bh,m,t] ----------------
__global__ __launch_bounds__(256) void ksum_k(const unsigned short* __restrict__ kpt,
                                              float* __restrict__ ksum) {
  int wv = threadIdx.x >> 6, ll = threadIdx.x & 63;
  long gid = (long)blockIdx.x * 4 + wv;
  const unsigned short* r = kpt + gid * CT;
  u16x8 a = *(const u16x8*)&r[ll * 16];
  u16x8 b = *(const u16x8*)&r[ll * 16 + 8];
  float s = 0;
#pragma unroll
  for (int e = 0; e < 8; e++) s += b2f(a[e]) + b2f(b[e]);
  s = wredsum(s);
  if (ll == 0) ksum[gid] = s;
}

// ---------------- dinv[bh,t] = 1 / (qp . ksum) ----------------
__global__ __launch_bounds__(256) void dinv_k(const unsigned short* __restrict__ qp,
                                              const float* __restrict__ ksum,
                                              float* __restrict__ dinv) {
  int wv = threadIdx.x >> 6, ll = threadIdx.x & 63;
  long gid = (long)blockIdx.x * 4 + wv;
  long bh = gid >> 10;
  const unsigned short* r = qp + gid * CM;
  const float* ks = ksum + bh * CM;
  u16x4 a = *(const u16x4*)&r[ll * 4];
  float s = 0;
#pragma unroll
  for (int e = 0; e < 4; e++) s += b2f(a[e]) * ks[ll * 4 + e];
  s = wredsum(s);
  if (ll == 0) dinv[gid] = 1.0f / s;
}

// ---------------- h += pe ----------------
__global__ __launch_bounds__(256) void addpe_k(float* __restrict__ h, const float* __restrict__ pe) {
  long i = ((long)blockIdx.x * 256 + threadIdx.x) * 4;
  int t = (int)((i >> 10) & 1023);
  int c = (int)(i & 1023);
  f32x4 v = *(f32x4*)&h[i];
  f32x4 p = *(const f32x4*)&pe[(long)t * 1024 + c];
  v += p;
  *(f32x4*)&h[i] = v;
}

// ---------------- fp32 -> bf16 flat ----------------
__global__ __launch_bounds__(256) void f2b_k(const float* __restrict__ in,
                                             unsigned short* __restrict__ out, long n) {
  long i = ((long)blockIdx.x * 256 + threadIdx.x) * 4;
  if (i >= n) return;
  f32x4 v = *(const f32x4*)&in[i];
  unsigned short o[4];
#pragma unroll
  for (int e = 0; e < 4; e++) o[e] = f2bu(v[e]);
  *(u16x4*)&out[i] = *(u16x4*)&o[0];
}

// ---------------- transpose-convert: in (R,C) fp32 -> out (C,R) bf16 ----------------
__global__ __launch_bounds__(256) void tconv_k(const float* __restrict__ in,
                                               unsigned short* __restrict__ out, int R, int C) {
  __shared__ float tile[32][33];
  int r0 = blockIdx.x * 32, c0 = blockIdx.y * 32;
  int tr = threadIdx.x >> 5, tc = threadIdx.x & 31;
#pragma unroll
  for (int p = 0; p < 4; p++) {
    int r = r0 + p * 8 + tr, c = c0 + tc;
    tile[p * 8 + tr][tc] = (r < R && c < C) ? in[(long)r * C + c] : 0.f;
  }
  __syncthreads();
#pragma unroll
  for (int p = 0; p < 4; p++) {
    int c = c0 + p * 8 + tr, r = r0 + tc;
    if (c < C && r < R) out[(long)c * R + r] = f2bu(tile[tc][p * 8 + tr]);
  }
}

// ---------------- Wconv (64,1024,3) -> per-tap (64,1024) bf16 ----------------
__global__ __launch_bounds__(256) void wconv_k(const float* __restrict__ W,
                                               unsigned short* __restrict__ out) {
  int idx = blockIdx.x * 256 + threadIdx.x;
  int r = idx >> 16, rem = idx & 65535, oc = rem >> 10, ic = rem & 1023;
  out[idx] = f2bu(W[oc * 3072 + ic * 3 + r]);
}

// ---------------- proj * dn -> bf16 ----------------
__global__ __launch_bounds__(256) void projc_k(const float* __restrict__ p,
                                               unsigned short* __restrict__ out) {
  int i = blockIdx.x * 256 + threadIdx.x;
  out[i] = f2bu(p[i] * CDN);
}

// ---------------- concat q/k/v biases ----------------
__global__ __launch_bounds__(256) void catb_k(const float* __restrict__ q,
                                              const float* __restrict__ k,
                                              const float* __restrict__ v,
                                              float* __restrict__ o) {
  int i = blockIdx.x * 256 + threadIdx.x;  // < 3072
  o[i] = i < 1024 ? q[i] : (i < 2048 ? k[i - 1024] : v[i - 2048]);
}

// ---------------- exact conv recompute at batch boundaries ----------------
__global__ __launch_bounds__(256) void patch_k(const float* __restrict__ h,
                                               const float* __restrict__ W,
                                               const float* __restrict__ bc,
                                               float* __restrict__ xa) {
  int b = blockIdx.x >> 1;
  int t = (blockIdx.x & 1) ? (CT - 1) : 0;
  int oc = threadIdx.x & 63, ch = threadIdx.x >> 6;
  float s = 0;
  for (int r = 0; r < 3; r++) {
    int tt = t + r - 1;
    if (tt < 0 || tt >= CT) continue;
    const float* hr = h + ((long)b * CT + tt) * CDM;
    const float* wr = W + oc * 3072 + r;
    for (int ic = ch * 256; ic < ch * 256 + 256; ic++) s += hr[ic] * wr[ic * 3];
  }
  __shared__ float sm[256];
  sm[threadIdx.x] = s;
  __syncthreads();
  if (threadIdx.x < 64) {
    float tot = sm[oc] + sm[64 + oc] + sm[128 + oc] + sm[192 + oc] + bc[oc];
    xa[((long)b * CT + t) * 64 + oc] = tot;
  }
}

#define LAUNCH_GEMM(EPI, A, Bt, bias, C, rsp, Mr, Nr, Kr, lda, ldb, ldc, nb, bdiv, As1, As2, Bs1, Bs2, Cs1, Cs2, Rs1, Rs2) \
  gemm_k<EPI><<<dim3(((Mr) + 127) / 128, ((Nr) + 127) / 128, (nb)), 256, 0, stream>>>(           \
      (const unsigned short*)(A), (const unsigned short*)(Bt), (bias), (void*)(C), (rsp),        \
      (Mr), (Nr), (Kr), (lda), (ldb), (ldc), (bdiv), (long)(As1), (long)(As2), (long)(Bs1),      \
      (long)(Bs2), (long)(Cs1), (long)(Cs2), (long)(Rs1), (long)(Rs2))

#define LAUNCH_G8(TMX, EPI, A, Bt, bias, C, Mr, Nr, Kr, lda, ldb, ldc)                           \
  gemm8_k<TMX, EPI><<<dim3(((Mr) + (TMX)-1) / (TMX), ((Nr) + 255) / 256), 512, 0, stream>>>(     \
      (const unsigned short*)(A), (const unsigned short*)(Bt), (bias), (void*)(C),               \
      (Mr), (Nr), (Kr), (lda), (ldb), (ldc))

extern "C" void kernel_launch(void* const* d_in, const int* in_sizes, int n_in,
                              void* d_out, int out_size, void* d_ws, size_t ws_size,
                              hipStream_t stream) {
  const float* x = (const float*)d_in[0];
  const float* Win = (const float*)d_in[1];
  const float* b_in = (const float*)d_in[2];
  const float* pe = (const float*)d_in[3];
  const float* ln1_g = (const float*)d_in[4];
  const float* ln1_b = (const float*)d_in[5];
  const float* Wq = (const float*)d_in[6];
  const float* bq = (const float*)d_in[7];
  const float* Wk = (const float*)d_in[8];
  const float* bk = (const float*)d_in[9];
  const float* Wv = (const float*)d_in[10];
  const float* bv = (const float*)d_in[11];
  const float* Wo = (const float*)d_in[12];
  const float* bo = (const float*)d_in[13];
  const float* ln2_g = (const float*)d_in[14];
  const float* ln2_b = (const float*)d_in[15];
  const float* W1 = (const float*)d_in[16];
  const float* b1 = (const float*)d_in[17];
  const float* W2 = (const float*)d_in[18];
  const float* b2 = (const float*)d_in[19];
  const float* Wc = (const float*)d_in[20];
  const float* bc = (const float*)d_in[21];
  const float* Wconv = (const float*)d_in[22];
  const float* bconv = (const float*)d_in[23];
  const float* Waux = (const float*)d_in[24];
  const float* baux = (const float*)d_in[25];
  const float* proj = (const float*)d_in[26];
  float* out = (float*)d_out;

  char* wsp = (char*)d_ws;
  size_t off = 0;
  auto take = [&](size_t bytes) {
    char* p = wsp + off;
    off = (off + bytes + 255) & ~(size_t)255;
    return p;
  };
  float* h_f = (float*)take(33554432);                      // (8192,1024) fp32 residual
  unsigned short* y_bf = (unsigned short*)take(16777216);   // LN out; aliased: vt, o
  unsigned short* qkv_bf = (unsigned short*)take(50331648); // (8192,3072) fused q,k,v
  float* dd_f = (float*)take(134217728);                    // (B,H,T,M) fp32; aliased: ff_bf
  unsigned short* qp_bf = (unsigned short*)take(67108864);  // (B,H,T,M)
  unsigned short* kpt_bf = (unsigned short*)take(67108864); // (B,H,M,T)
  unsigned short* ctx_bf = (unsigned short*)take(4194304);  // (B,H,DH,M)
  float* ksum_f = (float*)take(131072);
  float* dinv_f = (float*)take(524288);
  float* stab_f = (float*)take(8192);
  float* xa_f = (float*)take(2097152);
  unsigned short* xabf = (unsigned short*)take(1048576);
  float* bqkv_f = (float*)take(24576);                      // 2 layers x 3072
  take(65536);                                              // guard (conv reads before hbf)
  unsigned short* hbf = (unsigned short*)take(16777216);
  take(65536);                                              // guard (conv reads past hbf)
  unsigned short* xbf = (unsigned short*)take(4194304);
  unsigned short* win_t = (unsigned short*)take(524288);
  unsigned short* wqkvo_t = (unsigned short*)take(16777216);
  unsigned short* w1_t = (unsigned short*)take(16777216);
  unsigned short* w2_t = (unsigned short*)take(16777216);
  unsigned short* wc_t = (unsigned short*)take(4096000);
  unsigned short* projc = (unsigned short*)take(32768);
  unsigned short* wconv_t = (unsigned short*)take(393216);
  unsigned short* waux_t = (unsigned short*)take(256128);
  unsigned short* ff_bf = (unsigned short*)dd_f;   // alias
  unsigned short* vt_bf = y_bf;                    // alias (y dead after QKV)
  unsigned short* o_bf = y_bf;                     // alias (vt dead after ctx)
  (void)in_sizes; (void)n_in; (void)out_size; (void)ws_size;

  // ---- weight conversion ----
  f2b_k<<<2048, 256, 0, stream>>>(x, xbf, (long)CNT * 256);
  tconv_k<<<dim3(8, 32), 256, 0, stream>>>(Win, win_t, 256, 1024);
  for (int l = 0; l < 2; l++) {
    tconv_k<<<dim3(32, 32), 256, 0, stream>>>(Wq + (long)l * 1048576, wqkvo_t + (long)(l * 4 + 0) * 1048576, 1024, 1024);
    tconv_k<<<dim3(32, 32), 256, 0, stream>>>(Wk + (long)l * 1048576, wqkvo_t + (long)(l * 4 + 1) * 1048576, 1024, 1024);
    tconv_k<<<dim3(32, 32), 256, 0, stream>>>(Wv + (long)l * 1048576, wqkvo_t + (long)(l * 4 + 2) * 1048576, 1024, 1024);
    tconv_k<<<dim3(32, 32), 256, 0, stream>>>(Wo + (long)l * 1048576, wqkvo_t + (long)(l * 4 + 3) * 1048576, 1024, 1024);
    tconv_k<<<dim3(32, 128), 256, 0, stream>>>(W1 + (long)l * 4194304, w1_t + (long)l * 4194304, 1024, 4096);
    tconv_k<<<dim3(128, 32), 256, 0, stream>>>(W2 + (long)l * 4194304, w2_t + (long)l * 4194304, 4096, 1024);
    catb_k<<<12, 256, 0, stream>>>(bq + l * CDM, bk + l * CDM, bv + l * CDM, bqkv_f + l * CQKV);
  }
  tconv_k<<<dim3(32, 63), 256, 0, stream>>>(Wc, wc_t, 1024, 2000);
  tconv_k<<<dim3(2, 63), 256, 0, stream>>>(Waux, waux_t, 64, 2001);
  wconv_k<<<768, 256, 0, stream>>>(Wconv, wconv_t);
  projc_k<<<64, 256, 0, stream>>>(proj, projc);

  // ---- embed ----
  LAUNCH_G8(128, EPI_BIAS, xbf, win_t, b_in, h_f, CNT, CDM, 256, 256, 256, CDM);
  addpe_k<<<8192, 256, 0, stream>>>(h_f, pe);

  for (int l = 0; l < 2; l++) {
    const unsigned short* wqkv_t = wqkvo_t + (long)(l * 4) * 1048576;  // q,k,v adjacent: 3072 x 1024
    const unsigned short* wo_t = wqkvo_t + (long)(l * 4 + 3) * 1048576;

    ln_k<<<2048, 256, 0, stream>>>(h_f, ln1_g + l * CDM, ln1_b + l * CDM, y_bf);
    // fused QKV: (8192,1024) x (3072,1024)^T -> (8192,3072) bf16
    LAUNCH_G8(256, EPI_BIAS | EPI_OUTBF, y_bf, wqkv_t, bqkv_f + l * CQKV, qkv_bf, CNT, CQKV, CDM, CDM, CDM, CQKV);

    // dd = q @ (proj*dn)^T, batched over (b,h)
    LAUNCH_GEMM(0, qkv_bf, projc, nullptr, dd_f, nullptr, CT, CM, CDH, CQKV, CDH, CM, 128, CH,
                (long)CT * CQKV, 64, 0, 0, (long)CH * CT * CM, (long)CT * CM, 0, 0);
    featq_k<<<32768, 256, 0, stream>>>(dd_f, qkv_bf, qp_bf);
    LAUNCH_GEMM(0, qkv_bf + 1024, projc, nullptr, dd_f, nullptr, CT, CM, CDH, CQKV, CDH, CM, 128, CH,
                (long)CT * CQKV, 64, 0, 0, (long)CH * CT * CM, (long)CT * CM, 0, 0);
    stabp_k<<<2048, 256, 0, stream>>>(dd_f, stab_f);
    featk_k<<<4096, 256, 0, stream>>>(dd_f, qkv_bf + 1024, stab_f, kpt_bf);
    trv_k<<<4096, 256, 0, stream>>>(qkv_bf + 2048, vt_bf);
    ksum_k<<<8192, 256, 0, stream>>>(kpt_bf, ksum_f);
    // ctx^T (DH,M) = v^T @ kp, batched
    LAUNCH_GEMM(EPI_OUTBF, vt_bf, kpt_bf, nullptr, ctx_bf, nullptr, CDH, CM, CT, CT, CT, CM, 128, CH,
                (long)CH * CDH * CT, (long)CDH * CT, (long)CH * CM * CT, (long)CM * CT,
                (long)CH * CDH * CM, (long)CDH * CM, 0, 0);
    dinv_k<<<32768, 256, 0, stream>>>(qp_bf, ksum_f, dinv_f);
    // o = (qp @ ctx) * dinv -> (B,T,H*DH) bf16 (overwrites vt alias after ctx done)
    LAUNCH_GEMM(EPI_RSCALE | EPI_OUTBF, qp_bf, ctx_bf, nullptr, o_bf, dinv_f, CT, CDH, CM, CM, CM, CDM, 128, CH,
                (long)CH * CT * CM, (long)CT * CM, (long)CH * CDH * CM, (long)CDH * CM,
                (long)CT * CDM, 64, (long)CH * CT, (long)CT);
    LAUNCH_G8(128, EPI_BIAS | EPI_ACCUM, o_bf, wo_t, bo + l * CDM, h_f, CNT, CDM, CDM, CDM, CDM, CDM);

    ln_k<<<2048, 256, 0, stream>>>(h_f, ln2_g + l * CDM, ln2_b + l * CDM, y_bf);
    LAUNCH_G8(256, EPI_BIAS | EPI_GELU | EPI_OUTBF, y_bf, w1_t + (long)l * 4194304, b1 + l * CDFF, ff_bf,
              CNT, CDFF, CDM, CDM, CDM, CDFF);
    LAUNCH_G8(128, EPI_BIAS | EPI_ACCUM, ff_bf, w2_t + (long)l * 4194304, b2 + l * CDM, h_f,
              CNT, CDM, CDFF, CDFF, CDFF, CDM);

    if (l == 0) {
      f2b_k<<<8192, 256, 0, stream>>>(h_f, hbf, (long)CNT * CDM);
      LAUNCH_GEMM(0, hbf - CDM, wconv_t + 0 * 65536, nullptr, xa_f, nullptr, CNT, 64, CDM, CDM, CDM, 64, 1, 1, 0, 0, 0, 0, 0, 0, 0, 0);
      LAUNCH_GEMM(EPI_ACCUM, hbf, wconv_t + 1 * 65536, nullptr, xa_f, nullptr, CNT, 64, CDM, CDM, CDM, 64, 1, 1, 0, 0, 0, 0, 0, 0, 0, 0);
      LAUNCH_GEMM(EPI_BIAS | EPI_ACCUM, hbf + CDM, wconv_t + 2 * 65536, bconv, xa_f, nullptr, CNT, 64, CDM, CDM, CDM, 64, 1, 1, 0, 0, 0, 0, 0, 0, 0, 0);
      patch_k<<<16, 256, 0, stream>>>(h_f, Wconv, bconv, xa_f);
      f2b_k<<<512, 256, 0, stream>>>(xa_f, xabf, (long)CNT * 64);
      LAUNCH_GEMM(EPI_BIAS, xabf, waux_t, baux, out + 16384000, nullptr, CNT, CV + 1, 64, 64, 64, CV + 1, 1, 1, 0, 0, 0, 0, 0, 0, 0, 0);
    }
  }

  // ---- classifier ----
  f2b_k<<<8192, 256, 0, stream>>>(h_f, hbf, (long)CNT * CDM);
  LAUNCH_G8(256, EPI_BIAS, hbf, wc_t, bc, out, CNT, CV, CDM, CDM, CDM, CV);
}

// Round 4
// 1596.074 us; speedup vs baseline: 1.1937x; 1.1426x over previous
//
#include <hip/hip_runtime.h>
#include <hip/hip_bf16.h>

typedef __attribute__((ext_vector_type(4))) float f32x4;
typedef __attribute__((ext_vector_type(8))) unsigned short u16x8;
typedef __attribute__((ext_vector_type(4))) unsigned short u16x4;
typedef __bf16 bf16x8 __attribute__((ext_vector_type(8)));

#define DEVFN static __device__ __forceinline__

constexpr int CB = 8, CT = 1024, CDM = 1024, CH = 16, CDH = 64, CDFF = 4096, CV = 2000, CM = 256;
constexpr int CNT = CB * CT; // 8192 tokens
constexpr int CQKV = 3072;   // fused qkv row stride
constexpr float CDN = 0.35355339059327373f;   // 64^-0.25
constexpr float CRATIO = 0.0625f;             // 256^-0.5
constexpr float CKEPS = 1e-4f;

DEVFN unsigned short f2bu(float x) {
  __hip_bfloat16 h = __float2bfloat16(x);
  return __builtin_bit_cast(unsigned short, h);
}
DEVFN float b2f(unsigned short u) {
  __hip_bfloat16 h = __builtin_bit_cast(__hip_bfloat16, u);
  return __bfloat162float(h);
}
DEVFN float wredsum(float s) {
#pragma unroll
  for (int ofs = 32; ofs; ofs >>= 1) s += __shfl_xor(s, ofs, 64);
  return s;
}
DEVFN float wredmax(float s) {
#pragma unroll
  for (int ofs = 32; ofs; ofs >>= 1) s = fmaxf(s, __shfl_xor(s, ofs, 64));
  return s;
}
DEVFN void gl_lds16(const void* g, void* l) {
  __builtin_amdgcn_global_load_lds(
      (const __attribute__((address_space(1))) unsigned int*)g,
      (__attribute__((address_space(3))) unsigned int*)l, 16, 0, 0);
}
DEVFN f32x4 mfma16(u16x8 a, u16x8 b, f32x4 c) {
  return __builtin_amdgcn_mfma_f32_16x16x32_bf16(
      __builtin_bit_cast(bf16x8, a), __builtin_bit_cast(bf16x8, b), c, 0, 0, 0);
}
// compiler-invisible LDS read (no auto waitcnt insertion) — waits are manual
DEVFN u16x8 lds_rd128(unsigned addr) {
  u16x8 r;
  asm volatile("ds_read_b128 %0, %1" : "=v"(r) : "v"(addr));
  return r;
}
DEVFN unsigned lds_addr(const void* p) {
  return (unsigned)(unsigned long)(const __attribute__((address_space(3))) char*)p;
}

#define EPI_BIAS 1
#define EPI_ACCUM 2
#define EPI_GELU 4
#define EPI_OUTBF 8
#define EPI_RSCALE 16

// ================= big GEMM: C = A(M,K) * Bt(N,K)^T =================
// TMx x 256 tile, BK=64, 8 waves (2Mx4N), 2 LDS buffers, st-swizzle, XCD swizzle.
// Inline-asm K-loop: full-tile prefetch, counted vmcnt(ST), counted lgkmcnt,
// raw s_barrier, sched_barrier pins, setprio around MFMA clusters.
template <int TMx, int EPI>
__global__ __launch_bounds__(512, 2) void gemm8_k(
    const unsigned short* __restrict__ A, const unsigned short* __restrict__ Bt,
    const float* __restrict__ bias, void* __restrict__ C,
    int Mr, int Nr, int Kr, int lda, int ldb, int ldc) {
  constexpr int AR = TMx * 64 / 4096;  // A staging rounds (4 or 2)
  constexpr int BR = 4;                // B staging rounds
  constexpr int ST = AR + BR;
  constexpr int MREP = TMx / 32;       // per-wave m-fragments (8 or 4)
  __shared__ unsigned short smA[2][TMx * 64];
  __shared__ unsigned short smB[2][256 * 64];

  int tid = threadIdx.x, wv = tid >> 6, ll = tid & 63;
  int wm = wv >> 2, wn = wv & 3;  // 2 x 4 wave grid
  // ---- bijective XCD swizzle (T1); n-fastest within each XCD chunk ----
  int gx = gridDim.x, gy = gridDim.y;
  int nwg = gx * gy;
  int bid = blockIdx.y * gx + blockIdx.x;
  int q8 = nwg >> 3, r8 = nwg & 7;
  int xcd = bid & 7, rk = bid >> 3;
  int swz = (xcd < r8 ? xcd * (q8 + 1) : r8 * (q8 + 1) + (xcd - r8) * q8) + rk;
  int bx = swz / gy, by = swz % gy;
  int m0 = bx * TMx, n0 = by * 256;
  int fr = ll & 15, f16 = ll >> 4, fk = f16 * 8;

  const char* Ab = (const char*)A;
  const char* Bb = (const char*)Bt;

  // staging source byte offsets (inverse-swizzled: linear LDS dest + swizzled read)
  unsigned int offA[AR], offB[BR];
#pragma unroll
  for (int ro = 0; ro < AR; ro++) {
    int L = (ro * 512 + tid) * 16;
    int P = L ^ (((L >> 9) & 1) << 5);
    int kh = P / (TMx * 64), rem = P % (TMx * 64);
    int r = rem >> 6, cb = rem & 63;
    long row = min(m0 + r, Mr - 1);
    offA[ro] = (unsigned int)((row * lda + kh * 32) * 2 + cb);
  }
#pragma unroll
  for (int ro = 0; ro < BR; ro++) {
    int L = (ro * 512 + tid) * 16;
    int P = L ^ (((L >> 9) & 1) << 5);
    int kh = P / 16384, rem = P & 16383;
    int r = rem >> 6, cb = rem & 63;
    long row = min(n0 + r, Nr - 1);
    offB[ro] = (unsigned int)((row * ldb + kh * 32) * 2 + cb);
  }
  // fragment LDS byte addresses (buf0, ks0), swizzled
  unsigned aAb = lds_addr(&smA[0][0]);
  unsigned aBb = lds_addr(&smB[0][0]);
  unsigned offArd[MREP], offBrd[4];
#pragma unroll
  for (int i = 0; i < MREP; i++) {
    int r = wm * (TMx / 2) + i * 16 + fr;
    offArd[i] = aAb + (unsigned)(r * 64 + 2 * (fk ^ (((r >> 3) & 1) << 4)));
  }
#pragma unroll
  for (int j = 0; j < 4; j++) {
    int r = wn * 64 + j * 16 + fr;
    offBrd[j] = aBb + (unsigned)(r * 64 + 2 * (fk ^ (((r >> 3) & 1) << 4)));
  }

  f32x4 acc[MREP][4] = {};
  int NT = Kr / 64;  // always even for our shapes

  // prologue: stage tile 0 into buf 0
#pragma unroll
  for (int ro = 0; ro < ST; ro++) {
    if (ro < AR)
      gl_lds16(Ab + offA[ro], &smA[0][(ro * 512 + wv * 64) * 8]);
    else
      gl_lds16(Bb + offB[ro - AR], &smB[0][((ro - AR) * 512 + wv * 64) * 8]);
  }

#define WAIT_VM_ST()                                                       \
  {                                                                        \
    if constexpr (ST == 8) asm volatile("s_waitcnt vmcnt(8)" ::: "memory");\
    else asm volatile("s_waitcnt vmcnt(6)" ::: "memory");                  \
    __builtin_amdgcn_sched_barrier(0);                                     \
  }

#define TILEBODY(PB, KBN)                                                  \
  {                                                                        \
    __builtin_amdgcn_s_barrier(); /* all waves done reading buf PB^1 */    \
    __builtin_amdgcn_sched_barrier(0);                                     \
    _Pragma("unroll") for (int ro = 0; ro < ST; ro++) {                    \
      if (ro < AR)                                                         \
        gl_lds16(Ab + offA[ro] + (KBN), &smA[(PB) ^ 1][(ro * 512 + wv * 64) * 8]); \
      else                                                                 \
        gl_lds16(Bb + offB[ro - AR] + (KBN),                               \
                 &smB[(PB) ^ 1][((ro - AR) * 512 + wv * 64) * 8]);         \
    }                                                                      \
    __builtin_amdgcn_sched_barrier(0);                                     \
    WAIT_VM_ST(); /* retire tile's own loads (issued one tile ago) */      \
    __builtin_amdgcn_s_barrier(); /* buf PB globally ready */              \
    __builtin_amdgcn_sched_barrier(0);                                     \
    _Pragma("unroll") for (int ks = 0; ks < 2; ks++) {                     \
      u16x8 afr[MREP], bqs[4];                                             \
      _Pragma("unroll") for (int i = 0; i < MREP; i++)                     \
        afr[i] = lds_rd128(offArd[i] + (PB) * (TMx * 128) + ks * (TMx * 64)); \
      _Pragma("unroll") for (int j = 0; j < 4; j++)                        \
        bqs[j] = lds_rd128(offBrd[j] + (PB) * 32768 + ks * 16384);         \
      asm volatile("s_waitcnt lgkmcnt(2)" ::: "memory");                   \
      __builtin_amdgcn_sched_barrier(0);                                   \
      __builtin_amdgcn_s_setprio(1);                                       \
      _Pragma("unroll") for (int i = 0; i < MREP; i++) {                   \
        acc[i][0] = mfma16(afr[i], bqs[0], acc[i][0]);                     \
        acc[i][1] = mfma16(afr[i], bqs[1], acc[i][1]);                     \
      }                                                                    \
      __builtin_amdgcn_s_setprio(0);                                       \
      asm volatile("s_waitcnt lgkmcnt(0)" ::: "memory");                   \
      __builtin_amdgcn_sched_barrier(0);                                   \
      __builtin_amdgcn_s_setprio(1);                                       \
      _Pragma("unroll") for (int i = 0; i < MREP; i++) {                   \
        acc[i][2] = mfma16(afr[i], bqs[2], acc[i][2]);                     \
        acc[i][3] = mfma16(afr[i], bqs[3], acc[i][3]);                     \
      }                                                                    \
      __builtin_amdgcn_s_setprio(0);                                       \
    }                                                                      \
  }

  for (int t = 0; t < NT; t += 2) {
    long kb1 = (long)min(t + 1, NT - 1) * 128;
    long kb2 = (long)min(t + 2, NT - 1) * 128;
    TILEBODY(0, kb1);  // compute tile t from buf0; stage t+1 -> buf1
    TILEBODY(1, kb2);  // compute tile t+1 from buf1; stage t+2 -> buf0
  }
#undef TILEBODY
#undef WAIT_VM_ST

  // ---- epilogue ----
#pragma unroll
  for (int i = 0; i < MREP; i++) {
#pragma unroll
    for (int j = 0; j < 4; j++) {
#pragma unroll
      for (int e = 0; e < 4; e++) {
        int gr = m0 + wm * (TMx / 2) + i * 16 + f16 * 4 + e;
        int gc = n0 + wn * 64 + j * 16 + fr;
        if (gr < Mr && gc < Nr) {
          float v = acc[i][j][e];
          if (EPI & EPI_BIAS) v += bias[gc];
          if (EPI & EPI_GELU) v = 0.5f * v * (1.0f + erff(v * 0.70710678118f));
          long idx = (long)gr * ldc + gc;
          if (EPI & EPI_ACCUM) v += ((float*)C)[idx];
          if (EPI & EPI_OUTBF) ((unsigned short*)C)[idx] = f2bu(v);
          else ((float*)C)[idx] = v;
        }
      }
    }
  }
}

// ================= legacy 128x128 GEMM (small/batched shapes) =================
template <int EPI>
__global__ __launch_bounds__(256) void gemm_k(
    const unsigned short* __restrict__ Aall, const unsigned short* __restrict__ Btall,
    const float* __restrict__ bias, void* __restrict__ Call, const float* __restrict__ rsall,
    int Mr, int Nr, int Kr, int lda, int ldb, int ldc, int bdiv,
    long As1, long As2, long Bs1, long Bs2, long Cs1, long Cs2, long Rs1, long Rs2) {
  __shared__ unsigned short smA[128 * 32];
  __shared__ unsigned short smB[128 * 32];
  int bz = blockIdx.z;
  const unsigned short* A = Aall + (long)(bz / bdiv) * As1 + (long)(bz % bdiv) * As2;
  const unsigned short* Bt = Btall + (long)(bz / bdiv) * Bs1 + (long)(bz % bdiv) * Bs2;
  long coff = (long)(bz / bdiv) * Cs1 + (long)(bz % bdiv) * Cs2;
  const float* rs = nullptr;
  if (EPI & EPI_RSCALE) rs = rsall + (long)(bz / bdiv) * Rs1 + (long)(bz % bdiv) * Rs2;

  int tid = threadIdx.x, wv = tid >> 6, ll = tid & 63;
  int m0 = blockIdx.x * 128, n0 = blockIdx.y * 128;
  int sr = tid >> 2, sc = (tid & 3) * 8;
  long ar0 = min(m0 + sr, Mr - 1), ar1 = min(m0 + sr + 64, Mr - 1);
  long br0 = min(n0 + sr, Nr - 1), br1 = min(n0 + sr + 64, Nr - 1);
  unsigned short* lA0 = &smA[(wv * 16) * 32];
  unsigned short* lA1 = &smA[(64 + wv * 16) * 32];
  unsigned short* lB0 = &smB[(wv * 16) * 32];
  unsigned short* lB1 = &smB[(64 + wv * 16) * 32];

  f32x4 acc[4][4] = {};
  int wr = (wv >> 1) * 64, wc = (wv & 1) * 64;
  int fr = ll & 15, fk = (ll >> 4) * 8;

  for (int k0 = 0; k0 < Kr; k0 += 32) {
    __syncthreads();
    gl_lds16(A + ar0 * lda + k0 + sc, lA0);
    gl_lds16(A + ar1 * lda + k0 + sc, lA1);
    gl_lds16(Bt + br0 * ldb + k0 + sc, lB0);
    gl_lds16(Bt + br1 * ldb + k0 + sc, lB1);
    __syncthreads();
    u16x8 af[4], bfr[4];
#pragma unroll
    for (int i = 0; i < 4; i++) {
      af[i] = *(const u16x8*)&smA[(wr + i * 16 + fr) * 32 + fk];
      bfr[i] = *(const u16x8*)&smB[(wc + i * 16 + fr) * 32 + fk];
    }
#pragma unroll
    for (int i = 0; i < 4; i++)
#pragma unroll
      for (int j = 0; j < 4; j++) acc[i][j] = mfma16(af[i], bfr[j], acc[i][j]);
  }

#pragma unroll
  for (int i = 0; i < 4; i++) {
#pragma unroll
    for (int j = 0; j < 4; j++) {
#pragma unroll
      for (int e = 0; e < 4; e++) {
        int gr = m0 + wr + i * 16 + (ll >> 4) * 4 + e;
        int gc = n0 + wc + j * 16 + (ll & 15);
        if (gr < Mr && gc < Nr) {
          float v = acc[i][j][e];
          if (EPI & EPI_BIAS) v += bias[gc];
          if (EPI & EPI_GELU) v = 0.5f * v * (1.0f + erff(v * 0.70710678118f));
          if (EPI & EPI_RSCALE) v *= rs[gr];
          long idx = coff + (long)gr * ldc + gc;
          if (EPI & EPI_ACCUM) v += ((float*)Call)[idx];
          if (EPI & EPI_OUTBF) ((unsigned short*)Call)[idx] = f2bu(v);
          else ((float*)Call)[idx] = v;
        }
      }
    }
  }
}

// ---------------- LayerNorm: fp32 in -> bf16 out ----------------
__global__ __launch_bounds__(256) void ln_k(const float* __restrict__ h,
                                            const float* __restrict__ g,
                                            const float* __restrict__ b,
                                            unsigned short* __restrict__ y) {
  int wv = threadIdx.x >> 6, ll = threadIdx.x & 63;
  long row = (long)blockIdx.x * 4 + wv;
  const float* hr = h + row * CDM;
  f32x4 x[4];
#pragma unroll
  for (int i = 0; i < 4; i++) x[i] = *(const f32x4*)&hr[ll * 16 + i * 4];
  float s = 0;
#pragma unroll
  for (int i = 0; i < 4; i++)
#pragma unroll
    for (int e = 0; e < 4; e++) s += x[i][e];
  float mu = wredsum(s) * (1.f / CDM);
  float v = 0;
#pragma unroll
  for (int i = 0; i < 4; i++)
#pragma unroll
    for (int e = 0; e < 4; e++) {
      float d = x[i][e] - mu;
      v += d * d;
    }
  float inv = rsqrtf(wredsum(v) * (1.f / CDM) + 1e-5f);
  unsigned short o[16];
#pragma unroll
  for (int i = 0; i < 4; i++)
#pragma unroll
    for (int e = 0; e < 4; e++) {
      int c = ll * 16 + i * 4 + e;
      o[i * 4 + e] = f2bu((x[i][e] - mu) * inv * g[c] + b[c]);
    }
  *(u16x8*)&y[row * CDM + ll * 16] = *(u16x8*)&o[0];
  *(u16x8*)&y[row * CDM + ll * 16 + 8] = *(u16x8*)&o[8];
}

// ---------------- FAVOR+ query features (q from fused qkv, stride 3072) ----------------
__global__ __launch_bounds__(256) void featq_k(const float* __restrict__ dd,
                                               const unsigned short* __restrict__ qb,
                                               unsigned short* __restrict__ qp) {
  int wv = threadIdx.x >> 6, ll = threadIdx.x & 63;
  long gid = (long)blockIdx.x * 4 + wv;  // (b*H+h)*T + t
  long bh = gid >> 10;
  int t = gid & 1023;
  int b = bh >> 4, hh = bh & 15;
  const float* dr = dd + gid * CM;
  f32x4 d4 = *(const f32x4*)&dr[ll * 4];
  float qv = b2f(qb[((long)b * CT + t) * CQKV + hh * CDH + ll]);
  float diag = wredsum(qv * qv) * (0.5f * CDN * CDN);
  float mx = fmaxf(fmaxf(d4[0], d4[1]), fmaxf(d4[2], d4[3]));
  mx = wredmax(mx);
  unsigned short o[4];
#pragma unroll
  for (int e = 0; e < 4; e++) o[e] = f2bu(CRATIO * (expf(d4[e] - diag - mx) + CKEPS));
  *(u16x4*)&qp[gid * CM + ll * 4] = *(u16x4*)&o[0];
}

// ---------------- key stabilizer partial max ----------------
__global__ __launch_bounds__(256) void stabp_k(const float* __restrict__ dd,
                                               float* __restrict__ part) {
  int bh = blockIdx.x >> 4, c = blockIdx.x & 15;
  const float* base = dd + ((long)bh * CT * CM) + (long)c * 16384;
  float mx = -3.4e38f;
#pragma unroll 4
  for (int it = 0; it < 16; it++) {
    f32x4 v = *(const f32x4*)&base[(it * 256 + threadIdx.x) * 4];
    mx = fmaxf(mx, fmaxf(fmaxf(v[0], v[1]), fmaxf(v[2], v[3])));
  }
  mx = wredmax(mx);
  __shared__ float sm[4];
  if ((threadIdx.x & 63) == 0) sm[threadIdx.x >> 6] = mx;
  __syncthreads();
  if (threadIdx.x == 0) part[blockIdx.x] = fmaxf(fmaxf(sm[0], sm[1]), fmaxf(sm[2], sm[3]));
}

// ---------------- key features, transposed out (k from fused qkv) ----------------
__global__ __launch_bounds__(256) void featk_k(const float* __restrict__ dd,
                                               const unsigned short* __restrict__ kb,
                                               const float* __restrict__ part,
                                               unsigned short* __restrict__ kpt) {
  int bh = blockIdx.x >> 5;
  int t0 = (blockIdx.x & 31) * 32;
  int b = bh >> 4, hh = bh & 15;
  float st = -3.4e38f;
#pragma unroll
  for (int i = 0; i < 16; i++) st = fmaxf(st, part[bh * 16 + i]);
  __shared__ unsigned short tile[32][256];
  int wv = threadIdx.x >> 6, ll = threadIdx.x & 63;
  for (int rr = 0; rr < 8; rr++) {
    int tr = wv * 8 + rr;
    int t = t0 + tr;
    const float* drr = dd + ((long)bh * CT + t) * CM;
    f32x4 d4 = *(const f32x4*)&drr[ll * 4];
    float kv = b2f(kb[((long)b * CT + t) * CQKV + hh * CDH + ll]);
    float diag = wredsum(kv * kv) * (0.5f * CDN * CDN);
#pragma unroll
    for (int e = 0; e < 4; e++)
      tile[tr][ll * 4 + e] = f2bu(CRATIO * (expf(d4[e] - diag - st) + CKEPS));
  }
  __syncthreads();
#pragma unroll
  for (int p = 0; p < 4; p++) {
    int m = p * 64 + (threadIdx.x >> 2);
    int tz = (threadIdx.x & 3) * 8;
    unsigned short o[8];
#pragma unroll
    for (int e = 0; e < 8; e++) o[e] = tile[tz + e][m];
    *(u16x8*)&kpt[((long)bh * CM + m) * CT + t0 + tz] = *(u16x8*)&o[0];
  }
}

// ---------------- v (from fused qkv) -> v_t (B,H,DH,T) ----------------
__global__ __launch_bounds__(256) void trv_k(const unsigned short* __restrict__ vb,
                                             unsigned short* __restrict__ vt) {
  int bh = blockIdx.x >> 5;
  int t0 = (blockIdx.x & 31) * 32;
  int b = bh >> 4, hh = bh & 15;
  __shared__ unsigned short tile[32][64];
  int tr = threadIdx.x >> 3, dblk = (threadIdx.x & 7) * 8;
  *(u16x8*)&tile[tr][dblk] = *(const u16x8*)&vb[((long)b * CT + t0 + tr) * CQKV + hh * CDH + dblk];
  __syncthreads();
  int d = threadIdx.x >> 2, tz = (threadIdx.x & 3) * 8;
  unsigned short o[8];
#pragma unroll
  for (int e = 0; e < 8; e++) o[e] = tile[tz + e][d];
  *(u16x8*)&vt[((long)bh * CDH + d) * CT + t0 + tz] = *(u16x8*)&o[0];
}

// ---------------- ksum[bh,m] = sum_t kp_t[bh,m,t] ----------------
__global__ __launch_bounds__(256) void ksum_k(const unsigned short* __restrict__ kpt,
                                              float* __restrict__ ksum) {
  int wv = threadIdx.x >> 6, ll = threadIdx.x & 63;
  long gid = (long)blockIdx.x * 4 + wv;
  const unsigned short* r = kpt + gid * CT;
  u16x8 a = *(const u16x8*)&r[ll * 16];
  u16x8 b = *(const u16x8*)&r[ll * 16 + 8];
  float s = 0;
#pragma unroll
  for (int e = 0; e < 8; e++) s += b2f(a[e]) + b2f(b[e]);
  s = wredsum(s);
  if (ll == 0) ksum[gid] = s;
}

// ---------------- dinv[bh,t] = 1 / (qp . ksum) ----------------
__global__ __launch_bounds__(256) void dinv_k(const unsigned short* __restrict__ qp,
                                              const float* __restrict__ ksum,
                                              float* __restrict__ dinv) {
  int wv = threadIdx.x >> 6, ll = threadIdx.x & 63;
  long gid = (long)blockIdx.x * 4 + wv;
  long bh = gid >> 10;
  const unsigned short* r = qp + gid * CM;
  const float* ks = ksum + bh * CM;
  u16x4 a = *(const u16x4*)&r[ll * 4];
  float s = 0;
#pragma unroll
  for (int e = 0; e < 4; e++) s += b2f(a[e]) * ks[ll * 4 + e];
  s = wredsum(s);
  if (ll == 0) dinv[gid] = 1.0f / s;
}

// ---------------- h += pe ----------------
__global__ __launch_bounds__(256) void addpe_k(float* __restrict__ h, const float* __restrict__ pe) {
  long i = ((long)blockIdx.x * 256 + threadIdx.x) * 4;
  int t = (int)((i >> 10) & 1023);
  int c = (int)(i & 1023);
  f32x4 v = *(f32x4*)&h[i];
  f32x4 p = *(const f32x4*)&pe[(long)t * 1024 + c];
  v += p;
  *(f32x4*)&h[i] = v;
}

// ---------------- fp32 -> bf16 flat ----------------
__global__ __launch_bounds__(256) void f2b_k(const float* __restrict__ in,
                                             unsigned short* __restrict__ out, long n) {
  long i = ((long)blockIdx.x * 256 + threadIdx.x) * 4;
  if (i >= n) return;
  f32x4 v = *(const f32x4*)&in[i];
  unsigned short o[4];
#pragma unroll
  for (int e = 0; e < 4; e++) o[e] = f2bu(v[e]);
  *(u16x4*)&out[i] = *(u16x4*)&o[0];
}

// ---------------- transpose-convert: in (R,C) fp32 -> out (C,R) bf16 ----------------
__global__ __launch_bounds__(256) void tconv_k(const float* __restrict__ in,
                                               unsigned short* __restrict__ out, int R, int C) {
  __shared__ float tile[32][33];
  int r0 = blockIdx.x * 32, c0 = blockIdx.y * 32;
  int tr = threadIdx.x >> 5, tc = threadIdx.x & 31;
#pragma unroll
  for (int p = 0; p < 4; p++) {
    int r = r0 + p * 8 + tr, c = c0 + tc;
    tile[p * 8 + tr][tc] = (r < R && c < C) ? in[(long)r * C + c] : 0.f;
  }
  __syncthreads();
#pragma unroll
  for (int p = 0; p < 4; p++) {
    int c = c0 + p * 8 + tr, r = r0 + tc;
    if (c < C && r < R) out[(long)c * R + r] = f2bu(tile[tc][p * 8 + tr]);
  }
}

// ---------------- Wconv (64,1024,3) -> per-tap (64,1024) bf16: [r][oc][ic] = (192,1024) ----------------
__global__ __launch_bounds__(256) void wconv_k(const float* __restrict__ W,
                                               unsigned short* __restrict__ out) {
  int idx = blockIdx.x * 256 + threadIdx.x;
  int r = idx >> 16, rem = idx & 65535, oc = rem >> 10, ic = rem & 1023;
  out[idx] = f2bu(W[oc * 3072 + ic * 3 + r]);
}

// ---------------- conv tap-mix: xa[t,oc] = Y[t-1,oc] + Y[t,64+oc] + Y[t+1,128+oc] + bconv ----------------
__global__ __launch_bounds__(256) void convmix_k(const float* __restrict__ Y,
                                                 const float* __restrict__ bc,
                                                 float* __restrict__ xa) {
  long t = (long)blockIdx.x * 4 + (threadIdx.x >> 6);
  int oc = threadIdx.x & 63;
  long tm = t > 0 ? t - 1 : 0, tp = t < CNT - 1 ? t + 1 : CNT - 1;  // boundary rows re-patched later
  float v = Y[tm * 192 + oc] + Y[t * 192 + 64 + oc] + Y[tp * 192 + 128 + oc] + bc[oc];
  xa[t * 64 + oc] = v;
}

// ---------------- proj * dn -> bf16 ----------------
__global__ __launch_bounds__(256) void projc_k(const float* __restrict__ p,
                                               unsigned short* __restrict__ out) {
  int i = blockIdx.x * 256 + threadIdx.x;
  out[i] = f2bu(p[i] * CDN);
}

// ---------------- concat q/k/v biases ----------------
__global__ __launch_bounds__(256) void catb_k(const float* __restrict__ q,
                                              const float* __restrict__ k,
                                              const float* __restrict__ v,
                                              float* __restrict__ o) {
  int i = blockIdx.x * 256 + threadIdx.x;  // < 3072
  o[i] = i < 1024 ? q[i] : (i < 2048 ? k[i - 1024] : v[i - 2048]);
}

// ---------------- exact conv recompute at batch boundaries ----------------
__global__ __launch_bounds__(256) void patch_k(const float* __restrict__ h,
                                               const float* __restrict__ W,
                                               const float* __restrict__ bc,
                                               float* __restrict__ xa) {
  int b = blockIdx.x >> 1;
  int t = (blockIdx.x & 1) ? (CT - 1) : 0;
  int oc = threadIdx.x & 63, ch = threadIdx.x >> 6;
  float s = 0;
  for (int r = 0; r < 3; r++) {
    int tt = t + r - 1;
    if (tt < 0 || tt >= CT) continue;
    const float* hr = h + ((long)b * CT + tt) * CDM;
    const float* wr = W + oc * 3072 + r;
    for (int ic = ch * 256; ic < ch * 256 + 256; ic++) s += hr[ic] * wr[ic * 3];
  }
  __shared__ float sm[256];
  sm[threadIdx.x] = s;
  __syncthreads();
  if (threadIdx.x < 64) {
    float tot = sm[oc] + sm[64 + oc] + sm[128 + oc] + sm[192 + oc] + bc[oc];
    xa[((long)b * CT + t) * 64 + oc] = tot;
  }
}

#define LAUNCH_GEMM(EPI, A, Bt, bias, C, rsp, Mr, Nr, Kr, lda, ldb, ldc, nb, bdiv, As1, As2, Bs1, Bs2, Cs1, Cs2, Rs1, Rs2) \
  gemm_k<EPI><<<dim3(((Mr) + 127) / 128, ((Nr) + 127) / 128, (nb)), 256, 0, stream>>>(           \
      (const unsigned short*)(A), (const unsigned short*)(Bt), (bias), (void*)(C), (rsp),        \
      (Mr), (Nr), (Kr), (lda), (ldb), (ldc), (bdiv), (long)(As1), (long)(As2), (long)(Bs1),      \
      (long)(Bs2), (long)(Cs1), (long)(Cs2), (long)(Rs1), (long)(Rs2))

#define LAUNCH_G8(TMX, EPI, A, Bt, bias, C, Mr, Nr, Kr, lda, ldb, ldc)                           \
  gemm8_k<TMX, EPI><<<dim3(((Mr) + (TMX)-1) / (TMX), ((Nr) + 255) / 256), 512, 0, stream>>>(     \
      (const unsigned short*)(A), (const unsigned short*)(Bt), (bias), (void*)(C),               \
      (Mr), (Nr), (Kr), (lda), (ldb), (ldc))

extern "C" void kernel_launch(void* const* d_in, const int* in_sizes, int n_in,
                              void* d_out, int out_size, void* d_ws, size_t ws_size,
                              hipStream_t stream) {
  const float* x = (const float*)d_in[0];
  const float* Win = (const float*)d_in[1];
  const float* b_in = (const float*)d_in[2];
  const float* pe = (const float*)d_in[3];
  const float* ln1_g = (const float*)d_in[4];
  const float* ln1_b = (const float*)d_in[5];
  const float* Wq = (const float*)d_in[6];
  const float* bq = (const float*)d_in[7];
  const float* Wk = (const float*)d_in[8];
  const float* bk = (const float*)d_in[9];
  const float* Wv = (const float*)d_in[10];
  const float* bv = (const float*)d_in[11];
  const float* Wo = (const float*)d_in[12];
  const float* bo = (const float*)d_in[13];
  const float* ln2_g = (const float*)d_in[14];
  const float* ln2_b = (const float*)d_in[15];
  const float* W1 = (const float*)d_in[16];
  const float* b1 = (const float*)d_in[17];
  const float* W2 = (const float*)d_in[18];
  const float* b2 = (const float*)d_in[19];
  const float* Wc = (const float*)d_in[20];
  const float* bc = (const float*)d_in[21];
  const float* Wconv = (const float*)d_in[22];
  const float* bconv = (const float*)d_in[23];
  const float* Waux = (const float*)d_in[24];
  const float* baux = (const float*)d_in[25];
  const float* proj = (const float*)d_in[26];
  float* out = (float*)d_out;

  char* wsp = (char*)d_ws;
  size_t off = 0;
  auto take = [&](size_t bytes) {
    char* p = wsp + off;
    off = (off + bytes + 255) & ~(size_t)255;
    return p;
  };
  float* h_f = (float*)take(33554432);                      // (8192,1024) fp32 residual
  unsigned short* y_bf = (unsigned short*)take(16777216);   // LN out; aliased: vt, o
  unsigned short* qkv_bf = (unsigned short*)take(50331648); // (8192,3072) fused q,k,v
  float* dd_f = (float*)take(134217728);                    // (B,H,T,M) fp32; aliased: ff_bf
  unsigned short* qp_bf = (unsigned short*)take(67108864);  // (B,H,T,M)
  unsigned short* kpt_bf = (unsigned short*)take(67108864); // (B,H,M,T)
  unsigned short* ctx_bf = (unsigned short*)take(4194304);  // (B,H,DH,M)
  float* ksum_f = (float*)take(131072);
  float* dinv_f = (float*)take(524288);
  float* stab_f = (float*)take(8192);
  float* xa_f = (float*)take(2097152);
  float* ycv_f = (float*)take(6291456);                     // (8192,192) conv taps
  unsigned short* xabf = (unsigned short*)take(1048576);
  float* bqkv_f = (float*)take(24576);                      // 2 layers x 3072
  unsigned short* hbf = (unsigned short*)take(16777216);
  unsigned short* xbf = (unsigned short*)take(4194304);
  unsigned short* win_t = (unsigned short*)take(524288);
  unsigned short* wqkvo_t = (unsigned short*)take(16777216);
  unsigned short* w1_t = (unsigned short*)take(16777216);
  unsigned short* w2_t = (unsigned short*)take(16777216);
  unsigned short* wc_t = (unsigned short*)take(4096000);
  unsigned short* projc = (unsigned short*)take(32768);
  unsigned short* wconv_t = (unsigned short*)take(393216);
  unsigned short* waux_t = (unsigned short*)take(256128);
  unsigned short* ff_bf = (unsigned short*)dd_f;   // alias
  unsigned short* vt_bf = y_bf;                    // alias (y dead after QKV)
  unsigned short* o_bf = y_bf;                     // alias (vt dead after ctx)
  (void)in_sizes; (void)n_in; (void)out_size; (void)ws_size;

  // ---- weight conversion ----
  f2b_k<<<2048, 256, 0, stream>>>(x, xbf, (long)CNT * 256);
  tconv_k<<<dim3(8, 32), 256, 0, stream>>>(Win, win_t, 256, 1024);
  for (int l = 0; l < 2; l++) {
    tconv_k<<<dim3(32, 32), 256, 0, stream>>>(Wq + (long)l * 1048576, wqkvo_t + (long)(l * 4 + 0) * 1048576, 1024, 1024);
    tconv_k<<<dim3(32, 32), 256, 0, stream>>>(Wk + (long)l * 1048576, wqkvo_t + (long)(l * 4 + 1) * 1048576, 1024, 1024);
    tconv_k<<<dim3(32, 32), 256, 0, stream>>>(Wv + (long)l * 1048576, wqkvo_t + (long)(l * 4 + 2) * 1048576, 1024, 1024);
    tconv_k<<<dim3(32, 32), 256, 0, stream>>>(Wo + (long)l * 1048576, wqkvo_t + (long)(l * 4 + 3) * 1048576, 1024, 1024);
    tconv_k<<<dim3(32, 128), 256, 0, stream>>>(W1 + (long)l * 4194304, w1_t + (long)l * 4194304, 1024, 4096);
    tconv_k<<<dim3(128, 32), 256, 0, stream>>>(W2 + (long)l * 4194304, w2_t + (long)l * 4194304, 4096, 1024);
    catb_k<<<12, 256, 0, stream>>>(bq + l * CDM, bk + l * CDM, bv + l * CDM, bqkv_f + l * CQKV);
  }
  tconv_k<<<dim3(32, 63), 256, 0, stream>>>(Wc, wc_t, 1024, 2000);
  tconv_k<<<dim3(2, 63), 256, 0, stream>>>(Waux, waux_t, 64, 2001);
  wconv_k<<<768, 256, 0, stream>>>(Wconv, wconv_t);
  projc_k<<<64, 256, 0, stream>>>(proj, projc);

  // ---- embed ----
  LAUNCH_G8(128, EPI_BIAS, xbf, win_t, b_in, h_f, CNT, CDM, 256, 256, 256, CDM);
  addpe_k<<<8192, 256, 0, stream>>>(h_f, pe);

  for (int l = 0; l < 2; l++) {
    const unsigned short* wqkv_t = wqkvo_t + (long)(l * 4) * 1048576;  // q,k,v adjacent: 3072 x 1024
    const unsigned short* wo_t = wqkvo_t + (long)(l * 4 + 3) * 1048576;

    ln_k<<<2048, 256, 0, stream>>>(h_f, ln1_g + l * CDM, ln1_b + l * CDM, y_bf);
    // fused QKV: (8192,1024) x (3072,1024)^T -> (8192,3072) bf16
    LAUNCH_G8(256, EPI_BIAS | EPI_OUTBF, y_bf, wqkv_t, bqkv_f + l * CQKV, qkv_bf, CNT, CQKV, CDM, CDM, CDM, CQKV);

    // dd = q @ (proj*dn)^T, batched over (b,h)
    LAUNCH_GEMM(0, qkv_bf, projc, nullptr, dd_f, nullptr, CT, CM, CDH, CQKV, CDH, CM, 128, CH,
                (long)CT * CQKV, 64, 0, 0, (long)CH * CT * CM, (long)CT * CM, 0, 0);
    featq_k<<<32768, 256, 0, stream>>>(dd_f, qkv_bf, qp_bf);
    LAUNCH_GEMM(0, qkv_bf + 1024, projc, nullptr, dd_f, nullptr, CT, CM, CDH, CQKV, CDH, CM, 128, CH,
                (long)CT * CQKV, 64, 0, 0, (long)CH * CT * CM, (long)CT * CM, 0, 0);
    stabp_k<<<2048, 256, 0, stream>>>(dd_f, stab_f);
    featk_k<<<4096, 256, 0, stream>>>(dd_f, qkv_bf + 1024, stab_f, kpt_bf);
    trv_k<<<4096, 256, 0, stream>>>(qkv_bf + 2048, vt_bf);
    ksum_k<<<8192, 256, 0, stream>>>(kpt_bf, ksum_f);
    // ctx^T (DH,M) = v^T @ kp, batched
    LAUNCH_GEMM(EPI_OUTBF, vt_bf, kpt_bf, nullptr, ctx_bf, nullptr, CDH, CM, CT, CT, CT, CM, 128, CH,
                (long)CH * CDH * CT, (long)CDH * CT, (long)CH * CM * CT, (long)CM * CT,
                (long)CH * CDH * CM, (long)CDH * CM, 0, 0);
    dinv_k<<<32768, 256, 0, stream>>>(qp_bf, ksum_f, dinv_f);
    // o = (qp @ ctx) * dinv -> (B,T,H*DH) bf16 (overwrites vt alias after ctx done)
    LAUNCH_GEMM(EPI_RSCALE | EPI_OUTBF, qp_bf, ctx_bf, nullptr, o_bf, dinv_f, CT, CDH, CM, CM, CM, CDM, 128, CH,
                (long)CH * CT * CM, (long)CT * CM, (long)CH * CDH * CM, (long)CDH * CM,
                (long)CT * CDM, 64, (long)CH * CT, (long)CT);
    LAUNCH_G8(128, EPI_BIAS | EPI_ACCUM, o_bf, wo_t, bo + l * CDM, h_f, CNT, CDM, CDM, CDM, CDM, CDM);

    ln_k<<<2048, 256, 0, stream>>>(h_f, ln2_g + l * CDM, ln2_b + l * CDM, y_bf);
    LAUNCH_G8(256, EPI_BIAS | EPI_GELU | EPI_OUTBF, y_bf, w1_t + (long)l * 4194304, b1 + l * CDFF, ff_bf,
              CNT, CDFF, CDM, CDM, CDM, CDFF);
    LAUNCH_G8(128, EPI_BIAS | EPI_ACCUM, ff_bf, w2_t + (long)l * 4194304, b2 + l * CDM, h_f,
              CNT, CDM, CDFF, CDFF, CDFF, CDM);

    if (l == 0) {
      // conv1d: single N=192 GEMM over all 3 taps, then shift-add mix + exact boundary patch
      f2b_k<<<8192, 256, 0, stream>>>(h_f, hbf, (long)CNT * CDM);
      LAUNCH_GEMM(0, hbf, wconv_t, nullptr, ycv_f, nullptr, CNT, 192, CDM, CDM, CDM, 192, 1, 1, 0, 0, 0, 0, 0, 0, 0, 0);
      convmix_k<<<2048, 256, 0, stream>>>(ycv_f, bconv, xa_f);
      patch_k<<<16, 256, 0, stream>>>(h_f, Wconv, bconv, xa_f);
      f2b_k<<<512, 256, 0, stream>>>(xa_f, xabf, (long)CNT * 64);
      LAUNCH_GEMM(EPI_BIAS, xabf, waux_t, baux, out + 16384000, nullptr, CNT, CV + 1, 64, 64, 64, CV + 1, 1, 1, 0, 0, 0, 0, 0, 0, 0, 0);
    }
  }

  // ---- classifier ----
  f2b_k<<<8192, 256, 0, stream>>>(h_f, hbf, (long)CNT * CDM);
  LAUNCH_G8(256, EPI_BIAS, hbf, wc_t, bc, out, CNT, CV, CDM, CDM, CDM, CV);
}

// Round 5
// 1585.694 us; speedup vs baseline: 1.2016x; 1.0065x over previous
//
#include <hip/hip_runtime.h>
#include <hip/hip_bf16.h>

typedef __attribute__((ext_vector_type(4))) float f32x4;
typedef __attribute__((ext_vector_type(8))) unsigned short u16x8;
typedef __attribute__((ext_vector_type(4))) unsigned short u16x4;
typedef __bf16 bf16x8 __attribute__((ext_vector_type(8)));

#define DEVFN static __device__ __forceinline__

constexpr int CB = 8, CT = 1024, CDM = 1024, CH = 16, CDH = 64, CDFF = 4096, CV = 2000, CM = 256;
constexpr int CNT = CB * CT; // 8192 tokens
constexpr int CQKV = 3072;   // fused qkv row stride
constexpr float CDN = 0.35355339059327373f;   // 64^-0.25
constexpr float CRATIO = 0.0625f;             // 256^-0.5
constexpr float CKEPS = 1e-4f;

DEVFN unsigned short f2bu(float x) {
  __hip_bfloat16 h = __float2bfloat16(x);
  return __builtin_bit_cast(unsigned short, h);
}
DEVFN float b2f(unsigned short u) {
  __hip_bfloat16 h = __builtin_bit_cast(__hip_bfloat16, u);
  return __bfloat162float(h);
}
DEVFN float wredsum(float s) {
#pragma unroll
  for (int ofs = 32; ofs; ofs >>= 1) s += __shfl_xor(s, ofs, 64);
  return s;
}
DEVFN float wredmax(float s) {
#pragma unroll
  for (int ofs = 32; ofs; ofs >>= 1) s = fmaxf(s, __shfl_xor(s, ofs, 64));
  return s;
}
DEVFN void gl_lds16(const void* g, void* l) {
  __builtin_amdgcn_global_load_lds(
      (const __attribute__((address_space(1))) unsigned int*)g,
      (__attribute__((address_space(3))) unsigned int*)l, 16, 0, 0);
}
DEVFN f32x4 mfma16(u16x8 a, u16x8 b, f32x4 c) {
  return __builtin_amdgcn_mfma_f32_16x16x32_bf16(
      __builtin_bit_cast(bf16x8, a), __builtin_bit_cast(bf16x8, b), c, 0, 0, 0);
}
// compiler-invisible LDS read; waits are manual (counted lgkmcnt)
DEVFN u16x8 lds_rd128(unsigned addr) {
  u16x8 r;
  asm volatile("ds_read_b128 %0, %1" : "=v"(r) : "v"(addr));
  return r;
}
DEVFN unsigned lds_addr(const void* p) {
  return (unsigned)(unsigned long)(const __attribute__((address_space(3))) char*)p;
}

#define EPI_BIAS 1
#define EPI_ACCUM 2
#define EPI_GELU 4
#define EPI_OUTBF 8
#define EPI_RSCALE 16

// ================= big GEMM: C = A(M,K) * Bt(N,K)^T =================
// TMx x 256 tile, BK=64, 8 waves (2Mx4N), 2 LDS buffers, st-swizzle.
// m201-style schedule: 4 phases per K-tile, each
//   {ds_read subtile | stage 2 next-tile loads | s_barrier | lgkmcnt(0) |
//    setprio(1) 16xMFMA setprio(0) | s_barrier}
// single counted vmcnt(2) per tile at q0 (retires prev tile's ST loads).
template <int TMx, int EPI>
__global__ __launch_bounds__(512, 2) void gemm8_k(
    const unsigned short* __restrict__ A, const unsigned short* __restrict__ Bt,
    const float* __restrict__ bias, void* __restrict__ C,
    int Mr, int Nr, int Kr, int lda, int ldb, int ldc) {
  constexpr int AR = TMx * 64 / 4096;  // A staging rounds (4 or 2)
  constexpr int BR = 4;                // B staging rounds
  constexpr int ST = AR + BR;
  constexpr int MREP = TMx / 32;       // per-wave m-fragments (8 or 4)
  __shared__ unsigned short smA[2][TMx * 64];
  __shared__ unsigned short smB[2][256 * 64];

  int tid = threadIdx.x, wv = tid >> 6, ll = tid & 63;
  int wm = wv >> 2, wn = wv & 3;  // 2 x 4 wave grid
  int m0 = blockIdx.x * TMx, n0 = blockIdx.y * 256;
  int fr = ll & 15, f16 = ll >> 4, fk = f16 * 8;

  const char* Ab = (const char*)A;
  const char* Bb = (const char*)Bt;

  // staging source byte offsets (inverse-swizzled: linear LDS dest + swizzled read)
  unsigned int offA[AR], offB[BR];
#pragma unroll
  for (int ro = 0; ro < AR; ro++) {
    int L = (ro * 512 + tid) * 16;
    int P = L ^ (((L >> 9) & 1) << 5);
    int kh = P / (TMx * 64), rem = P % (TMx * 64);
    int r = rem >> 6, cb = rem & 63;
    long row = min(m0 + r, Mr - 1);
    offA[ro] = (unsigned int)((row * lda + kh * 32) * 2 + cb);
  }
#pragma unroll
  for (int ro = 0; ro < BR; ro++) {
    int L = (ro * 512 + tid) * 16;
    int P = L ^ (((L >> 9) & 1) << 5);
    int kh = P / 16384, rem = P & 16383;
    int r = rem >> 6, cb = rem & 63;
    long row = min(n0 + r, Nr - 1);
    offB[ro] = (unsigned int)((row * ldb + kh * 32) * 2 + cb);
  }
  // fragment LDS byte addresses (buf0, ks0), swizzled
  unsigned aAb = lds_addr(&smA[0][0]);
  unsigned aBb = lds_addr(&smB[0][0]);
  unsigned offArd[MREP], offBrd[4];
#pragma unroll
  for (int i = 0; i < MREP; i++) {
    int r = wm * (TMx / 2) + i * 16 + fr;
    offArd[i] = aAb + (unsigned)(r * 64 + 2 * (fk ^ (((r >> 3) & 1) << 4)));
  }
#pragma unroll
  for (int j = 0; j < 4; j++) {
    int r = wn * 64 + j * 16 + fr;
    offBrd[j] = aBb + (unsigned)(r * 64 + 2 * (fk ^ (((r >> 3) & 1) << 4)));
  }

  f32x4 acc[MREP][4] = {};
  int NT = Kr / 64;  // even for all our shapes

  // prologue: stage tile 0 into buf 0
#pragma unroll
  for (int ro = 0; ro < ST; ro++) {
    if (ro < AR)
      gl_lds16(Ab + offA[ro], &smA[0][(ro * 512 + wv * 64) * 8]);
    else
      gl_lds16(Bb + offB[ro - AR], &smB[0][((ro - AR) * 512 + wv * 64) * 8]);
  }

#define BARR()                                                              \
  {                                                                         \
    __builtin_amdgcn_s_barrier();                                           \
    __builtin_amdgcn_sched_barrier(0);                                      \
  }
#define LGKM0()                                                             \
  {                                                                         \
    asm volatile("s_waitcnt lgkmcnt(0)" ::: "memory");                      \
    __builtin_amdgcn_sched_barrier(0);                                      \
  }
// stage the Q-th pair of next-tile loads (ST=8: {0,1}{2,3}{4,5}{6,7};
// ST=6: {0,1}{2,3}{4}{5})
#define STGPH(PB, Q, KBN)                                                   \
  {                                                                         \
    constexpr int lo = (ST == 8) ? (Q)*2 : ((Q) < 2 ? (Q)*2 : (Q) + 2);     \
    constexpr int hi = (ST == 8) ? (Q)*2 + 2 : ((Q) < 2 ? (Q)*2 + 2 : (Q) + 3); \
    _Pragma("unroll") for (int ro = lo; ro < hi; ro++) {                    \
      if (ro < AR)                                                          \
        gl_lds16(Ab + offA[ro] + (KBN), &smA[PB][(ro * 512 + wv * 64) * 8]);\
      else                                                                  \
        gl_lds16(Bb + offB[ro - AR] + (KBN),                                \
                 &smB[PB][((ro - AR) * 512 + wv * 64) * 8]);                \
    }                                                                       \
  }
#define RDA_PH(PB, KS)                                                      \
  {                                                                         \
    _Pragma("unroll") for (int i = 0; i < MREP; i++)                        \
        afr[i] = lds_rd128(offArd[i] + (PB) * (TMx * 128) + (KS) * (TMx * 64)); \
  }
#define RDB_PH(PB, KS, JH)                                                  \
  {                                                                         \
    bq0 = lds_rd128(offBrd[(JH)*2] + (PB)*32768 + (KS)*16384);              \
    bq1 = lds_rd128(offBrd[(JH)*2 + 1] + (PB)*32768 + (KS)*16384);          \
  }
#define MFMA_PH(JH)                                                         \
  {                                                                         \
    __builtin_amdgcn_s_setprio(1);                                          \
    _Pragma("unroll") for (int i = 0; i < MREP; i++) {                      \
      acc[i][(JH)*2] = mfma16(afr[i], bq0, acc[i][(JH)*2]);                 \
      acc[i][(JH)*2 + 1] = mfma16(afr[i], bq1, acc[i][(JH)*2 + 1]);         \
    }                                                                       \
    __builtin_amdgcn_s_setprio(0);                                          \
  }
#define TILE(PB, KBN)                                                       \
  {                                                                         \
    /* q0: gate buf PB ready, then (ks0,jh0) */                             \
    STGPH((PB) ^ 1, 0, KBN);                                                \
    asm volatile("s_waitcnt vmcnt(2)" ::: "memory");                        \
    __builtin_amdgcn_sched_barrier(0);                                      \
    BARR();                                                                 \
    RDA_PH(PB, 0);                                                          \
    RDB_PH(PB, 0, 0);                                                       \
    LGKM0();                                                                \
    MFMA_PH(0);                                                             \
    BARR();                                                                 \
    /* q1: (ks0,jh1) */                                                     \
    RDB_PH(PB, 0, 1);                                                       \
    STGPH((PB) ^ 1, 1, KBN);                                                \
    BARR();                                                                 \
    LGKM0();                                                                \
    MFMA_PH(1);                                                             \
    BARR();                                                                 \
    /* q2: (ks1,jh0) */                                                     \
    RDA_PH(PB, 1);                                                          \
    RDB_PH(PB, 1, 0);                                                       \
    STGPH((PB) ^ 1, 2, KBN);                                                \
    BARR();                                                                 \
    LGKM0();                                                                \
    MFMA_PH(0);                                                             \
    BARR();                                                                 \
    /* q3: (ks1,jh1) */                                                     \
    RDB_PH(PB, 1, 1);                                                       \
    STGPH((PB) ^ 1, 3, KBN);                                                \
    BARR();                                                                 \
    LGKM0();                                                                \
    MFMA_PH(1);                                                             \
    BARR();                                                                 \
  }

  u16x8 afr[MREP], bq0, bq1;
  for (int t = 0; t < NT; t += 2) {
    long kb1 = (long)(t + 1) * 128;
    long kb2 = (long)min(t + 2, NT - 1) * 128;
    TILE(0, kb1);  // compute tile t from buf0; stage t+1 -> buf1
    TILE(1, kb2);  // compute tile t+1 from buf1; stage t+2 -> buf0
  }
  asm volatile("s_waitcnt vmcnt(0)" ::: "memory");
  __builtin_amdgcn_sched_barrier(0);
#undef TILE
#undef MFMA_PH
#undef RDB_PH
#undef RDA_PH
#undef STGPH
#undef LGKM0
#undef BARR

  // ---- epilogue ----
#pragma unroll
  for (int i = 0; i < MREP; i++) {
#pragma unroll
    for (int j = 0; j < 4; j++) {
#pragma unroll
      for (int e = 0; e < 4; e++) {
        int gr = m0 + wm * (TMx / 2) + i * 16 + f16 * 4 + e;
        int gc = n0 + wn * 64 + j * 16 + fr;
        if (gr < Mr && gc < Nr) {
          float v = acc[i][j][e];
          if (EPI & EPI_BIAS) v += bias[gc];
          if (EPI & EPI_GELU) v = 0.5f * v * (1.0f + erff(v * 0.70710678118f));
          long idx = (long)gr * ldc + gc;
          if (EPI & EPI_ACCUM) v += ((float*)C)[idx];
          if (EPI & EPI_OUTBF) ((unsigned short*)C)[idx] = f2bu(v);
          else ((float*)C)[idx] = v;
        }
      }
    }
  }
}

// ================= legacy 128x128 GEMM (small/batched shapes) =================
template <int EPI>
__global__ __launch_bounds__(256) void gemm_k(
    const unsigned short* __restrict__ Aall, const unsigned short* __restrict__ Btall,
    const float* __restrict__ bias, void* __restrict__ Call, const float* __restrict__ rsall,
    int Mr, int Nr, int Kr, int lda, int ldb, int ldc, int bdiv,
    long As1, long As2, long Bs1, long Bs2, long Cs1, long Cs2, long Rs1, long Rs2) {
  __shared__ unsigned short smA[128 * 32];
  __shared__ unsigned short smB[128 * 32];
  int bz = blockIdx.z;
  const unsigned short* A = Aall + (long)(bz / bdiv) * As1 + (long)(bz % bdiv) * As2;
  const unsigned short* Bt = Btall + (long)(bz / bdiv) * Bs1 + (long)(bz % bdiv) * Bs2;
  long coff = (long)(bz / bdiv) * Cs1 + (long)(bz % bdiv) * Cs2;
  const float* rs = nullptr;
  if (EPI & EPI_RSCALE) rs = rsall + (long)(bz / bdiv) * Rs1 + (long)(bz % bdiv) * Rs2;

  int tid = threadIdx.x, wv = tid >> 6, ll = tid & 63;
  int m0 = blockIdx.x * 128, n0 = blockIdx.y * 128;
  int sr = tid >> 2, sc = (tid & 3) * 8;
  long ar0 = min(m0 + sr, Mr - 1), ar1 = min(m0 + sr + 64, Mr - 1);
  long br0 = min(n0 + sr, Nr - 1), br1 = min(n0 + sr + 64, Nr - 1);
  unsigned short* lA0 = &smA[(wv * 16) * 32];
  unsigned short* lA1 = &smA[(64 + wv * 16) * 32];
  unsigned short* lB0 = &smB[(wv * 16) * 32];
  unsigned short* lB1 = &smB[(64 + wv * 16) * 32];

  f32x4 acc[4][4] = {};
  int wr = (wv >> 1) * 64, wc = (wv & 1) * 64;
  int fr = ll & 15, fk = (ll >> 4) * 8;

  for (int k0 = 0; k0 < Kr; k0 += 32) {
    __syncthreads();
    gl_lds16(A + ar0 * lda + k0 + sc, lA0);
    gl_lds16(A + ar1 * lda + k0 + sc, lA1);
    gl_lds16(Bt + br0 * ldb + k0 + sc, lB0);
    gl_lds16(Bt + br1 * ldb + k0 + sc, lB1);
    __syncthreads();
    u16x8 af[4], bfr[4];
#pragma unroll
    for (int i = 0; i < 4; i++) {
      af[i] = *(const u16x8*)&smA[(wr + i * 16 + fr) * 32 + fk];
      bfr[i] = *(const u16x8*)&smB[(wc + i * 16 + fr) * 32 + fk];
    }
#pragma unroll
    for (int i = 0; i < 4; i++)
#pragma unroll
      for (int j = 0; j < 4; j++) acc[i][j] = mfma16(af[i], bfr[j], acc[i][j]);
  }

#pragma unroll
  for (int i = 0; i < 4; i++) {
#pragma unroll
    for (int j = 0; j < 4; j++) {
#pragma unroll
      for (int e = 0; e < 4; e++) {
        int gr = m0 + wr + i * 16 + (ll >> 4) * 4 + e;
        int gc = n0 + wc + j * 16 + (ll & 15);
        if (gr < Mr && gc < Nr) {
          float v = acc[i][j][e];
          if (EPI & EPI_BIAS) v += bias[gc];
          if (EPI & EPI_GELU) v = 0.5f * v * (1.0f + erff(v * 0.70710678118f));
          if (EPI & EPI_RSCALE) v *= rs[gr];
          long idx = coff + (long)gr * ldc + gc;
          if (EPI & EPI_ACCUM) v += ((float*)Call)[idx];
          if (EPI & EPI_OUTBF) ((unsigned short*)Call)[idx] = f2bu(v);
          else ((float*)Call)[idx] = v;
        }
      }
    }
  }
}

// ---------------- LayerNorm: fp32 in -> bf16 out ----------------
__global__ __launch_bounds__(256) void ln_k(const float* __restrict__ h,
                                            const float* __restrict__ g,
                                            const float* __restrict__ b,
                                            unsigned short* __restrict__ y) {
  int wv = threadIdx.x >> 6, ll = threadIdx.x & 63;
  long row = (long)blockIdx.x * 4 + wv;
  const float* hr = h + row * CDM;
  f32x4 x[4];
#pragma unroll
  for (int i = 0; i < 4; i++) x[i] = *(const f32x4*)&hr[ll * 16 + i * 4];
  float s = 0;
#pragma unroll
  for (int i = 0; i < 4; i++)
#pragma unroll
    for (int e = 0; e < 4; e++) s += x[i][e];
  float mu = wredsum(s) * (1.f / CDM);
  float v = 0;
#pragma unroll
  for (int i = 0; i < 4; i++)
#pragma unroll
    for (int e = 0; e < 4; e++) {
      float d = x[i][e] - mu;
      v += d * d;
    }
  float inv = rsqrtf(wredsum(v) * (1.f / CDM) + 1e-5f);
  unsigned short o[16];
#pragma unroll
  for (int i = 0; i < 4; i++)
#pragma unroll
    for (int e = 0; e < 4; e++) {
      int c = ll * 16 + i * 4 + e;
      o[i * 4 + e] = f2bu((x[i][e] - mu) * inv * g[c] + b[c]);
    }
  *(u16x8*)&y[row * CDM + ll * 16] = *(u16x8*)&o[0];
  *(u16x8*)&y[row * CDM + ll * 16 + 8] = *(u16x8*)&o[8];
}

// ---------------- FAVOR+ query features (q from fused qkv, stride 3072) ----------------
__global__ __launch_bounds__(256) void featq_k(const float* __restrict__ dd,
                                               const unsigned short* __restrict__ qb,
                                               unsigned short* __restrict__ qp) {
  int wv = threadIdx.x >> 6, ll = threadIdx.x & 63;
  long gid = (long)blockIdx.x * 4 + wv;  // (b*H+h)*T + t
  long bh = gid >> 10;
  int t = gid & 1023;
  int b = bh >> 4, hh = bh & 15;
  const float* dr = dd + gid * CM;
  f32x4 d4 = *(const f32x4*)&dr[ll * 4];
  float qv = b2f(qb[((long)b * CT + t) * CQKV + hh * CDH + ll]);
  float diag = wredsum(qv * qv) * (0.5f * CDN * CDN);
  float mx = fmaxf(fmaxf(d4[0], d4[1]), fmaxf(d4[2], d4[3]));
  mx = wredmax(mx);
  unsigned short o[4];
#pragma unroll
  for (int e = 0; e < 4; e++) o[e] = f2bu(CRATIO * (expf(d4[e] - diag - mx) + CKEPS));
  *(u16x4*)&qp[gid * CM + ll * 4] = *(u16x4*)&o[0];
}

// ---------------- key stabilizer partial max ----------------
__global__ __launch_bounds__(256) void stabp_k(const float* __restrict__ dd,
                                               float* __restrict__ part) {
  int bh = blockIdx.x >> 4, c = blockIdx.x & 15;
  const float* base = dd + ((long)bh * CT * CM) + (long)c * 16384;
  float mx = -3.4e38f;
#pragma unroll 4
  for (int it = 0; it < 16; it++) {
    f32x4 v = *(const f32x4*)&base[(it * 256 + threadIdx.x) * 4];
    mx = fmaxf(mx, fmaxf(fmaxf(v[0], v[1]), fmaxf(v[2], v[3])));
  }
  mx = wredmax(mx);
  __shared__ float sm[4];
  if ((threadIdx.x & 63) == 0) sm[threadIdx.x >> 6] = mx;
  __syncthreads();
  if (threadIdx.x == 0) part[blockIdx.x] = fmaxf(fmaxf(sm[0], sm[1]), fmaxf(sm[2], sm[3]));
}

// ---------------- key features, transposed out (k from fused qkv) ----------------
__global__ __launch_bounds__(256) void featk_k(const float* __restrict__ dd,
                                               const unsigned short* __restrict__ kb,
                                               const float* __restrict__ part,
                                               unsigned short* __restrict__ kpt) {
  int bh = blockIdx.x >> 5;
  int t0 = (blockIdx.x & 31) * 32;
  int b = bh >> 4, hh = bh & 15;
  float st = -3.4e38f;
#pragma unroll
  for (int i = 0; i < 16; i++) st = fmaxf(st, part[bh * 16 + i]);
  __shared__ unsigned short tile[32][256];
  int wv = threadIdx.x >> 6, ll = threadIdx.x & 63;
  for (int rr = 0; rr < 8; rr++) {
    int tr = wv * 8 + rr;
    int t = t0 + tr;
    const float* drr = dd + ((long)bh * CT + t) * CM;
    f32x4 d4 = *(const f32x4*)&drr[ll * 4];
    float kv = b2f(kb[((long)b * CT + t) * CQKV + hh * CDH + ll]);
    float diag = wredsum(kv * kv) * (0.5f * CDN * CDN);
#pragma unroll
    for (int e = 0; e < 4; e++)
      tile[tr][ll * 4 + e] = f2bu(CRATIO * (expf(d4[e] - diag - st) + CKEPS));
  }
  __syncthreads();
#pragma unroll
  for (int p = 0; p < 4; p++) {
    int m = p * 64 + (threadIdx.x >> 2);
    int tz = (threadIdx.x & 3) * 8;
    unsigned short o[8];
#pragma unroll
    for (int e = 0; e < 8; e++) o[e] = tile[tz + e][m];
    *(u16x8*)&kpt[((long)bh * CM + m) * CT + t0 + tz] = *(u16x8*)&o[0];
  }
}

// ---------------- v (from fused qkv) -> v_t (B,H,DH,T) ----------------
__global__ __launch_bounds__(256) void trv_k(const unsigned short* __restrict__ vb,
                                             unsigned short* __restrict__ vt) {
  int bh = blockIdx.x >> 5;
  int t0 = (blockIdx.x & 31) * 32;
  int b = bh >> 4, hh = bh & 15;
  __shared__ unsigned short tile[32][64];
  int tr = threadIdx.x >> 3, dblk = (threadIdx.x & 7) * 8;
  *(u16x8*)&tile[tr][dblk] = *(const u16x8*)&vb[((long)b * CT + t0 + tr) * CQKV + hh * CDH + dblk];
  __syncthreads();
  int d = threadIdx.x >> 2, tz = (threadIdx.x & 3) * 8;
  unsigned short o[8];
#pragma unroll
  for (int e = 0; e < 8; e++) o[e] = tile[tz + e][d];
  *(u16x8*)&vt[((long)bh * CDH + d) * CT + t0 + tz] = *(u16x8*)&o[0];
}

// ---------------- ksum[bh,m] = sum_t kp_t[bh,m,t] ----------------
__global__ __launch_bounds__(256) void ksum_k(const unsigned short* __restrict__ kpt,
                                              float* __restrict__ ksum) {
  int wv = threadIdx.x >> 6, ll = threadIdx.x & 63;
  long gid = (long)blockIdx.x * 4 + wv;
  const unsigned short* r = kpt + gid * CT;
  u16x8 a = *(const u16x8*)&r[ll * 16];
  u16x8 b = *(const u16x8*)&r[ll * 16 + 8];
  float s = 0;
#pragma unroll
  for (int e = 0; e < 8; e++) s += b2f(a[e]) + b2f(b[e]);
  s = wredsum(s);
  if (ll == 0) ksum[gid] = s;
}

// ---------------- dinv[bh,t] = 1 / (qp . ksum) ----------------
__global__ __launch_bounds__(256) void dinv_k(const unsigned short* __restrict__ qp,
                                              const float* __restrict__ ksum,
                                              float* __restrict__ dinv) {
  int wv = threadIdx.x >> 6, ll = threadIdx.x & 63;
  long gid = (long)blockIdx.x * 4 + wv;
  long bh = gid >> 10;
  const unsigned short* r = qp + gid * CM;
  const float* ks = ksum + bh * CM;
  u16x4 a = *(const u16x4*)&r[ll * 4];
  float s = 0;
#pragma unroll
  for (int e = 0; e < 4; e++) s += b2f(a[e]) * ks[ll * 4 + e];
  s = wredsum(s);
  if (ll == 0) dinv[gid] = 1.0f / s;
}

// ---------------- h += pe ----------------
__global__ __launch_bounds__(256) void addpe_k(float* __restrict__ h, const float* __restrict__ pe) {
  long i = ((long)blockIdx.x * 256 + threadIdx.x) * 4;
  int t = (int)((i >> 10) & 1023);
  int c = (int)(i & 1023);
  f32x4 v = *(f32x4*)&h[i];
  f32x4 p = *(const f32x4*)&pe[(long)t * 1024 + c];
  v += p;
  *(f32x4*)&h[i] = v;
}

// ---------------- fp32 -> bf16 flat ----------------
__global__ __launch_bounds__(256) void f2b_k(const float* __restrict__ in,
                                             unsigned short* __restrict__ out, long n) {
  long i = ((long)blockIdx.x * 256 + threadIdx.x) * 4;
  if (i >= n) return;
  f32x4 v = *(const f32x4*)&in[i];
  unsigned short o[4];
#pragma unroll
  for (int e = 0; e < 4; e++) o[e] = f2bu(v[e]);
  *(u16x4*)&out[i] = *(u16x4*)&o[0];
}

// ---------------- transpose-convert: in (R,C) fp32 -> out (C,R) bf16 ----------------
__global__ __launch_bounds__(256) void tconv_k(const float* __restrict__ in,
                                               unsigned short* __restrict__ out, int R, int C) {
  __shared__ float tile[32][33];
  int r0 = blockIdx.x * 32, c0 = blockIdx.y * 32;
  int tr = threadIdx.x >> 5, tc = threadIdx.x & 31;
#pragma unroll
  for (int p = 0; p < 4; p++) {
    int r = r0 + p * 8 + tr, c = c0 + tc;
    tile[p * 8 + tr][tc] = (r < R && c < C) ? in[(long)r * C + c] : 0.f;
  }
  __syncthreads();
#pragma unroll
  for (int p = 0; p < 4; p++) {
    int c = c0 + p * 8 + tr, r = r0 + tc;
    if (c < C && r < R) out[(long)c * R + r] = f2bu(tile[tc][p * 8 + tr]);
  }
}

// ---------------- Wconv (64,1024,3) -> per-tap (64,1024) bf16: [r][oc][ic] = (192,1024) ----------------
__global__ __launch_bounds__(256) void wconv_k(const float* __restrict__ W,
                                               unsigned short* __restrict__ out) {
  int idx = blockIdx.x * 256 + threadIdx.x;
  int r = idx >> 16, rem = idx & 65535, oc = rem >> 10, ic = rem & 1023;
  out[idx] = f2bu(W[oc * 3072 + ic * 3 + r]);
}

// ---------------- conv tap-mix: xa[t,oc] = Y[t-1,oc] + Y[t,64+oc] + Y[t+1,128+oc] + bconv ----------------
__global__ __launch_bounds__(256) void convmix_k(const float* __restrict__ Y,
                                                 const float* __restrict__ bc,
                                                 float* __restrict__ xa) {
  long t = (long)blockIdx.x * 4 + (threadIdx.x >> 6);
  int oc = threadIdx.x & 63;
  long tm = t > 0 ? t - 1 : 0, tp = t < CNT - 1 ? t + 1 : CNT - 1;  // boundary rows re-patched later
  float v = Y[tm * 192 + oc] + Y[t * 192 + 64 + oc] + Y[tp * 192 + 128 + oc] + bc[oc];
  xa[t * 64 + oc] = v;
}

// ---------------- proj * dn -> bf16 ----------------
__global__ __launch_bounds__(256) void projc_k(const float* __restrict__ p,
                                               unsigned short* __restrict__ out) {
  int i = blockIdx.x * 256 + threadIdx.x;
  out[i] = f2bu(p[i] * CDN);
}

// ---------------- concat q/k/v biases ----------------
__global__ __launch_bounds__(256) void catb_k(const float* __restrict__ q,
                                              const float* __restrict__ k,
                                              const float* __restrict__ v,
                                              float* __restrict__ o) {
  int i = blockIdx.x * 256 + threadIdx.x;  // < 3072
  o[i] = i < 1024 ? q[i] : (i < 2048 ? k[i - 1024] : v[i - 2048]);
}

// ---------------- exact conv recompute at batch boundaries ----------------
__global__ __launch_bounds__(256) void patch_k(const float* __restrict__ h,
                                               const float* __restrict__ W,
                                               const float* __restrict__ bc,
                                               float* __restrict__ xa) {
  int b = blockIdx.x >> 1;
  int t = (blockIdx.x & 1) ? (CT - 1) : 0;
  int oc = threadIdx.x & 63, ch = threadIdx.x >> 6;
  float s = 0;
  for (int r = 0; r < 3; r++) {
    int tt = t + r - 1;
    if (tt < 0 || tt >= CT) continue;
    const float* hr = h + ((long)b * CT + tt) * CDM;
    const float* wr = W + oc * 3072 + r;
    for (int ic = ch * 256; ic < ch * 256 + 256; ic++) s += hr[ic] * wr[ic * 3];
  }
  __shared__ float sm[256];
  sm[threadIdx.x] = s;
  __syncthreads();
  if (threadIdx.x < 64) {
    float tot = sm[oc] + sm[64 + oc] + sm[128 + oc] + sm[192 + oc] + bc[oc];
    xa[((long)b * CT + t) * 64 + oc] = tot;
  }
}

#define LAUNCH_GEMM(EPI, A, Bt, bias, C, rsp, Mr, Nr, Kr, lda, ldb, ldc, nb, bdiv, As1, As2, Bs1, Bs2, Cs1, Cs2, Rs1, Rs2) \
  gemm_k<EPI><<<dim3(((Mr) + 127) / 128, ((Nr) + 127) / 128, (nb)), 256, 0, stream>>>(           \
      (const unsigned short*)(A), (const unsigned short*)(Bt), (bias), (void*)(C), (rsp),        \
      (Mr), (Nr), (Kr), (lda), (ldb), (ldc), (bdiv), (long)(As1), (long)(As2), (long)(Bs1),      \
      (long)(Bs2), (long)(Cs1), (long)(Cs2), (long)(Rs1), (long)(Rs2))

#define LAUNCH_G8(TMX, EPI, A, Bt, bias, C, Mr, Nr, Kr, lda, ldb, ldc)                           \
  gemm8_k<TMX, EPI><<<dim3(((Mr) + (TMX)-1) / (TMX), ((Nr) + 255) / 256), 512, 0, stream>>>(     \
      (const unsigned short*)(A), (const unsigned short*)(Bt), (bias), (void*)(C),               \
      (Mr), (Nr), (Kr), (lda), (ldb), (ldc))

extern "C" void kernel_launch(void* const* d_in, const int* in_sizes, int n_in,
                              void* d_out, int out_size, void* d_ws, size_t ws_size,
                              hipStream_t stream) {
  const float* x = (const float*)d_in[0];
  const float* Win = (const float*)d_in[1];
  const float* b_in = (const float*)d_in[2];
  const float* pe = (const float*)d_in[3];
  const float* ln1_g = (const float*)d_in[4];
  const float* ln1_b = (const float*)d_in[5];
  const float* Wq = (const float*)d_in[6];
  const float* bq = (const float*)d_in[7];
  const float* Wk = (const float*)d_in[8];
  const float* bk = (const float*)d_in[9];
  const float* Wv = (const float*)d_in[10];
  const float* bv = (const float*)d_in[11];
  const float* Wo = (const float*)d_in[12];
  const float* bo = (const float*)d_in[13];
  const float* ln2_g = (const float*)d_in[14];
  const float* ln2_b = (const float*)d_in[15];
  const float* W1 = (const float*)d_in[16];
  const float* b1 = (const float*)d_in[17];
  const float* W2 = (const float*)d_in[18];
  const float* b2 = (const float*)d_in[19];
  const float* Wc = (const float*)d_in[20];
  const float* bc = (const float*)d_in[21];
  const float* Wconv = (const float*)d_in[22];
  const float* bconv = (const float*)d_in[23];
  const float* Waux = (const float*)d_in[24];
  const float* baux = (const float*)d_in[25];
  const float* proj = (const float*)d_in[26];
  float* out = (float*)d_out;

  char* wsp = (char*)d_ws;
  size_t off = 0;
  auto take = [&](size_t bytes) {
    char* p = wsp + off;
    off = (off + bytes + 255) & ~(size_t)255;
    return p;
  };
  float* h_f = (float*)take(33554432);                      // (8192,1024) fp32 residual
  unsigned short* y_bf = (unsigned short*)take(16777216);   // LN out; aliased: vt, o
  unsigned short* qkv_bf = (unsigned short*)take(50331648); // (8192,3072) fused q,k,v
  float* dd_f = (float*)take(134217728);                    // (B,H,T,M) fp32; aliased: ff_bf
  unsigned short* qp_bf = (unsigned short*)take(67108864);  // (B,H,T,M)
  unsigned short* kpt_bf = (unsigned short*)take(67108864); // (B,H,M,T)
  unsigned short* ctx_bf = (unsigned short*)take(4194304);  // (B,H,DH,M)
  float* ksum_f = (float*)take(131072);
  float* dinv_f = (float*)take(524288);
  float* stab_f = (float*)take(8192);
  float* xa_f = (float*)take(2097152);
  float* ycv_f = (float*)take(6291456);                     // (8192,192) conv taps
  unsigned short* xabf = (unsigned short*)take(1048576);
  float* bqkv_f = (float*)take(24576);                      // 2 layers x 3072
  unsigned short* hbf = (unsigned short*)take(16777216);
  unsigned short* xbf = (unsigned short*)take(4194304);
  unsigned short* win_t = (unsigned short*)take(524288);
  unsigned short* wqkvo_t = (unsigned short*)take(16777216);
  unsigned short* w1_t = (unsigned short*)take(16777216);
  unsigned short* w2_t = (unsigned short*)take(16777216);
  unsigned short* wc_t = (unsigned short*)take(4096000);
  unsigned short* projc = (unsigned short*)take(32768);
  unsigned short* wconv_t = (unsigned short*)take(393216);
  unsigned short* waux_t = (unsigned short*)take(256128);
  unsigned short* ff_bf = (unsigned short*)dd_f;   // alias
  unsigned short* vt_bf = y_bf;                    // alias (y dead after QKV)
  unsigned short* o_bf = y_bf;                     // alias (vt dead after ctx)
  (void)in_sizes; (void)n_in; (void)out_size; (void)ws_size;

  // ---- weight conversion ----
  f2b_k<<<2048, 256, 0, stream>>>(x, xbf, (long)CNT * 256);
  tconv_k<<<dim3(8, 32), 256, 0, stream>>>(Win, win_t, 256, 1024);
  for (int l = 0; l < 2; l++) {
    tconv_k<<<dim3(32, 32), 256, 0, stream>>>(Wq + (long)l * 1048576, wqkvo_t + (long)(l * 4 + 0) * 1048576, 1024, 1024);
    tconv_k<<<dim3(32, 32), 256, 0, stream>>>(Wk + (long)l * 1048576, wqkvo_t + (long)(l * 4 + 1) * 1048576, 1024, 1024);
    tconv_k<<<dim3(32, 32), 256, 0, stream>>>(Wv + (long)l * 1048576, wqkvo_t + (long)(l * 4 + 2) * 1048576, 1024, 1024);
    tconv_k<<<dim3(32, 32), 256, 0, stream>>>(Wo + (long)l * 1048576, wqkvo_t + (long)(l * 4 + 3) * 1048576, 1024, 1024);
    tconv_k<<<dim3(32, 128), 256, 0, stream>>>(W1 + (long)l * 4194304, w1_t + (long)l * 4194304, 1024, 4096);
    tconv_k<<<dim3(128, 32), 256, 0, stream>>>(W2 + (long)l * 4194304, w2_t + (long)l * 4194304, 4096, 1024);
    catb_k<<<12, 256, 0, stream>>>(bq + l * CDM, bk + l * CDM, bv + l * CDM, bqkv_f + l * CQKV);
  }
  tconv_k<<<dim3(32, 63), 256, 0, stream>>>(Wc, wc_t, 1024, 2000);
  tconv_k<<<dim3(2, 63), 256, 0, stream>>>(Waux, waux_t, 64, 2001);
  wconv_k<<<768, 256, 0, stream>>>(Wconv, wconv_t);
  projc_k<<<64, 256, 0, stream>>>(proj, projc);

  // ---- embed ----
  LAUNCH_G8(128, EPI_BIAS, xbf, win_t, b_in, h_f, CNT, CDM, 256, 256, 256, CDM);
  addpe_k<<<8192, 256, 0, stream>>>(h_f, pe);

  for (int l = 0; l < 2; l++) {
    const unsigned short* wqkv_t = wqkvo_t + (long)(l * 4) * 1048576;  // q,k,v adjacent: 3072 x 1024
    const unsigned short* wo_t = wqkvo_t + (long)(l * 4 + 3) * 1048576;

    ln_k<<<2048, 256, 0, stream>>>(h_f, ln1_g + l * CDM, ln1_b + l * CDM, y_bf);
    // fused QKV: (8192,1024) x (3072,1024)^T -> (8192,3072) bf16
    LAUNCH_G8(256, EPI_BIAS | EPI_OUTBF, y_bf, wqkv_t, bqkv_f + l * CQKV, qkv_bf, CNT, CQKV, CDM, CDM, CDM, CQKV);

    // dd = q @ (proj*dn)^T, batched over (b,h)
    LAUNCH_GEMM(0, qkv_bf, projc, nullptr, dd_f, nullptr, CT, CM, CDH, CQKV, CDH, CM, 128, CH,
                (long)CT * CQKV, 64, 0, 0, (long)CH * CT * CM, (long)CT * CM, 0, 0);
    featq_k<<<32768, 256, 0, stream>>>(dd_f, qkv_bf, qp_bf);
    LAUNCH_GEMM(0, qkv_bf + 1024, projc, nullptr, dd_f, nullptr, CT, CM, CDH, CQKV, CDH, CM, 128, CH,
                (long)CT * CQKV, 64, 0, 0, (long)CH * CT * CM, (long)CT * CM, 0, 0);
    stabp_k<<<2048, 256, 0, stream>>>(dd_f, stab_f);
    featk_k<<<4096, 256, 0, stream>>>(dd_f, qkv_bf + 1024, stab_f, kpt_bf);
    trv_k<<<4096, 256, 0, stream>>>(qkv_bf + 2048, vt_bf);
    ksum_k<<<8192, 256, 0, stream>>>(kpt_bf, ksum_f);
    // ctx^T (DH,M) = v^T @ kp, batched
    LAUNCH_GEMM(EPI_OUTBF, vt_bf, kpt_bf, nullptr, ctx_bf, nullptr, CDH, CM, CT, CT, CT, CM, 128, CH,
                (long)CH * CDH * CT, (long)CDH * CT, (long)CH * CM * CT, (long)CM * CT,
                (long)CH * CDH * CM, (long)CDH * CM, 0, 0);
    dinv_k<<<32768, 256, 0, stream>>>(qp_bf, ksum_f, dinv_f);
    // o = (qp @ ctx) * dinv -> (B,T,H*DH) bf16 (overwrites vt alias after ctx done)
    LAUNCH_GEMM(EPI_RSCALE | EPI_OUTBF, qp_bf, ctx_bf, nullptr, o_bf, dinv_f, CT, CDH, CM, CM, CM, CDM, 128, CH,
                (long)CH * CT * CM, (long)CT * CM, (long)CH * CDH * CM, (long)CDH * CM,
                (long)CT * CDM, 64, (long)CH * CT, (long)CT);
    LAUNCH_G8(128, EPI_BIAS | EPI_ACCUM, o_bf, wo_t, bo + l * CDM, h_f, CNT, CDM, CDM, CDM, CDM, CDM);

    ln_k<<<2048, 256, 0, stream>>>(h_f, ln2_g + l * CDM, ln2_b + l * CDM, y_bf);
    LAUNCH_G8(256, EPI_BIAS | EPI_GELU | EPI_OUTBF, y_bf, w1_t + (long)l * 4194304, b1 + l * CDFF, ff_bf,
              CNT, CDFF, CDM, CDM, CDM, CDFF);
    LAUNCH_G8(128, EPI_BIAS | EPI_ACCUM, ff_bf, w2_t + (long)l * 4194304, b2 + l * CDM, h_f,
              CNT, CDM, CDFF, CDFF, CDFF, CDM);

    if (l == 0) {
      // conv1d: single N=192 GEMM over all 3 taps, then shift-add mix + exact boundary patch
      f2b_k<<<8192, 256, 0, stream>>>(h_f, hbf, (long)CNT * CDM);
      LAUNCH_GEMM(0, hbf, wconv_t, nullptr, ycv_f, nullptr, CNT, 192, CDM, CDM, CDM, 192, 1, 1, 0, 0, 0, 0, 0, 0, 0, 0);
      convmix_k<<<2048, 256, 0, stream>>>(ycv_f, bconv, xa_f);
      patch_k<<<16, 256, 0, stream>>>(h_f, Wconv, bconv, xa_f);
      f2b_k<<<512, 256, 0, stream>>>(xa_f, xabf, (long)CNT * 64);
      LAUNCH_GEMM(EPI_BIAS, xabf, waux_t, baux, out + 16384000, nullptr, CNT, CV + 1, 64, 64, 64, CV + 1, 1, 1, 0, 0, 0, 0, 0, 0, 0, 0);
    }
  }

  // ---- classifier ----
  f2b_k<<<8192, 256, 0, stream>>>(h_f, hbf, (long)CNT * CDM);
  LAUNCH_G8(256, EPI_BIAS, hbf, wc_t, bc, out, CNT, CV, CDM, CDM, CDM, CV);
}

// Round 6
// 1325.434 us; speedup vs baseline: 1.4375x; 1.1964x over previous
//
#include <hip/hip_runtime.h>
#include <hip/hip_bf16.h>

typedef __attribute__((ext_vector_type(4))) float f32x4;
typedef __attribute__((ext_vector_type(8))) unsigned short u16x8;
typedef __attribute__((ext_vector_type(4))) unsigned short u16x4;
typedef __bf16 bf16x8 __attribute__((ext_vector_type(8)));

#define DEVFN static __device__ __forceinline__

constexpr int CB = 8, CT = 1024, CDM = 1024, CH = 16, CDH = 64, CDFF = 4096, CV = 2000, CM = 256;
constexpr int CNT = CB * CT; // 8192 tokens
constexpr int CQKV = 3072;   // fused qkv row stride
constexpr float CDN = 0.35355339059327373f;   // 64^-0.25
constexpr float CRATIO = 0.0625f;             // 256^-0.5
constexpr float CKEPS = 1e-4f;

DEVFN unsigned short f2bu(float x) {
  __hip_bfloat16 h = __float2bfloat16(x);
  return __builtin_bit_cast(unsigned short, h);
}
DEVFN float b2f(unsigned short u) {
  __hip_bfloat16 h = __builtin_bit_cast(__hip_bfloat16, u);
  return __bfloat162float(h);
}
DEVFN float wredsum(float s) {
#pragma unroll
  for (int ofs = 32; ofs; ofs >>= 1) s += __shfl_xor(s, ofs, 64);
  return s;
}
DEVFN float wredmax(float s) {
#pragma unroll
  for (int ofs = 32; ofs; ofs >>= 1) s = fmaxf(s, __shfl_xor(s, ofs, 64));
  return s;
}
DEVFN void gl_lds16(const void* g, void* l) {
  __builtin_amdgcn_global_load_lds(
      (const __attribute__((address_space(1))) unsigned int*)g,
      (__attribute__((address_space(3))) unsigned int*)l, 16, 0, 0);
}
DEVFN f32x4 mfma16(u16x8 a, u16x8 b, f32x4 c) {
  return __builtin_amdgcn_mfma_f32_16x16x32_bf16(
      __builtin_bit_cast(bf16x8, a), __builtin_bit_cast(bf16x8, b), c, 0, 0, 0);
}
// compiler-invisible LDS read; waits are manual (counted lgkmcnt)
DEVFN u16x8 lds_rd128(unsigned addr) {
  u16x8 r;
  asm volatile("ds_read_b128 %0, %1" : "=v"(r) : "v"(addr));
  return r;
}
DEVFN unsigned lds_addr(const void* p) {
  return (unsigned)(unsigned long)(const __attribute__((address_space(3))) char*)p;
}

#define EPI_BIAS 1
#define EPI_ACCUM 2
#define EPI_GELU 4
#define EPI_OUTBF 8
#define EPI_RSCALE 16

// ================= 128x128 big GEMM, 2 blocks/CU: C = A(M,K) * Bt(N,K)^T =================
// BK=64, 8 waves (2Mx4N), 2 LDS buffers (64KB total -> 2 blocks/CU), st-swizzle,
// asm ds_read + counted lgkmcnt, full-tile prefetch + counted vmcnt(4), setprio.
template <int EPI>
__global__ __launch_bounds__(512, 4) void gemm128_k(
    const unsigned short* __restrict__ A, const unsigned short* __restrict__ Bt,
    const float* __restrict__ bias, void* __restrict__ C,
    int Mr, int Nr, int Kr, int lda, int ldb, int ldc) {
  __shared__ unsigned short smA[2][128 * 64];
  __shared__ unsigned short smB[2][128 * 64];

  int tid = threadIdx.x, wv = tid >> 6, ll = tid & 63;
  int wm = wv >> 2, wn = wv & 3;  // 2 x 4 wave grid; per-wave out 64x32
  int m0 = blockIdx.x * 128, n0 = blockIdx.y * 128;
  int fr = ll & 15, f16 = ll >> 4, fk = f16 * 8;

  const char* Ab = (const char*)A;
  const char* Bb = (const char*)Bt;

  // staging source byte offsets (inverse-swizzled: linear LDS dest + swizzled read)
  unsigned int offA[2], offB[2];
#pragma unroll
  for (int ro = 0; ro < 2; ro++) {
    int L = (ro * 512 + tid) * 16;
    int P = L ^ (((L >> 9) & 1) << 5);
    int kh = P >> 13, rem = P & 8191;  // [kh half-K slab][row][64B]
    int r = rem >> 6, cb = rem & 63;
    long rowA = min(m0 + r, Mr - 1);
    offA[ro] = (unsigned)((rowA * lda + kh * 32) * 2 + cb);
    long rowB = min(n0 + r, Nr - 1);
    offB[ro] = (unsigned)((rowB * ldb + kh * 32) * 2 + cb);
  }
  // fragment LDS byte addresses (buf0, ks0), swizzled
  unsigned aAb = lds_addr(&smA[0][0]), aBb = lds_addr(&smB[0][0]);
  unsigned offArd[4], offBrd[2];
#pragma unroll
  for (int i = 0; i < 4; i++) {
    int r = wm * 64 + i * 16 + fr;
    offArd[i] = aAb + (unsigned)(r * 64 + 2 * (fk ^ (((r >> 3) & 1) << 4)));
  }
#pragma unroll
  for (int j = 0; j < 2; j++) {
    int r = wn * 32 + j * 16 + fr;
    offBrd[j] = aBb + (unsigned)(r * 64 + 2 * (fk ^ (((r >> 3) & 1) << 4)));
  }

  f32x4 acc[4][2] = {};
  int NT = Kr / 64;  // even for all our shapes

#define STGALL(PB, KBN)                                                      \
  {                                                                          \
    _Pragma("unroll") for (int ro = 0; ro < 2; ro++)                         \
        gl_lds16(Ab + offA[ro] + (KBN), &smA[PB][(ro * 512 + wv * 64) * 8]); \
    _Pragma("unroll") for (int ro = 0; ro < 2; ro++)                         \
        gl_lds16(Bb + offB[ro] + (KBN), &smB[PB][(ro * 512 + wv * 64) * 8]); \
  }
#define TILE(PB, KBN)                                                        \
  {                                                                          \
    __builtin_amdgcn_s_barrier(); /* readers of buf PB^1 done */             \
    __builtin_amdgcn_sched_barrier(0);                                       \
    STGALL((PB) ^ 1, KBN);                                                   \
    asm volatile("s_waitcnt vmcnt(4)" ::: "memory");                         \
    __builtin_amdgcn_sched_barrier(0);                                       \
    __builtin_amdgcn_s_barrier(); /* buf PB globally ready */                \
    __builtin_amdgcn_sched_barrier(0);                                       \
    u16x8 a0[4], b0[2], a1[4], b1[2];                                        \
    _Pragma("unroll") for (int i = 0; i < 4; i++)                            \
        a0[i] = lds_rd128(offArd[i] + (PB)*16384);                           \
    _Pragma("unroll") for (int j = 0; j < 2; j++)                            \
        b0[j] = lds_rd128(offBrd[j] + (PB)*16384);                           \
    _Pragma("unroll") for (int i = 0; i < 4; i++)                            \
        a1[i] = lds_rd128(offArd[i] + (PB)*16384 + 8192);                    \
    _Pragma("unroll") for (int j = 0; j < 2; j++)                            \
        b1[j] = lds_rd128(offBrd[j] + (PB)*16384 + 8192);                    \
    asm volatile("s_waitcnt lgkmcnt(6)" ::: "memory");                       \
    __builtin_amdgcn_sched_barrier(0);                                       \
    __builtin_amdgcn_s_setprio(1);                                           \
    _Pragma("unroll") for (int i = 0; i < 4; i++) {                          \
      acc[i][0] = mfma16(a0[i], b0[0], acc[i][0]);                           \
      acc[i][1] = mfma16(a0[i], b0[1], acc[i][1]);                           \
    }                                                                        \
    __builtin_amdgcn_s_setprio(0);                                           \
    asm volatile("s_waitcnt lgkmcnt(0)" ::: "memory");                       \
    __builtin_amdgcn_sched_barrier(0);                                       \
    __builtin_amdgcn_s_setprio(1);                                           \
    _Pragma("unroll") for (int i = 0; i < 4; i++) {                          \
      acc[i][0] = mfma16(a1[i], b1[0], acc[i][0]);                           \
      acc[i][1] = mfma16(a1[i], b1[1], acc[i][1]);                           \
    }                                                                        \
    __builtin_amdgcn_s_setprio(0);                                           \
  }

  STGALL(0, 0);  // prologue: tile 0 -> buf0
  for (int t = 0; t < NT; t += 2) {
    long kb1 = (long)(t + 1) * 128;
    long kb2 = (long)min(t + 2, NT - 1) * 128;
    TILE(0, kb1);
    TILE(1, kb2);
  }
  asm volatile("s_waitcnt vmcnt(0)" ::: "memory");  // drain dangling DMA before exit
  __builtin_amdgcn_sched_barrier(0);
#undef TILE
#undef STGALL

  // ---- epilogue ----
#pragma unroll
  for (int i = 0; i < 4; i++) {
#pragma unroll
    for (int j = 0; j < 2; j++) {
#pragma unroll
      for (int e = 0; e < 4; e++) {
        int gr = m0 + wm * 64 + i * 16 + f16 * 4 + e;
        int gc = n0 + wn * 32 + j * 16 + fr;
        if (gr < Mr && gc < Nr) {
          float v = acc[i][j][e];
          if (EPI & EPI_BIAS) v += bias[gc];
          if (EPI & EPI_GELU) v = 0.5f * v * (1.0f + erff(v * 0.70710678118f));
          long idx = (long)gr * ldc + gc;
          if (EPI & EPI_ACCUM) v += ((float*)C)[idx];
          if (EPI & EPI_OUTBF) ((unsigned short*)C)[idx] = f2bu(v);
          else ((float*)C)[idx] = v;
        }
      }
    }
  }
}

// ================= legacy 128x128 GEMM (small/batched shapes) =================
template <int EPI>
__global__ __launch_bounds__(256) void gemm_k(
    const unsigned short* __restrict__ Aall, const unsigned short* __restrict__ Btall,
    const float* __restrict__ bias, void* __restrict__ Call, const float* __restrict__ rsall,
    int Mr, int Nr, int Kr, int lda, int ldb, int ldc, int bdiv,
    long As1, long As2, long Bs1, long Bs2, long Cs1, long Cs2, long Rs1, long Rs2) {
  __shared__ unsigned short smA[128 * 32];
  __shared__ unsigned short smB[128 * 32];
  int bz = blockIdx.z;
  const unsigned short* A = Aall + (long)(bz / bdiv) * As1 + (long)(bz % bdiv) * As2;
  const unsigned short* Bt = Btall + (long)(bz / bdiv) * Bs1 + (long)(bz % bdiv) * Bs2;
  long coff = (long)(bz / bdiv) * Cs1 + (long)(bz % bdiv) * Cs2;
  const float* rs = nullptr;
  if (EPI & EPI_RSCALE) rs = rsall + (long)(bz / bdiv) * Rs1 + (long)(bz % bdiv) * Rs2;

  int tid = threadIdx.x, wv = tid >> 6, ll = tid & 63;
  int m0 = blockIdx.x * 128, n0 = blockIdx.y * 128;
  int sr = tid >> 2, sc = (tid & 3) * 8;
  long ar0 = min(m0 + sr, Mr - 1), ar1 = min(m0 + sr + 64, Mr - 1);
  long br0 = min(n0 + sr, Nr - 1), br1 = min(n0 + sr + 64, Nr - 1);
  unsigned short* lA0 = &smA[(wv * 16) * 32];
  unsigned short* lA1 = &smA[(64 + wv * 16) * 32];
  unsigned short* lB0 = &smB[(wv * 16) * 32];
  unsigned short* lB1 = &smB[(64 + wv * 16) * 32];

  f32x4 acc[4][4] = {};
  int wr = (wv >> 1) * 64, wc = (wv & 1) * 64;
  int fr = ll & 15, fk = (ll >> 4) * 8;

  for (int k0 = 0; k0 < Kr; k0 += 32) {
    __syncthreads();
    gl_lds16(A + ar0 * lda + k0 + sc, lA0);
    gl_lds16(A + ar1 * lda + k0 + sc, lA1);
    gl_lds16(Bt + br0 * ldb + k0 + sc, lB0);
    gl_lds16(Bt + br1 * ldb + k0 + sc, lB1);
    __syncthreads();
    u16x8 af[4], bfr[4];
#pragma unroll
    for (int i = 0; i < 4; i++) {
      af[i] = *(const u16x8*)&smA[(wr + i * 16 + fr) * 32 + fk];
      bfr[i] = *(const u16x8*)&smB[(wc + i * 16 + fr) * 32 + fk];
    }
#pragma unroll
    for (int i = 0; i < 4; i++)
#pragma unroll
      for (int j = 0; j < 4; j++) acc[i][j] = mfma16(af[i], bfr[j], acc[i][j]);
  }

#pragma unroll
  for (int i = 0; i < 4; i++) {
#pragma unroll
    for (int j = 0; j < 4; j++) {
#pragma unroll
      for (int e = 0; e < 4; e++) {
        int gr = m0 + wr + i * 16 + (ll >> 4) * 4 + e;
        int gc = n0 + wc + j * 16 + (ll & 15);
        if (gr < Mr && gc < Nr) {
          float v = acc[i][j][e];
          if (EPI & EPI_BIAS) v += bias[gc];
          if (EPI & EPI_GELU) v = 0.5f * v * (1.0f + erff(v * 0.70710678118f));
          if (EPI & EPI_RSCALE) v *= rs[gr];
          long idx = coff + (long)gr * ldc + gc;
          if (EPI & EPI_ACCUM) v += ((float*)Call)[idx];
          if (EPI & EPI_OUTBF) ((unsigned short*)Call)[idx] = f2bu(v);
          else ((float*)Call)[idx] = v;
        }
      }
    }
  }
}

// ================= fused FAVOR+ kernels =================
// dd chunk GEMM: block = (bh, chunk of 128 t-rows) x M=256; 512 thr / 8 waves,
// wave w owns rows w*16..w*16+15; acc[16] = 16 j-frags (C: row=(ll>>4)*4+e, col=j*16+(ll&15)).
DEVFN void feat_dd(const unsigned short* __restrict__ src, const unsigned short* __restrict__ projc,
                   unsigned short* ldsq, unsigned short* ldsp, int b, int t0, int hh,
                   f32x4 acc[16]) {
  int tid = threadIdx.x, wv = tid >> 6, ll = tid & 63;
#pragma unroll
  for (int p = 0; p < 2; p++) {
    int r = p * 64 + (tid >> 3), c8 = (tid & 7) * 8;
    *(u16x8*)&ldsq[r * 72 + c8] =
        *(const u16x8*)&src[((long)b * CT + t0 + r) * CQKV + hh * CDH + c8];
  }
#pragma unroll
  for (int p = 0; p < 4; p++) {
    int r = p * 64 + (tid >> 3), c8 = (tid & 7) * 8;
    *(u16x8*)&ldsp[r * 72 + c8] = *(const u16x8*)&projc[r * 64 + c8];
  }
  __syncthreads();
  int fr = ll & 15, fk = (ll >> 4) * 8;
#pragma unroll
  for (int ks = 0; ks < 2; ks++) {
    u16x8 af = *(const u16x8*)&ldsq[(wv * 16 + fr) * 72 + ks * 32 + fk];
#pragma unroll
    for (int j = 0; j < 16; j++) {
      u16x8 bf = *(const u16x8*)&ldsp[(j * 16 + fr) * 72 + ks * 32 + fk];
      acc[j] = mfma16(af, bf, acc[j]);
    }
  }
}

// pass 1 (keys): partial max of dd per (bh, chunk)
__global__ __launch_bounds__(512, 4) void kstab_f(const unsigned short* __restrict__ kb,
                                                  const unsigned short* __restrict__ projc,
                                                  float* __restrict__ part) {
  extern __shared__ char dynsm[];
  unsigned short* ldsq = (unsigned short*)dynsm;            // [128][72]
  unsigned short* ldsp = (unsigned short*)(dynsm + 18432);  // [256][72]
  __shared__ float smx[8];
  int bh = blockIdx.x >> 3, chunk = blockIdx.x & 7;
  int b = bh >> 4, hh = bh & 15;
  f32x4 acc[16] = {};
  feat_dd(kb, projc, ldsq, ldsp, b, chunk * 128, hh, acc);
  float mx = -3.4e38f;
#pragma unroll
  for (int j = 0; j < 16; j++)
#pragma unroll
    for (int e = 0; e < 4; e++) mx = fmaxf(mx, acc[j][e]);
  mx = wredmax(mx);
  int wv = threadIdx.x >> 6;
  if ((threadIdx.x & 63) == 0) smx[wv] = mx;
  __syncthreads();
  if (threadIdx.x == 0) {
    float m2 = smx[0];
#pragma unroll
    for (int i = 1; i < 8; i++) m2 = fmaxf(m2, smx[i]);
    part[blockIdx.x] = m2;
  }
}

// pass 2 (keys): recompute dd, exp with global stab -> kpt (bh,m,t) bf16 + partial ksum
__global__ __launch_bounds__(512, 4) void featk_f(const unsigned short* __restrict__ kb,
                                                  const unsigned short* __restrict__ projc,
                                                  const float* __restrict__ part,
                                                  unsigned short* __restrict__ kpt,
                                                  float* __restrict__ kspart) {
  extern __shared__ char dynsm[];
  unsigned short* ldsq = (unsigned short*)dynsm;            // [128][72]
  unsigned short* ldsp = (unsigned short*)(dynsm + 18432);  // [256][72]
  unsigned short* ldso = (unsigned short*)dynsm;            // overlay [256][136] (m,t)
  int tid = threadIdx.x, wv = tid >> 6, ll = tid & 63;
  int bh = blockIdx.x >> 3, chunk = blockIdx.x & 7;
  int b = bh >> 4, hh = bh & 15;
  float st = part[bh * 8];
#pragma unroll
  for (int i = 1; i < 8; i++) st = fmaxf(st, part[bh * 8 + i]);
  f32x4 acc[16] = {};
  feat_dd(kb, projc, ldsq, ldsp, b, chunk * 128, hh, acc);
  int fr = ll & 15, g = ll >> 4;
  float diag[4];
#pragma unroll
  for (int e = 0; e < 4; e++) {
    int row = wv * 16 + g * 4 + e;
    u16x4 kv = *(const u16x4*)&ldsq[row * 72 + fr * 4];
    float s = 0;
#pragma unroll
    for (int z = 0; z < 4; z++) { float f = b2f(kv[z]); s += f * f; }
#pragma unroll
    for (int o = 1; o < 16; o <<= 1) s += __shfl_xor(s, o, 64);
    diag[e] = s * (0.5f * CDN * CDN);
  }
  __syncthreads();  // all ldsq/ldsp reads done -> overlay
#pragma unroll
  for (int j = 0; j < 16; j++)
#pragma unroll
    for (int e = 0; e < 4; e++) {
      float v = CRATIO * (expf(acc[j][e] - diag[e] - st) + CKEPS);
      ldso[(j * 16 + fr) * 136 + wv * 16 + g * 4 + e] = f2bu(v);
    }
  __syncthreads();
  // coalesced store (m-major) + partial ksum
  int m = tid >> 1, seg = (tid & 1) * 64;
  long base = ((long)bh * CM + m) * CT + chunk * 128;
  float ks = 0;
#pragma unroll
  for (int z = 0; z < 8; z++) {
    u16x8 v8 = *(u16x8*)&ldso[m * 136 + seg + z * 8];
    *(u16x8*)&kpt[base + seg + z * 8] = v8;
#pragma unroll
    for (int w = 0; w < 8; w++) ks += b2f(v8[w]);
  }
  ks += __shfl_xor(ks, 1, 64);
  if ((tid & 1) == 0) kspart[((long)bh * 8 + chunk) * CM + m] = ks;
}

// reduce partial ksums: ksum[bh,m] = sum_c kspart[bh,c,m]
__global__ __launch_bounds__(256) void ksred_k(const float* __restrict__ kspart,
                                               float* __restrict__ ksum) {
  int i = blockIdx.x * 256 + threadIdx.x;  // < 32768
  int bh = i >> 8, m = i & 255;
  float s = 0;
#pragma unroll
  for (int c = 0; c < 8; c++) s += kspart[((long)bh * 8 + c) * CM + m];
  ksum[i] = s;
}

// queries: dd -> row-max -> qp (bh,t,m) bf16 + fused dinv
__global__ __launch_bounds__(512, 4) void featq_f(const unsigned short* __restrict__ qb,
                                                  const unsigned short* __restrict__ projc,
                                                  const float* __restrict__ ksum,
                                                  unsigned short* __restrict__ qp,
                                                  float* __restrict__ dinv) {
  extern __shared__ char dynsm[];
  unsigned short* ldsq = (unsigned short*)dynsm;            // [128][72]
  unsigned short* ldsp = (unsigned short*)(dynsm + 18432);  // [256][72]
  unsigned short* ldso = (unsigned short*)dynsm;            // overlay [128][264] (t,m)
  float* ldks = (float*)(dynsm + 67584);                    // [256]
  int tid = threadIdx.x, wv = tid >> 6, ll = tid & 63;
  int bh = blockIdx.x >> 3, chunk = blockIdx.x & 7;
  int b = bh >> 4, hh = bh & 15;
  int t0 = chunk * 128;
  if (tid < 256) ldks[tid] = ksum[bh * CM + tid];
  f32x4 acc[16] = {};
  feat_dd(qb, projc, ldsq, ldsp, b, t0, hh, acc);
  int fr = ll & 15, g = ll >> 4;
  float rmax[4], diag[4];
#pragma unroll
  for (int e = 0; e < 4; e++) {
    float mx = acc[0][e];
#pragma unroll
    for (int j = 1; j < 16; j++) mx = fmaxf(mx, acc[j][e]);
#pragma unroll
    for (int o = 1; o < 16; o <<= 1) mx = fmaxf(mx, __shfl_xor(mx, o, 64));
    rmax[e] = mx;
    int row = wv * 16 + g * 4 + e;
    u16x4 qv = *(const u16x4*)&ldsq[row * 72 + fr * 4];
    float s = 0;
#pragma unroll
    for (int z = 0; z < 4; z++) { float f = b2f(qv[z]); s += f * f; }
#pragma unroll
    for (int o = 1; o < 16; o <<= 1) s += __shfl_xor(s, o, 64);
    diag[e] = s * (0.5f * CDN * CDN);
  }
  __syncthreads();  // ldsq/ldsp reads done -> overlay
#pragma unroll
  for (int j = 0; j < 16; j++)
#pragma unroll
    for (int e = 0; e < 4; e++) {
      float v = CRATIO * (expf(acc[j][e] - diag[e] - rmax[e]) + CKEPS);
      ldso[(wv * 16 + g * 4 + e) * 264 + j * 16 + fr] = f2bu(v);
    }
  __syncthreads();
  // coalesced store + fused dinv
  int row = tid >> 2, seg = (tid & 3) * 64;
  long base = ((long)bh * CT + t0) * CM;
  float dot = 0;
#pragma unroll
  for (int z = 0; z < 8; z++) {
    u16x8 v8 = *(u16x8*)&ldso[row * 264 + seg + z * 8];
    *(u16x8*)&qp[base + (long)row * CM + seg + z * 8] = v8;
#pragma unroll
    for (int w = 0; w < 8; w++) dot += b2f(v8[w]) * ldks[seg + z * 8 + w];
  }
  dot += __shfl_xor(dot, 1, 64);
  dot += __shfl_xor(dot, 2, 64);
  if ((tid & 3) == 0) dinv[(long)bh * CT + t0 + row] = 1.0f / dot;
}

// ---------------- LayerNorm: fp32 in -> bf16 out ----------------
__global__ __launch_bounds__(256) void ln_k(const float* __restrict__ h,
                                            const float* __restrict__ g,
                                            const float* __restrict__ b,
                                            unsigned short* __restrict__ y) {
  int wv = threadIdx.x >> 6, ll = threadIdx.x & 63;
  long row = (long)blockIdx.x * 4 + wv;
  const float* hr = h + row * CDM;
  f32x4 x[4];
#pragma unroll
  for (int i = 0; i < 4; i++) x[i] = *(const f32x4*)&hr[ll * 16 + i * 4];
  float s = 0;
#pragma unroll
  for (int i = 0; i < 4; i++)
#pragma unroll
    for (int e = 0; e < 4; e++) s += x[i][e];
  float mu = wredsum(s) * (1.f / CDM);
  float v = 0;
#pragma unroll
  for (int i = 0; i < 4; i++)
#pragma unroll
    for (int e = 0; e < 4; e++) {
      float d = x[i][e] - mu;
      v += d * d;
    }
  float inv = rsqrtf(wredsum(v) * (1.f / CDM) + 1e-5f);
  unsigned short o[16];
#pragma unroll
  for (int i = 0; i < 4; i++)
#pragma unroll
    for (int e = 0; e < 4; e++) {
      int c = ll * 16 + i * 4 + e;
      o[i * 4 + e] = f2bu((x[i][e] - mu) * inv * g[c] + b[c]);
    }
  *(u16x8*)&y[row * CDM + ll * 16] = *(u16x8*)&o[0];
  *(u16x8*)&y[row * CDM + ll * 16 + 8] = *(u16x8*)&o[8];
}

// ---------------- v (from fused qkv) -> v_t (B,H,DH,T) ----------------
__global__ __launch_bounds__(256) void trv_k(const unsigned short* __restrict__ vb,
                                             unsigned short* __restrict__ vt) {
  int bh = blockIdx.x >> 5;
  int t0 = (blockIdx.x & 31) * 32;
  int b = bh >> 4, hh = bh & 15;
  __shared__ unsigned short tile[32][64];
  int tr = threadIdx.x >> 3, dblk = (threadIdx.x & 7) * 8;
  *(u16x8*)&tile[tr][dblk] = *(const u16x8*)&vb[((long)b * CT + t0 + tr) * CQKV + hh * CDH + dblk];
  __syncthreads();
  int d = threadIdx.x >> 2, tz = (threadIdx.x & 3) * 8;
  unsigned short o[8];
#pragma unroll
  for (int e = 0; e < 8; e++) o[e] = tile[tz + e][d];
  *(u16x8*)&vt[((long)bh * CDH + d) * CT + t0 + tz] = *(u16x8*)&o[0];
}

// ---------------- h += pe ----------------
__global__ __launch_bounds__(256) void addpe_k(float* __restrict__ h, const float* __restrict__ pe) {
  long i = ((long)blockIdx.x * 256 + threadIdx.x) * 4;
  int t = (int)((i >> 10) & 1023);
  int c = (int)(i & 1023);
  f32x4 v = *(f32x4*)&h[i];
  f32x4 p = *(const f32x4*)&pe[(long)t * 1024 + c];
  v += p;
  *(f32x4*)&h[i] = v;
}

// ---------------- fp32 -> bf16 flat ----------------
__global__ __launch_bounds__(256) void f2b_k(const float* __restrict__ in,
                                             unsigned short* __restrict__ out, long n) {
  long i = ((long)blockIdx.x * 256 + threadIdx.x) * 4;
  if (i >= n) return;
  f32x4 v = *(const f32x4*)&in[i];
  unsigned short o[4];
#pragma unroll
  for (int e = 0; e < 4; e++) o[e] = f2bu(v[e]);
  *(u16x4*)&out[i] = *(u16x4*)&o[0];
}

// ---------------- transpose-convert: in (R,C) fp32 -> out (C,R) bf16 ----------------
__global__ __launch_bounds__(256) void tconv_k(const float* __restrict__ in,
                                               unsigned short* __restrict__ out, int R, int C) {
  __shared__ float tile[32][33];
  int r0 = blockIdx.x * 32, c0 = blockIdx.y * 32;
  int tr = threadIdx.x >> 5, tc = threadIdx.x & 31;
#pragma unroll
  for (int p = 0; p < 4; p++) {
    int r = r0 + p * 8 + tr, c = c0 + tc;
    tile[p * 8 + tr][tc] = (r < R && c < C) ? in[(long)r * C + c] : 0.f;
  }
  __syncthreads();
#pragma unroll
  for (int p = 0; p < 4; p++) {
    int c = c0 + p * 8 + tr, r = r0 + tc;
    if (c < C && r < R) out[(long)c * R + r] = f2bu(tile[tc][p * 8 + tr]);
  }
}

// ---------------- Wconv (64,1024,3) -> per-tap bf16: [r][oc][ic] = (192,1024) ----------------
__global__ __launch_bounds__(256) void wconv_k(const float* __restrict__ W,
                                               unsigned short* __restrict__ out) {
  int idx = blockIdx.x * 256 + threadIdx.x;
  int r = idx >> 16, rem = idx & 65535, oc = rem >> 10, ic = rem & 1023;
  out[idx] = f2bu(W[oc * 3072 + ic * 3 + r]);
}

// ---------------- conv tap-mix ----------------
__global__ __launch_bounds__(256) void convmix_k(const float* __restrict__ Y,
                                                 const float* __restrict__ bc,
                                                 float* __restrict__ xa) {
  long t = (long)blockIdx.x * 4 + (threadIdx.x >> 6);
  int oc = threadIdx.x & 63;
  long tm = t > 0 ? t - 1 : 0, tp = t < CNT - 1 ? t + 1 : CNT - 1;  // boundary rows re-patched
  float v = Y[tm * 192 + oc] + Y[t * 192 + 64 + oc] + Y[tp * 192 + 128 + oc] + bc[oc];
  xa[t * 64 + oc] = v;
}

// ---------------- proj * dn -> bf16 ----------------
__global__ __launch_bounds__(256) void projc_k(const float* __restrict__ p,
                                               unsigned short* __restrict__ out) {
  int i = blockIdx.x * 256 + threadIdx.x;
  out[i] = f2bu(p[i] * CDN);
}

// ---------------- concat q/k/v biases ----------------
__global__ __launch_bounds__(256) void catb_k(const float* __restrict__ q,
                                              const float* __restrict__ k,
                                              const float* __restrict__ v,
                                              float* __restrict__ o) {
  int i = blockIdx.x * 256 + threadIdx.x;  // < 3072
  o[i] = i < 1024 ? q[i] : (i < 2048 ? k[i - 1024] : v[i - 2048]);
}

// ---------------- exact conv recompute at batch boundaries ----------------
__global__ __launch_bounds__(256) void patch_k(const float* __restrict__ h,
                                               const float* __restrict__ W,
                                               const float* __restrict__ bc,
                                               float* __restrict__ xa) {
  int b = blockIdx.x >> 1;
  int t = (blockIdx.x & 1) ? (CT - 1) : 0;
  int oc = threadIdx.x & 63, ch = threadIdx.x >> 6;
  float s = 0;
  for (int r = 0; r < 3; r++) {
    int tt = t + r - 1;
    if (tt < 0 || tt >= CT) continue;
    const float* hr = h + ((long)b * CT + tt) * CDM;
    const float* wr = W + oc * 3072 + r;
    for (int ic = ch * 256; ic < ch * 256 + 256; ic++) s += hr[ic] * wr[ic * 3];
  }
  __shared__ float sm[256];
  sm[threadIdx.x] = s;
  __syncthreads();
  if (threadIdx.x < 64) {
    float tot = sm[oc] + sm[64 + oc] + sm[128 + oc] + sm[192 + oc] + bc[oc];
    xa[((long)b * CT + t) * 64 + oc] = tot;
  }
}

#define LAUNCH_GEMM(EPI, A, Bt, bias, C, rsp, Mr, Nr, Kr, lda, ldb, ldc, nb, bdiv, As1, As2, Bs1, Bs2, Cs1, Cs2, Rs1, Rs2) \
  gemm_k<EPI><<<dim3(((Mr) + 127) / 128, ((Nr) + 127) / 128, (nb)), 256, 0, stream>>>(           \
      (const unsigned short*)(A), (const unsigned short*)(Bt), (bias), (void*)(C), (rsp),        \
      (Mr), (Nr), (Kr), (lda), (ldb), (ldc), (bdiv), (long)(As1), (long)(As2), (long)(Bs1),      \
      (long)(Bs2), (long)(Cs1), (long)(Cs2), (long)(Rs1), (long)(Rs2))

#define LAUNCH_G1(EPI, A, Bt, bias, C, Mr, Nr, Kr, lda, ldb, ldc)                                \
  gemm128_k<EPI><<<dim3(((Mr) + 127) / 128, ((Nr) + 127) / 128), 512, 0, stream>>>(              \
      (const unsigned short*)(A), (const unsigned short*)(Bt), (bias), (void*)(C),               \
      (Mr), (Nr), (Kr), (lda), (ldb), (ldc))

extern "C" void kernel_launch(void* const* d_in, const int* in_sizes, int n_in,
                              void* d_out, int out_size, void* d_ws, size_t ws_size,
                              hipStream_t stream) {
  const float* x = (const float*)d_in[0];
  const float* Win = (const float*)d_in[1];
  const float* b_in = (const float*)d_in[2];
  const float* pe = (const float*)d_in[3];
  const float* ln1_g = (const float*)d_in[4];
  const float* ln1_b = (const float*)d_in[5];
  const float* Wq = (const float*)d_in[6];
  const float* bq = (const float*)d_in[7];
  const float* Wk = (const float*)d_in[8];
  const float* bk = (const float*)d_in[9];
  const float* Wv = (const float*)d_in[10];
  const float* bv = (const float*)d_in[11];
  const float* Wo = (const float*)d_in[12];
  const float* bo = (const float*)d_in[13];
  const float* ln2_g = (const float*)d_in[14];
  const float* ln2_b = (const float*)d_in[15];
  const float* W1 = (const float*)d_in[16];
  const float* b1 = (const float*)d_in[17];
  const float* W2 = (const float*)d_in[18];
  const float* b2 = (const float*)d_in[19];
  const float* Wc = (const float*)d_in[20];
  const float* bc = (const float*)d_in[21];
  const float* Wconv = (const float*)d_in[22];
  const float* bconv = (const float*)d_in[23];
  const float* Waux = (const float*)d_in[24];
  const float* baux = (const float*)d_in[25];
  const float* proj = (const float*)d_in[26];
  float* out = (float*)d_out;

  char* wsp = (char*)d_ws;
  size_t off = 0;
  auto take = [&](size_t bytes) {
    char* p = wsp + off;
    off = (off + bytes + 255) & ~(size_t)255;
    return p;
  };
  float* h_f = (float*)take(33554432);                      // (8192,1024) fp32 residual
  unsigned short* y_bf = (unsigned short*)take(16777216);   // LN out; aliased: vt, o
  unsigned short* qkv_bf = (unsigned short*)take(50331648); // (8192,3072) fused q,k,v
  unsigned short* qp_bf = (unsigned short*)take(67108864);  // (B,H,T,M)
  unsigned short* kpt_bf = (unsigned short*)take(67108864); // (B,H,M,T)
  unsigned short* ff_bf = (unsigned short*)take(67108864);  // (8192,4096) FFN mid
  unsigned short* ctx_bf = (unsigned short*)take(4194304);  // (B,H,DH,M)
  float* ksum_f = (float*)take(131072);
  float* kspart_f = (float*)take(1048576);                  // (bh,8,256)
  float* kstab_f_buf = (float*)take(4096);                  // (bh,8)
  float* dinv_f = (float*)take(524288);
  float* xa_f = (float*)take(2097152);
  float* ycv_f = (float*)take(6291456);                     // (8192,192) conv taps
  unsigned short* xabf = (unsigned short*)take(1048576);
  float* bqkv_f = (float*)take(24576);                      // 2 layers x 3072
  unsigned short* hbf = (unsigned short*)take(16777216);
  unsigned short* xbf = (unsigned short*)take(4194304);
  unsigned short* win_t = (unsigned short*)take(524288);
  unsigned short* wqkvo_t = (unsigned short*)take(16777216);
  unsigned short* w1_t = (unsigned short*)take(16777216);
  unsigned short* w2_t = (unsigned short*)take(16777216);
  unsigned short* wc_t = (unsigned short*)take(4096000);
  unsigned short* projc = (unsigned short*)take(32768);
  unsigned short* wconv_t = (unsigned short*)take(393216);
  unsigned short* waux_t = (unsigned short*)take(256128);
  unsigned short* vt_bf = y_bf;                    // alias (y dead after QKV)
  unsigned short* o_bf = y_bf;                     // alias (vt dead after ctx)
  (void)in_sizes; (void)n_in; (void)out_size; (void)ws_size;

  // ---- weight conversion ----
  f2b_k<<<2048, 256, 0, stream>>>(x, xbf, (long)CNT * 256);
  tconv_k<<<dim3(8, 32), 256, 0, stream>>>(Win, win_t, 256, 1024);
  for (int l = 0; l < 2; l++) {
    tconv_k<<<dim3(32, 32), 256, 0, stream>>>(Wq + (long)l * 1048576, wqkvo_t + (long)(l * 4 + 0) * 1048576, 1024, 1024);
    tconv_k<<<dim3(32, 32), 256, 0, stream>>>(Wk + (long)l * 1048576, wqkvo_t + (long)(l * 4 + 1) * 1048576, 1024, 1024);
    tconv_k<<<dim3(32, 32), 256, 0, stream>>>(Wv + (long)l * 1048576, wqkvo_t + (long)(l * 4 + 2) * 1048576, 1024, 1024);
    tconv_k<<<dim3(32, 32), 256, 0, stream>>>(Wo + (long)l * 1048576, wqkvo_t + (long)(l * 4 + 3) * 1048576, 1024, 1024);
    tconv_k<<<dim3(32, 128), 256, 0, stream>>>(W1 + (long)l * 4194304, w1_t + (long)l * 4194304, 1024, 4096);
    tconv_k<<<dim3(128, 32), 256, 0, stream>>>(W2 + (long)l * 4194304, w2_t + (long)l * 4194304, 4096, 1024);
    catb_k<<<12, 256, 0, stream>>>(bq + l * CDM, bk + l * CDM, bv + l * CDM, bqkv_f + l * CQKV);
  }
  tconv_k<<<dim3(32, 63), 256, 0, stream>>>(Wc, wc_t, 1024, 2000);
  tconv_k<<<dim3(2, 63), 256, 0, stream>>>(Waux, waux_t, 64, 2001);
  wconv_k<<<768, 256, 0, stream>>>(Wconv, wconv_t);
  projc_k<<<64, 256, 0, stream>>>(proj, projc);

  // ---- embed ----
  LAUNCH_G1(EPI_BIAS, xbf, win_t, b_in, h_f, CNT, CDM, 256, 256, 256, CDM);
  addpe_k<<<8192, 256, 0, stream>>>(h_f, pe);

  for (int l = 0; l < 2; l++) {
    const unsigned short* wqkv_t = wqkvo_t + (long)(l * 4) * 1048576;  // q,k,v adjacent
    const unsigned short* wo_t = wqkvo_t + (long)(l * 4 + 3) * 1048576;

    ln_k<<<2048, 256, 0, stream>>>(h_f, ln1_g + l * CDM, ln1_b + l * CDM, y_bf);
    LAUNCH_G1(EPI_BIAS | EPI_OUTBF, y_bf, wqkv_t, bqkv_f + l * CQKV, qkv_bf, CNT, CQKV, CDM, CDM, CDM, CQKV);

    // fused FAVOR+: keys (2 passes) then queries (+dinv)
    kstab_f<<<1024, 512, 55296, stream>>>(qkv_bf + 1024, projc, kstab_f_buf);
    featk_f<<<1024, 512, 69632, stream>>>(qkv_bf + 1024, projc, kstab_f_buf, kpt_bf, kspart_f);
    ksred_k<<<128, 256, 0, stream>>>(kspart_f, ksum_f);
    featq_f<<<1024, 512, 68608, stream>>>(qkv_bf, projc, ksum_f, qp_bf, dinv_f);
    trv_k<<<4096, 256, 0, stream>>>(qkv_bf + 2048, vt_bf);
    // ctx^T (DH,M) = v^T @ kp, batched
    LAUNCH_GEMM(EPI_OUTBF, vt_bf, kpt_bf, nullptr, ctx_bf, nullptr, CDH, CM, CT, CT, CT, CM, 128, CH,
                (long)CH * CDH * CT, (long)CDH * CT, (long)CH * CM * CT, (long)CM * CT,
                (long)CH * CDH * CM, (long)CDH * CM, 0, 0);
    // o = (qp @ ctx) * dinv -> (B,T,H*DH) bf16
    LAUNCH_GEMM(EPI_RSCALE | EPI_OUTBF, qp_bf, ctx_bf, nullptr, o_bf, dinv_f, CT, CDH, CM, CM, CM, CDM, 128, CH,
                (long)CH * CT * CM, (long)CT * CM, (long)CH * CDH * CM, (long)CDH * CM,
                (long)CT * CDM, 64, (long)CH * CT, (long)CT);
    LAUNCH_G1(EPI_BIAS | EPI_ACCUM, o_bf, wo_t, bo + l * CDM, h_f, CNT, CDM, CDM, CDM, CDM, CDM);

    ln_k<<<2048, 256, 0, stream>>>(h_f, ln2_g + l * CDM, ln2_b + l * CDM, y_bf);
    LAUNCH_G1(EPI_BIAS | EPI_GELU | EPI_OUTBF, y_bf, w1_t + (long)l * 4194304, b1 + l * CDFF, ff_bf,
              CNT, CDFF, CDM, CDM, CDM, CDFF);
    LAUNCH_G1(EPI_BIAS | EPI_ACCUM, ff_bf, w2_t + (long)l * 4194304, b2 + l * CDM, h_f,
              CNT, CDM, CDFF, CDFF, CDFF, CDM);

    if (l == 0) {
      // conv1d: single N=192 GEMM over 3 taps, shift-add mix + exact boundary patch
      f2b_k<<<8192, 256, 0, stream>>>(h_f, hbf, (long)CNT * CDM);
      LAUNCH_GEMM(0, hbf, wconv_t, nullptr, ycv_f, nullptr, CNT, 192, CDM, CDM, CDM, 192, 1, 1, 0, 0, 0, 0, 0, 0, 0, 0);
      convmix_k<<<2048, 256, 0, stream>>>(ycv_f, bconv, xa_f);
      patch_k<<<16, 256, 0, stream>>>(h_f, Wconv, bconv, xa_f);
      f2b_k<<<512, 256, 0, stream>>>(xa_f, xabf, (long)CNT * 64);
      LAUNCH_GEMM(EPI_BIAS, xabf, waux_t, baux, out + 16384000, nullptr, CNT, CV + 1, 64, 64, 64, CV + 1, 1, 1, 0, 0, 0, 0, 0, 0, 0, 0);
    }
  }

  // ---- classifier ----
  f2b_k<<<8192, 256, 0, stream>>>(h_f, hbf, (long)CNT * CDM);
  LAUNCH_G1(EPI_BIAS, hbf, wc_t, bc, out, CNT, CV, CDM, CDM, CDM, CV);
}